// Round 1
// baseline (902.145 us; speedup 1.0000x reference)
//
#include <hip/hip_runtime.h>
#include <math.h>

#define HW      1792
#define NMEM    28672
#define CKDIM   64
#define CVDIM   512
#define TOPK    30
#define NT      1024     // n-range per block (partial topk tile)
#define NSUB    64       // n per compute subtile
#define PT      64       // pixels per block
#define NTILES  (NMEM / NT)      // 28
#define PTILES  (HW / PT)        // 28
#define NCAND   (NTILES * TOPK)  // 840

// ---------------------------------------------------------------------------
// Kernel 1: fused sim computation + per-n-tile top-30 per pixel.
// sim[n,p] = (sum_c mk*u + mk^2*w  - bsq[p]) * shr[n],  u=2*qk*qs, w=-qs
// ---------------------------------------------------------------------------
__global__ __launch_bounds__(256, 2)
void k_sim_topk(const float* __restrict__ q_key, const float* __restrict__ q_sel,
                const float* __restrict__ mem_key, const float* __restrict__ mem_shr,
                float* __restrict__ pvals, int* __restrict__ pidx)
{
  __shared__ float sU[CKDIM][PT];      // 16 KB
  __shared__ float sW[CKDIM][PT];      // 16 KB
  __shared__ float sA[CKDIM][NSUB];    // 16 KB (reused as sim[NSUB][PT])
  __shared__ float sBsq[PT];
  __shared__ float sShr[NSUB];
  __shared__ float sTopV[PT][TOPK];    // 7.5 KB
  __shared__ int   sTopI[PT][TOPK];    // 7.5 KB

  const int tid = threadIdx.x;
  const int p0 = blockIdx.y * PT;
  const int nbase = blockIdx.x * NT;

  // stage U = 2*qk*qs and W = -qs for this pixel tile
  for (int i = tid; i < CKDIM * PT; i += 256) {
    int c = i >> 6, p = i & (PT - 1);
    float k = q_key[c * HW + p0 + p];
    float s = q_sel[c * HW + p0 + p];
    sU[c][p] = 2.f * k * s;
    sW[c][p] = -s;
  }
  float curmin = -INFINITY;
  int   minpos = 0;
  if (tid < PT) {
    float b = 0.f;
    for (int c = 0; c < CKDIM; ++c) {
      float k = q_key[c * HW + p0 + tid];
      float s = q_sel[c * HW + p0 + tid];
      b = fmaf(s * k, k, b);
    }
    sBsq[tid] = b;
    for (int k2 = 0; k2 < TOPK; ++k2) { sTopV[tid][k2] = -INFINITY; sTopI[tid][k2] = 0; }
  }
  __syncthreads();

  const int tn = (tid & 15) * 4;   // 4 n's per thread
  const int tp = (tid >> 4) * 4;   // 4 p's per thread

  for (int sub = 0; sub < NT / NSUB; ++sub) {
    const int n0 = nbase + sub * NSUB;
    // stage mk tile [64c][64n]
    for (int i = tid; i < CKDIM * NSUB / 4; i += 256) {
      int c = i >> 4, j = (i & 15) << 2;
      *reinterpret_cast<float4*>(&sA[c][j]) =
          *reinterpret_cast<const float4*>(&mem_key[(size_t)c * NMEM + n0 + j]);
    }
    if (tid < NSUB) sShr[tid] = mem_shr[n0 + tid] * 0.125f;
    __syncthreads();

    float acc[4][4];
    #pragma unroll
    for (int i = 0; i < 4; ++i)
      #pragma unroll
      for (int j = 0; j < 4; ++j) acc[i][j] = 0.f;

    #pragma unroll 8
    for (int c = 0; c < CKDIM; ++c) {
      float4 a4 = *reinterpret_cast<const float4*>(&sA[c][tn]);
      float4 u4 = *reinterpret_cast<const float4*>(&sU[c][tp]);
      float4 w4 = *reinterpret_cast<const float4*>(&sW[c][tp]);
      float a[4] = {a4.x, a4.y, a4.z, a4.w};
      float u[4] = {u4.x, u4.y, u4.z, u4.w};
      float w[4] = {w4.x, w4.y, w4.z, w4.w};
      #pragma unroll
      for (int i = 0; i < 4; ++i) {
        float a2 = a[i] * a[i];
        #pragma unroll
        for (int j = 0; j < 4; ++j)
          acc[i][j] = fmaf(a[i], u[j], fmaf(a2, w[j], acc[i][j]));
      }
    }
    __syncthreads();   // done reading sA; reuse it as sim[NSUB][PT]
    float* sim = &sA[0][0];
    #pragma unroll
    for (int i = 0; i < 4; ++i)
      #pragma unroll
      for (int j = 0; j < 4; ++j)
        sim[(tn + i) * PT + tp + j] = (acc[i][j] - sBsq[tp + j]) * sShr[tn + i];
    __syncthreads();

    // wave 0: per-pixel running top-30 (replace-min)
    if (tid < PT) {
      #pragma unroll 1
      for (int n = 0; n < NSUB; ++n) {
        float v = sim[n * PT + tid];
        if (v > curmin) {
          sTopV[tid][minpos] = v;
          sTopI[tid][minpos] = n0 + n;
          float m = sTopV[tid][0]; int mp = 0;
          #pragma unroll 1
          for (int k2 = 1; k2 < TOPK; ++k2) {
            float tv = sTopV[tid][k2];
            if (tv < m) { m = tv; mp = k2; }
          }
          curmin = m; minpos = mp;
        }
      }
    }
    __syncthreads();
  }

  if (tid < PT) {
    size_t base = ((size_t)(p0 + tid) * NTILES + blockIdx.x) * 32;
    for (int k2 = 0; k2 < TOPK; ++k2) {
      pvals[base + k2] = sTopV[tid][k2];
      pidx[base + k2]  = sTopI[tid][k2];
    }
  }
}

// ---------------------------------------------------------------------------
// Kernel 2: merge 28x30 partial candidates per pixel -> top-30 -> softmax
// ---------------------------------------------------------------------------
__global__ __launch_bounds__(64)
void k_merge(const float* __restrict__ pvals, const int* __restrict__ pidx,
             float* __restrict__ wgt, int* __restrict__ widx)
{
  __shared__ float cv[NCAND];
  __shared__ int   ci[NCAND];
  __shared__ float stv[TOPK];
  __shared__ int   sti[TOPK];
  const int pix = blockIdx.x;
  const int tid = threadIdx.x;

  for (int i = tid; i < NCAND; i += 64) {
    int t = i / TOPK, k = i - t * TOPK;
    cv[i] = pvals[((size_t)pix * NTILES + t) * 32 + k];
    ci[i] = pidx[((size_t)pix * NTILES + t) * 32 + k];
  }
  __syncthreads();

  for (int r = 0; r < TOPK; ++r) {
    float best = -INFINITY; int bpos = 0;
    for (int i = tid; i < NCAND; i += 64) {
      float v = cv[i];
      if (v > best) { best = v; bpos = i; }
    }
    #pragma unroll
    for (int off = 32; off > 0; off >>= 1) {
      float ov = __shfl_down(best, off);
      int   op = __shfl_down(bpos, off);
      if (ov > best) { best = ov; bpos = op; }
    }
    if (tid == 0) { stv[r] = best; sti[r] = ci[bpos]; cv[bpos] = -INFINITY; }
    __syncthreads();
  }

  // softmax over the 30 selected values (all <= 0, exp is safe, matches ref)
  float e = (tid < TOPK) ? expf(stv[tid]) : 0.f;
  float ssum = e;
  #pragma unroll
  for (int off = 32; off > 0; off >>= 1) ssum += __shfl_down(ssum, off);
  ssum = __shfl(ssum, 0);
  if (tid < TOPK) {
    wgt [(size_t)pix * 32 + tid] = e / ssum;
    widx[(size_t)pix * 32 + tid] = sti[tid];
  }
}

// ---------------------------------------------------------------------------
// Kernel 3: transpose mem_value [1024][N] -> [N][1024] for coalesced gathers
// ---------------------------------------------------------------------------
__global__ __launch_bounds__(256)
void k_transpose(const float* __restrict__ mv, float* __restrict__ mvT)
{
  __shared__ float t[64][65];
  const int n0 = blockIdx.x * 64, ch0 = blockIdx.y * 64;
  const int tid = threadIdx.x;
  for (int i = tid; i < 64 * 16; i += 256) {
    int r = i >> 4, c4 = (i & 15) << 2;
    float4 v = *reinterpret_cast<const float4*>(&mv[(size_t)(ch0 + r) * NMEM + n0 + c4]);
    t[r][c4] = v.x; t[r][c4 + 1] = v.y; t[r][c4 + 2] = v.z; t[r][c4 + 3] = v.w;
  }
  __syncthreads();
  for (int i = tid; i < 64 * 16; i += 256) {
    int r = i >> 4, c4 = (i & 15) << 2;   // r: n within tile, c4: ch within tile
    float4 v = make_float4(t[c4][r], t[c4 + 1][r], t[c4 + 2][r], t[c4 + 3][r]);
    *reinterpret_cast<float4*>(&mvT[(size_t)(n0 + r) * 1024 + ch0 + c4]) = v;
  }
}

// ---------------------------------------------------------------------------
// Kernel 4: out[ch][p] = sum_k w[p][k] * src[idx[p][k]][ch]
// src indexing via strides so it works on mvT (fast) or mem_value (fallback)
// ---------------------------------------------------------------------------
__global__ __launch_bounds__(256)
void k_gather(const float* __restrict__ src, const float* __restrict__ wgt,
              const int* __restrict__ widx, float* __restrict__ out,
              int n_stride, int ch_stride)
{
  __shared__ float sw[16][TOPK];
  __shared__ int   si[16][TOPK];
  __shared__ float sbuf[256][17];
  const int p0 = blockIdx.x * 16, chg = blockIdx.y * 256;
  const int tid = threadIdx.x;

  for (int i = tid; i < 16 * TOPK; i += 256) {
    int q = i / TOPK, k = i - q * TOPK;
    sw[q][k] = wgt [(size_t)(p0 + q) * 32 + k];
    si[q][k] = widx[(size_t)(p0 + q) * 32 + k];
  }
  __syncthreads();

  const int ch = chg + tid;
  #pragma unroll 2
  for (int q = 0; q < 16; ++q) {
    float a = 0.f;
    #pragma unroll
    for (int k = 0; k < TOPK; ++k)
      a = fmaf(sw[q][k], src[(size_t)si[q][k] * n_stride + (size_t)ch * ch_stride], a);
    sbuf[tid][q] = a;
  }
  __syncthreads();

  for (int i = tid; i < 256 * 16; i += 256) {
    int cl = i >> 4, q = i & 15;
    out[(size_t)(chg + cl) * HW + p0 + q] = sbuf[cl][q];
  }
}

// ---------------------------------------------------------------------------
extern "C" void kernel_launch(void* const* d_in, const int* in_sizes, int n_in,
                              void* d_out, int out_size, void* d_ws, size_t ws_size,
                              hipStream_t stream)
{
  (void)in_sizes; (void)n_in; (void)out_size;
  const float* q_key     = (const float*)d_in[0];
  const float* q_sel     = (const float*)d_in[1];
  const float* mem_key   = (const float*)d_in[2];
  const float* mem_shr   = (const float*)d_in[3];
  const float* mem_value = (const float*)d_in[4];
  float* out = (float*)d_out;

  char* ws = (char*)d_ws;
  size_t off = 0;
  auto alloc = [&](size_t b) { size_t c = off; off = (off + b + 255) & ~(size_t)255; return c; };
  size_t o_pv  = alloc((size_t)HW * NTILES * 32 * 4);   // 6.4 MB
  size_t o_pi  = alloc((size_t)HW * NTILES * 32 * 4);   // 6.4 MB
  size_t o_w   = alloc((size_t)HW * 32 * 4);
  size_t o_wi  = alloc((size_t)HW * 32 * 4);
  size_t o_mvT = alloc((size_t)NMEM * 1024 * 4);        // 117.4 MB
  bool useT = (ws_size >= off);

  float* pv  = (float*)(ws + o_pv);
  int*   pi  = (int*)  (ws + o_pi);
  float* wg  = (float*)(ws + o_w);
  int*   wi  = (int*)  (ws + o_wi);
  float* mvT = (float*)(ws + o_mvT);

  k_sim_topk<<<dim3(NTILES, PTILES), 256, 0, stream>>>(q_key, q_sel, mem_key, mem_shr, pv, pi);
  k_merge<<<dim3(HW), 64, 0, stream>>>(pv, pi, wg, wi);
  if (useT) {
    k_transpose<<<dim3(NMEM / 64, 1024 / 64), 256, 0, stream>>>(mem_value, mvT);
    k_gather<<<dim3(HW / 16, 4), 256, 0, stream>>>(mvT, wg, wi, out, 1024, 1);
  } else {
    k_gather<<<dim3(HW / 16, 4), 256, 0, stream>>>(mem_value, wg, wi, out, 1, NMEM);
  }
}

// Round 2
// 496.815 us; speedup vs baseline: 1.8159x; 1.8159x over previous
//
#include <hip/hip_runtime.h>
#include <math.h>

#define HW      1792
#define NMEM    28672
#define TOPK    30
#define NT      1024     // n-range per k_sim block
#define BINS    4096

// key: larger v  <->  smaller key (v <= 0 up to rounding noise)
static __device__ __forceinline__ unsigned fkey(float v) {
  return __float_as_uint(-v) & 0x7FFFFFFFu;
}

// ---------------------------------------------------------------------------
// Kernel 1: pure sim GEMM -> simT[p][n] (pixel-major, fp32)
// sim[n,p] = (sum_c mk*u + mk^2*w - bsq[p]) * shr[n],  u=2*qk*qs, w=-qs
// ---------------------------------------------------------------------------
__global__ __launch_bounds__(256, 3)
void k_sim(const float* __restrict__ q_key, const float* __restrict__ q_sel,
           const float* __restrict__ mem_key, const float* __restrict__ mem_shr,
           float* __restrict__ simT, int p0)
{
  __shared__ float sU[64][64];   // 16 KB
  __shared__ float sW[64][64];   // 16 KB
  __shared__ float sA[64][64];   // 16 KB
  __shared__ float sBsq[64];
  __shared__ float sShr[64];

  const int tid = threadIdx.x;
  const int prow0 = blockIdx.y * 64;   // pixel row within chunk
  const int pg = p0 + prow0;           // global pixel base
  const int nbase = blockIdx.x * NT;

  for (int i = tid; i < 64 * 64; i += 256) {
    int c = i >> 6, p = i & 63;
    float k = q_key[c * HW + pg + p];
    float s = q_sel[c * HW + pg + p];
    sU[c][p] = 2.f * k * s;
    sW[c][p] = -s;
  }
  if (tid < 64) {
    float b = 0.f;
    for (int c = 0; c < 64; ++c) {
      float k = q_key[c * HW + pg + tid];
      float s = q_sel[c * HW + pg + tid];
      b = fmaf(s * k, k, b);
    }
    sBsq[tid] = b;
  }
  __syncthreads();

  const int tn = (tid & 15) * 4;   // 4 n per thread
  const int tp = (tid >> 4) * 4;   // 4 p per thread

  for (int sub = 0; sub < NT / 64; ++sub) {
    const int n0 = nbase + sub * 64;
    for (int i = tid; i < 64 * 16; i += 256) {
      int c = i >> 4, j = (i & 15) << 2;
      *reinterpret_cast<float4*>(&sA[c][j]) =
          *reinterpret_cast<const float4*>(&mem_key[(size_t)c * NMEM + n0 + j]);
    }
    if (tid < 64) sShr[tid] = mem_shr[n0 + tid] * 0.125f;
    __syncthreads();

    float acc[4][4];
    #pragma unroll
    for (int i = 0; i < 4; ++i)
      #pragma unroll
      for (int j = 0; j < 4; ++j) acc[i][j] = 0.f;

    #pragma unroll 8
    for (int c = 0; c < 64; ++c) {
      float4 a4 = *reinterpret_cast<const float4*>(&sA[c][tn]);
      float4 u4 = *reinterpret_cast<const float4*>(&sU[c][tp]);
      float4 w4 = *reinterpret_cast<const float4*>(&sW[c][tp]);
      float a[4] = {a4.x, a4.y, a4.z, a4.w};
      float u[4] = {u4.x, u4.y, u4.z, u4.w};
      float w[4] = {w4.x, w4.y, w4.z, w4.w};
      #pragma unroll
      for (int i = 0; i < 4; ++i) {
        float a2 = a[i] * a[i];
        #pragma unroll
        for (int j = 0; j < 4; ++j)
          acc[i][j] = fmaf(a[i], u[j], fmaf(a2, w[j], acc[i][j]));
      }
    }
    float4 shr4 = *reinterpret_cast<const float4*>(&sShr[tn]);
    __syncthreads();   // all reads of sA/sShr done before next staging

    #pragma unroll
    for (int j = 0; j < 4; ++j) {
      float b = sBsq[tp + j];
      float4 v = make_float4((acc[0][j] - b) * shr4.x, (acc[1][j] - b) * shr4.y,
                             (acc[2][j] - b) * shr4.z, (acc[3][j] - b) * shr4.w);
      *reinterpret_cast<float4*>(&simT[(size_t)(prow0 + tp + j) * NMEM + n0 + tn]) = v;
    }
  }
}

// ---------------------------------------------------------------------------
// crossing finder: smallest bin B with prefix(<B) < target <= prefix(<=B)
// ---------------------------------------------------------------------------
__device__ __forceinline__ void find_cross(int* hist, int* lsum, int* wsum,
                                           int tid, int target,
                                           int* sB, int* sNA)
{
  const int base = tid * (BINS / 256);
  int ls = 0;
  #pragma unroll
  for (int k = 0; k < BINS / 256; ++k) ls += hist[base + k];
  lsum[tid] = ls;
  __syncthreads();
  int lane = tid & 63, wv = tid >> 6;
  int v = ls;
  #pragma unroll
  for (int off = 1; off < 64; off <<= 1) {
    int t = __shfl_up(v, off);
    if (lane >= off) v += t;
  }
  if (lane == 63) wsum[wv] = v;
  __syncthreads();
  int wo = 0;
  for (int k = 0; k < wv; ++k) wo += wsum[k];
  int run = wo + v - ls;            // exclusive global prefix
  #pragma unroll 1
  for (int k = 0; k < BINS / 256; ++k) {
    int h = hist[base + k];
    if (run < target && run + h >= target) { *sB = base + k; *sNA = run; }
    run += h;
  }
  __syncthreads();
}

// ---------------------------------------------------------------------------
// Kernel 2: exact per-pixel top-30 + softmax weights.
// Fast path: per-thread top-4 -> 1024 pool -> histogram select -> verify.
// Fallback (verify fail, ~never): exact histogram over all N.
// ---------------------------------------------------------------------------
__global__ __launch_bounds__(256)
void k_select(const float* __restrict__ simT, float* __restrict__ wgt,
              int* __restrict__ widx, int p0)
{
  __shared__ int      hist[BINS];   // 16 KB
  __shared__ unsigned pu[1024];     // 4 KB pool keys
  __shared__ int      pidd[1024];   // 4 KB pool indices
  __shared__ unsigned bu[1024];     // 4 KB boundary keys
  __shared__ int      bi[1024];     // 4 KB boundary indices
  __shared__ unsigned au[40];
  __shared__ int      ai[40];
  __shared__ float    ew[32];
  __shared__ int      lsum[256], wsum[4];
  __shared__ int      sB, sNA, cA, cB;
  __shared__ float    sSum;

  const float* row = simT + (size_t)blockIdx.x * NMEM;
  const int pix = p0 + blockIdx.x;
  const int tid = threadIdx.x;

  // ---- per-thread exact top-4 over strided subset (ties: earlier idx wins)
  float t0 = -INFINITY, t1 = -INFINITY, t2 = -INFINITY, t3 = -INFINITY;
  int j0 = 0, j1 = 0, j2 = 0, j3 = 0;
  for (int i = tid; i < NMEM; i += 256) {
    float v = row[i];
    if (v > t3) {
      if (v > t1) {
        t3 = t2; j3 = j2; t2 = t1; j2 = j1;
        if (v > t0) { t1 = t0; j1 = j0; t0 = v; j0 = i; }
        else        { t1 = v;  j1 = i; }
      } else {
        t3 = t2; j3 = j2;
        if (v > t2) { t2 = v; j2 = i; }
        else        { t3 = v; j3 = i; }
      }
    }
  }
  pu[tid * 4 + 0] = fkey(t0); pidd[tid * 4 + 0] = j0;
  pu[tid * 4 + 1] = fkey(t1); pidd[tid * 4 + 1] = j1;
  pu[tid * 4 + 2] = fkey(t2); pidd[tid * 4 + 2] = j2;
  pu[tid * 4 + 3] = fkey(t3); pidd[tid * 4 + 3] = j3;

  for (int i = tid; i < BINS; i += 256) hist[i] = 0;
  if (tid == 0) { cA = 0; cB = 0; }
  __syncthreads();

  // ---- histogram over the 1024-candidate pool
  for (int i = tid; i < 1024; i += 256) atomicAdd(&hist[pu[i] >> 19], 1);
  __syncthreads();
  find_cross(hist, lsum, wsum, tid, TOPK, &sB, &sNA);

  {
    const int B = sB;
    for (int i = tid; i < 1024; i += 256) {
      unsigned u = pu[i];
      int bin = (int)(u >> 19);
      if (bin < B)       { int k = atomicAdd(&cA, 1); au[k] = u; ai[k] = pidd[i]; }
      else if (bin == B) { int k = atomicAdd(&cB, 1); bu[k] = u; bi[k] = pidd[i]; }
    }
    __syncthreads();
    const int nAv = cA, m = cB, need = TOPK - nAv;
    for (int t = tid; t < m; t += 256) {
      unsigned u = bu[t]; int id = bi[t];
      int r = 0;
      for (int j = 0; j < m; ++j) {
        unsigned uj = bu[j];
        r += (uj < u) || (uj == u && bi[j] < id);
      }
      if (r < need) { au[nAv + r] = u; ai[nAv + r] = id; }
    }
    __syncthreads();
  }

  // ---- verify: exactly 29 items globally must beat our 30th
  {
    unsigned u30 = au[TOPK - 1]; int i30 = ai[TOPK - 1];
    int cnt = 0;
    for (int i = tid; i < NMEM; i += 256) {
      unsigned u = fkey(row[i]);
      cnt += (u < u30) || (u == u30 && i < i30);
    }
    lsum[tid] = cnt;
    __syncthreads();
    for (int s = 128; s > 0; s >>= 1) {
      if (tid < s) lsum[tid] += lsum[tid + s];
      __syncthreads();
    }
  }
  const int nbetter = lsum[0];
  __syncthreads();

  if (nbetter > TOPK - 1) {
    // ---- exact fallback over all N (rare: pool missed a top-30 item)
    for (int i = tid; i < BINS; i += 256) hist[i] = 0;
    if (tid == 0) { cA = 0; cB = 0; }
    __syncthreads();
    for (int i = tid; i < NMEM; i += 256) atomicAdd(&hist[fkey(row[i]) >> 19], 1);
    __syncthreads();
    find_cross(hist, lsum, wsum, tid, TOPK, &sB, &sNA);
    const int B = sB;
    for (int i = tid; i < NMEM; i += 256) {
      unsigned u = fkey(row[i]);
      int bin = (int)(u >> 19);
      if (bin < B)       { int k = atomicAdd(&cA, 1); au[k] = u; ai[k] = i; }
      else if (bin == B) { int k = atomicAdd(&cB, 1); if (k < 1024) { bu[k] = u; bi[k] = i; } }
    }
    __syncthreads();
    const int nAv = cA, m = (cB < 1024 ? cB : 1024), need = TOPK - nAv;
    for (int t = tid; t < m; t += 256) {
      unsigned u = bu[t]; int id = bi[t];
      int r = 0;
      for (int j = 0; j < m; ++j) {
        unsigned uj = bu[j];
        r += (uj < u) || (uj == u && bi[j] < id);
      }
      if (r < need) { au[nAv + r] = u; ai[nAv + r] = id; }
    }
    __syncthreads();
  }

  // ---- softmax over the 30 selected (values <= 0: exp without max-sub, as ref)
  if (tid < TOPK) ew[tid] = expf(-__uint_as_float(au[tid]));
  __syncthreads();
  if (tid < 64) {
    float e = (tid < TOPK) ? ew[tid] : 0.f;
    #pragma unroll
    for (int off = 32; off > 0; off >>= 1) e += __shfl_down(e, off);
    if (tid == 0) sSum = e;
  }
  __syncthreads();
  if (tid < TOPK) {
    wgt [(size_t)pix * 32 + tid] = ew[tid] / sSum;
    widx[(size_t)pix * 32 + tid] = ai[tid];
  }
}

// ---------------------------------------------------------------------------
// Kernel 3: transpose mem_value rows [chbase..chbase+ld) -> mvT[N][ld]
// ---------------------------------------------------------------------------
__global__ __launch_bounds__(256)
void k_transpose(const float* __restrict__ mv, float* __restrict__ mvT,
                 int chbase, int ld)
{
  __shared__ float t[64][65];
  const int n0 = blockIdx.x * 64, ch0 = blockIdx.y * 64;
  const int tid = threadIdx.x;
  for (int i = tid; i < 64 * 16; i += 256) {
    int r = i >> 4, c4 = (i & 15) << 2;
    float4 v = *reinterpret_cast<const float4*>(
        &mv[(size_t)(chbase + ch0 + r) * NMEM + n0 + c4]);
    t[r][c4] = v.x; t[r][c4 + 1] = v.y; t[r][c4 + 2] = v.z; t[r][c4 + 3] = v.w;
  }
  __syncthreads();
  for (int i = tid; i < 64 * 16; i += 256) {
    int r = i >> 4, c4 = (i & 15) << 2;
    float4 v = make_float4(t[c4][r], t[c4 + 1][r], t[c4 + 2][r], t[c4 + 3][r]);
    *reinterpret_cast<float4*>(&mvT[(size_t)(n0 + r) * ld + ch0 + c4]) = v;
  }
}

// ---------------------------------------------------------------------------
// Kernel 4: out[ch][p] = sum_k w[p][k] * mvT[idx[p][k]][ch]
// ---------------------------------------------------------------------------
__global__ __launch_bounds__(256)
void k_gather(const float* __restrict__ mvT, const float* __restrict__ wgt,
              const int* __restrict__ widx, float* __restrict__ out,
              int chbase, int ld)
{
  __shared__ float sw[16][TOPK];
  __shared__ int   si[16][TOPK];
  __shared__ float sbuf[256][17];
  const int p0 = blockIdx.x * 16, chg = blockIdx.y * 256;
  const int tid = threadIdx.x;

  for (int i = tid; i < 16 * TOPK; i += 256) {
    int q = i / TOPK, k = i - q * TOPK;
    sw[q][k] = wgt [(size_t)(p0 + q) * 32 + k];
    si[q][k] = widx[(size_t)(p0 + q) * 32 + k];
  }
  __syncthreads();

  const int ch = chg + tid;
  #pragma unroll 2
  for (int q = 0; q < 16; ++q) {
    float a = 0.f;
    #pragma unroll
    for (int k = 0; k < TOPK; ++k)
      a = fmaf(sw[q][k], mvT[(size_t)si[q][k] * ld + ch], a);
    sbuf[tid][q] = a;
  }
  __syncthreads();

  for (int i = tid; i < 256 * 16; i += 256) {
    int cl = i >> 4, q = i & 15;
    out[(size_t)(chbase + chg + cl) * HW + p0 + q] = sbuf[cl][q];
  }
}

// ---------------------------------------------------------------------------
extern "C" void kernel_launch(void* const* d_in, const int* in_sizes, int n_in,
                              void* d_out, int out_size, void* d_ws, size_t ws_size,
                              hipStream_t stream)
{
  (void)in_sizes; (void)n_in; (void)out_size;
  const float* q_key     = (const float*)d_in[0];
  const float* q_sel     = (const float*)d_in[1];
  const float* mem_key   = (const float*)d_in[2];
  const float* mem_shr   = (const float*)d_in[3];
  const float* mem_value = (const float*)d_in[4];
  float* out = (float*)d_out;

  char* ws = (char*)d_ws;
  size_t off = 0;
  auto alloc = [&](size_t b) { size_t c = off; off = (off + b + 255) & ~(size_t)255; return c; };
  size_t o_w  = alloc((size_t)HW * 32 * 4);
  size_t o_wi = alloc((size_t)HW * 32 * 4);
  size_t o_big = off;

  const size_t simfull = (size_t)HW * NMEM * 4;      // 205.5 MB
  const size_t mvTfull = (size_t)NMEM * 1024 * 4;    // 117.4 MB
  size_t bigav = (ws_size > o_big) ? ws_size - o_big : 0;

  int nchunks, chld;
  if      (bigav >= simfull) { nchunks = 1; chld = 1024; }
  else if (bigav >= mvTfull) { nchunks = 2; chld = 1024; }  // sim half = 102.8 MB
  else                       { nchunks = 4; chld = 256;  }  // sim quarter = 51.4 MB

  float* big = (float*)(ws + o_big);   // sim chunks, later overlaid by mvT
  float* wg  = (float*)(ws + o_w);
  int*   wi  = (int*)  (ws + o_wi);

  const int PCH = HW / nchunks;
  for (int c = 0; c < nchunks; ++c) {
    int p0 = c * PCH;
    k_sim<<<dim3(NMEM / NT, PCH / 64), 256, 0, stream>>>(
        q_key, q_sel, mem_key, mem_shr, big, p0);
    k_select<<<dim3(PCH), 256, 0, stream>>>(big, wg, wi, p0);
  }
  for (int g = 0; g < 1024 / chld; ++g) {
    k_transpose<<<dim3(NMEM / 64, chld / 64), 256, 0, stream>>>(
        mem_value, big, g * chld, chld);
    k_gather<<<dim3(HW / 16, chld / 256), 256, 0, stream>>>(
        big, wg, wi, out, g * chld, chld);
  }
}

// Round 3
// 411.306 us; speedup vs baseline: 2.1934x; 1.2079x over previous
//
#include <hip/hip_runtime.h>
#include <math.h>

#define HW    1792
#define NMEM  28672
#define TOPK  30
#define CAND  48
#define BINS  4096

typedef __attribute__((ext_vector_type(8))) short bf16x8;
typedef __attribute__((ext_vector_type(8))) unsigned short u16x8;
typedef __attribute__((ext_vector_type(4))) float f32x4;

static __device__ __forceinline__ unsigned short f2bf(float v) {
  unsigned b = __float_as_uint(v);
  return (unsigned short)((b + 0x7FFFu + ((b >> 16) & 1u)) >> 16);
}
static __device__ __forceinline__ float bf2f(unsigned short h) {
  return __uint_as_float(((unsigned)h) << 16);
}
// key: larger v <-> smaller key
static __device__ __forceinline__ unsigned fkey(float v) {
  return __float_as_uint(-v) & 0x7FFFFFFFu;
}

// ---------------------------------------------------------------------------
// Prep B: Bh/Bl[n][cc] bf16 hi/lo, cc<64: mk[cc][n], cc>=64: mk[cc-64][n]^2.
// Also shr_s = mem_shr / 8.
// ---------------------------------------------------------------------------
__global__ __launch_bounds__(256)
void k_prep_b(const float* __restrict__ mk, const float* __restrict__ shr_in,
              unsigned short* __restrict__ Bh, unsigned short* __restrict__ Bl,
              float* __restrict__ shr_s)
{
  const int n = blockIdx.x * 256 + threadIdx.x;
  shr_s[n] = shr_in[n] * 0.125f;
  for (int cb = 0; cb < 64; cb += 8) {
    u16x8 h1, l1, h2, l2;
    #pragma unroll
    for (int j = 0; j < 8; ++j) {
      float v = mk[(size_t)(cb + j) * NMEM + n];
      unsigned short h = f2bf(v);
      h1[j] = h; l1[j] = f2bf(v - bf2f(h));
      float v2 = v * v;
      unsigned short g = f2bf(v2);
      h2[j] = g; l2[j] = f2bf(v2 - bf2f(g));
    }
    *reinterpret_cast<u16x8*>(&Bh[(size_t)n * 128 + cb])      = h1;
    *reinterpret_cast<u16x8*>(&Bl[(size_t)n * 128 + cb])      = l1;
    *reinterpret_cast<u16x8*>(&Bh[(size_t)n * 128 + 64 + cb]) = h2;
    *reinterpret_cast<u16x8*>(&Bl[(size_t)n * 128 + 64 + cb]) = l2;
  }
}

// ---------------------------------------------------------------------------
// Prep U: Uh/Ul[p][cc] bf16 hi/lo, cc<64: 2*qk*qs, cc>=64: -qs. Also bsq[p].
// ---------------------------------------------------------------------------
__global__ __launch_bounds__(256)
void k_prep_u(const float* __restrict__ q_key, const float* __restrict__ q_sel,
              unsigned short* __restrict__ Uh, unsigned short* __restrict__ Ul,
              float* __restrict__ bsq)
{
  const int p = blockIdx.x * 256 + threadIdx.x;
  float bs = 0.f;
  for (int cb = 0; cb < 64; cb += 8) {
    u16x8 h1, l1, h2, l2;
    #pragma unroll
    for (int j = 0; j < 8; ++j) {
      int c = cb + j;
      float k = q_key[(size_t)c * HW + p];
      float s = q_sel[(size_t)c * HW + p];
      float u = 2.f * k * s;
      float w = -s;
      bs = fmaf(s * k, k, bs);
      unsigned short h = f2bf(u); h1[j] = h; l1[j] = f2bf(u - bf2f(h));
      unsigned short g = f2bf(w); h2[j] = g; l2[j] = f2bf(w - bf2f(g));
    }
    *reinterpret_cast<u16x8*>(&Uh[(size_t)p * 128 + cb])      = h1;
    *reinterpret_cast<u16x8*>(&Ul[(size_t)p * 128 + cb])      = l1;
    *reinterpret_cast<u16x8*>(&Uh[(size_t)p * 128 + 64 + cb]) = h2;
    *reinterpret_cast<u16x8*>(&Ul[(size_t)p * 128 + 64 + cb]) = l2;
  }
  bsq[p] = bs;
}

// ---------------------------------------------------------------------------
// Kernel 1: MFMA sim GEMM -> simT[p][n] fp32.
// Block: 4 waves = 2x2, covers 64p x 256n. Wave: 32p x 128n = 2x8 MFMA tiles.
// 3-way bf16 split: hh + lh + hl (error ~3e-5 in sim).
// ---------------------------------------------------------------------------
__global__ __launch_bounds__(256)
void k_sim_mfma(const unsigned short* __restrict__ Uh, const unsigned short* __restrict__ Ul,
                const unsigned short* __restrict__ Bh, const unsigned short* __restrict__ Bl,
                const float* __restrict__ bsq, const float* __restrict__ shr_s,
                float* __restrict__ simT, int p0)
{
  const int tid = threadIdx.x;
  const int wid = tid >> 6, lane = tid & 63;
  const int lr = lane & 15, lg = lane >> 4;
  const int pl = blockIdx.x * 64 + (wid >> 1) * 32;   // chunk-local pixel base
  const int nw = blockIdx.y * 256 + (wid & 1) * 128;  // global n base
  const int pg = p0 + pl;                             // global pixel base

  f32x4 acc[2][8];
  #pragma unroll
  for (int a = 0; a < 2; ++a)
    #pragma unroll
    for (int b = 0; b < 8; ++b) acc[a][b] = (f32x4){0.f, 0.f, 0.f, 0.f};

  const size_t arow0 = (size_t)(pg + lr) * 128;
  const size_t arow1 = (size_t)(pg + 16 + lr) * 128;

  #pragma unroll
  for (int t = 0; t < 4; ++t) {
    const int ko = t * 32 + lg * 8;
    bf16x8 a0h = *reinterpret_cast<const bf16x8*>(&Uh[arow0 + ko]);
    bf16x8 a0l = *reinterpret_cast<const bf16x8*>(&Ul[arow0 + ko]);
    bf16x8 a1h = *reinterpret_cast<const bf16x8*>(&Uh[arow1 + ko]);
    bf16x8 a1l = *reinterpret_cast<const bf16x8*>(&Ul[arow1 + ko]);
    #pragma unroll
    for (int nt = 0; nt < 8; ++nt) {
      const size_t brow = (size_t)(nw + nt * 16 + lr) * 128 + ko;
      bf16x8 bh = *reinterpret_cast<const bf16x8*>(&Bh[brow]);
      bf16x8 bl = *reinterpret_cast<const bf16x8*>(&Bl[brow]);
      acc[0][nt] = __builtin_amdgcn_mfma_f32_16x16x32_bf16(a0h, bh, acc[0][nt], 0, 0, 0);
      acc[0][nt] = __builtin_amdgcn_mfma_f32_16x16x32_bf16(a0l, bh, acc[0][nt], 0, 0, 0);
      acc[0][nt] = __builtin_amdgcn_mfma_f32_16x16x32_bf16(a0h, bl, acc[0][nt], 0, 0, 0);
      acc[1][nt] = __builtin_amdgcn_mfma_f32_16x16x32_bf16(a1h, bh, acc[1][nt], 0, 0, 0);
      acc[1][nt] = __builtin_amdgcn_mfma_f32_16x16x32_bf16(a1l, bh, acc[1][nt], 0, 0, 0);
      acc[1][nt] = __builtin_amdgcn_mfma_f32_16x16x32_bf16(a1h, bl, acc[1][nt], 0, 0, 0);
    }
  }

  float shv[8];
  #pragma unroll
  for (int nt = 0; nt < 8; ++nt) shv[nt] = shr_s[nw + nt * 16 + lr];

  #pragma unroll
  for (int pt = 0; pt < 2; ++pt) {
    #pragma unroll
    for (int r = 0; r < 4; ++r) {
      const int pr = pt * 16 + 4 * lg + r;
      const float bq = bsq[pg + pr];
      float* orow = simT + (size_t)(pl + pr) * NMEM + nw;
      #pragma unroll
      for (int nt = 0; nt < 8; ++nt)
        orow[nt * 16 + lr] = (acc[pt][nt][r] - bq) * shv[nt];
    }
  }
}

// ---------------------------------------------------------------------------
// crossing finder: smallest bin B with prefix(<B) < target <= prefix(<=B)
// ---------------------------------------------------------------------------
__device__ __forceinline__ void find_cross(int* hist, int* lsum, int* wsum,
                                           int tid, int target, int* sB, int* sNA)
{
  const int base = tid * (BINS / 256);
  int ls = 0;
  #pragma unroll
  for (int k = 0; k < BINS / 256; ++k) ls += hist[base + k];
  lsum[tid] = ls;
  __syncthreads();
  int lane = tid & 63, wv = tid >> 6;
  int v = ls;
  #pragma unroll
  for (int off = 1; off < 64; off <<= 1) {
    int t = __shfl_up(v, off);
    if (lane >= off) v += t;
  }
  if (lane == 63) wsum[wv] = v;
  __syncthreads();
  int wo = 0;
  for (int k = 0; k < wv; ++k) wo += wsum[k];
  int run = wo + v - ls;
  #pragma unroll 1
  for (int k = 0; k < BINS / 256; ++k) {
    int h = hist[base + k];
    if (run < target && run + h >= target) { *sB = base + k; *sNA = run; }
    run += h;
  }
  __syncthreads();
}

#define INS8(v, ii)                                                         \
  if ((v) > t7) {                                                           \
    if ((v) > t3) {                                                         \
      t7=t6; j7=j6; t6=t5; j6=j5; t5=t4; j5=j4; t4=t3; j4=j3;               \
      if ((v) > t1) {                                                       \
        t3=t2; j3=j2; t2=t1; j2=j1;                                         \
        if ((v) > t0) { t1=t0; j1=j0; t0=(v); j0=(ii); }                    \
        else          { t1=(v); j1=(ii); }                                  \
      } else {                                                              \
        if ((v) > t2) { t3=t2; j3=j2; t2=(v); j2=(ii); }                    \
        else          { t3=(v); j3=(ii); }                                  \
      }                                                                     \
    } else {                                                                \
      if ((v) > t5) {                                                       \
        t7=t6; j7=j6; t6=t5; j6=j5;                                         \
        if ((v) > t4) { t5=t4; j5=j4; t4=(v); j4=(ii); }                    \
        else          { t5=(v); j5=(ii); }                                  \
      } else {                                                              \
        if ((v) > t6) { t7=t6; j7=j6; t6=(v); j6=(ii); }                    \
        else          { t7=(v); j7=(ii); }                                  \
      }                                                                     \
    }                                                                       \
  }

// ---------------------------------------------------------------------------
// Kernel 2: approx top-48 (pool + histogram + verify; exact-fallback), then
// exact fp32 recompute of the 48 sims, exact top-30 rank, softmax weights.
// ---------------------------------------------------------------------------
__global__ __launch_bounds__(256)
void k_select(const float* __restrict__ simT,
              const float* __restrict__ q_key, const float* __restrict__ q_sel,
              const float* __restrict__ mem_key, const float* __restrict__ shr_s,
              float* __restrict__ wgt, int* __restrict__ widx, int p0)
{
  __shared__ int      hist[BINS];    // 16 KB
  __shared__ unsigned pu[2048];      // 8 KB
  __shared__ int      pidd[2048];    // 8 KB
  __shared__ unsigned bu[2048];      // 8 KB
  __shared__ int      bi[2048];      // 8 KB
  __shared__ unsigned au[64];
  __shared__ int      ai[64];
  __shared__ float    sqk[64], sqs[64];
  __shared__ float    ev[64];
  __shared__ float    fv[32];
  __shared__ int      fi[32];
  __shared__ float    ew[32];
  __shared__ int      lsum[256], wsum[4];
  __shared__ int      sB, sNA, cA, cB;
  __shared__ float    sSum;

  const float*  row  = simT + (size_t)blockIdx.x * NMEM;
  const float4* row4 = reinterpret_cast<const float4*>(row);
  const int pix = p0 + blockIdx.x;
  const int tid = threadIdx.x;

  if (tid < 64) {
    sqk[tid] = q_key[(size_t)tid * HW + pix];
    sqs[tid] = q_sel[(size_t)tid * HW + pix];
  }

  // ---- per-thread exact top-8 over strided subset (float4 loads)
  float t0=-INFINITY,t1=-INFINITY,t2=-INFINITY,t3=-INFINITY,
        t4=-INFINITY,t5=-INFINITY,t6=-INFINITY,t7=-INFINITY;
  int j0=0,j1=0,j2=0,j3=0,j4=0,j5=0,j6=0,j7=0;
  for (int i = tid; i < NMEM / 4; i += 256) {
    float4 q = row4[i];
    int b = i * 4;
    INS8(q.x, b); INS8(q.y, b + 1); INS8(q.z, b + 2); INS8(q.w, b + 3);
  }
  pu[tid*8+0]=fkey(t0); pidd[tid*8+0]=j0;  pu[tid*8+1]=fkey(t1); pidd[tid*8+1]=j1;
  pu[tid*8+2]=fkey(t2); pidd[tid*8+2]=j2;  pu[tid*8+3]=fkey(t3); pidd[tid*8+3]=j3;
  pu[tid*8+4]=fkey(t4); pidd[tid*8+4]=j4;  pu[tid*8+5]=fkey(t5); pidd[tid*8+5]=j5;
  pu[tid*8+6]=fkey(t6); pidd[tid*8+6]=j6;  pu[tid*8+7]=fkey(t7); pidd[tid*8+7]=j7;

  for (int i = tid; i < BINS; i += 256) hist[i] = 0;
  if (tid == 0) { cA = 0; cB = 0; }
  __syncthreads();

  for (int i = tid; i < 2048; i += 256) atomicAdd(&hist[pu[i] >> 19], 1);
  __syncthreads();
  find_cross(hist, lsum, wsum, tid, CAND, &sB, &sNA);

  {
    const int B = sB;
    for (int i = tid; i < 2048; i += 256) {
      unsigned u = pu[i];
      int bin = (int)(u >> 19);
      if (bin < B)       { int k = atomicAdd(&cA, 1); au[k] = u; ai[k] = pidd[i]; }
      else if (bin == B) { int k = atomicAdd(&cB, 1); bu[k] = u; bi[k] = pidd[i]; }
    }
    __syncthreads();
    const int nAv = cA, m = cB, need = CAND - nAv;
    for (int t = tid; t < m; t += 256) {
      unsigned u = bu[t]; int id = bi[t];
      int r = 0;
      for (int k = 0; k < m; ++k) {
        unsigned uk = bu[k];
        r += (uk < u) || (uk == u && bi[k] < id);
      }
      if (r < need) { au[nAv + r] = u; ai[nAv + r] = id; }
    }
    __syncthreads();
  }

  // ---- verify pool adequacy: exactly CAND-1 items beat our 48th
  {
    unsigned u48 = au[CAND - 1]; int i48 = ai[CAND - 1];
    int cnt = 0;
    for (int i = tid; i < NMEM / 4; i += 256) {
      float4 q = row4[i];
      int b = i * 4;
      unsigned ux = fkey(q.x), uy = fkey(q.y), uz = fkey(q.z), uw = fkey(q.w);
      cnt += (ux < u48) || (ux == u48 && b     < i48);
      cnt += (uy < u48) || (uy == u48 && b + 1 < i48);
      cnt += (uz < u48) || (uz == u48 && b + 2 < i48);
      cnt += (uw < u48) || (uw == u48 && b + 3 < i48);
    }
    lsum[tid] = cnt;
    __syncthreads();
    for (int s = 128; s > 0; s >>= 1) {
      if (tid < s) lsum[tid] += lsum[tid + s];
      __syncthreads();
    }
  }
  const int nbetter = lsum[0];
  __syncthreads();

  if (nbetter != CAND - 1) {
    // ---- exact-over-approx fallback: full-row histogram select (rare)
    for (int i = tid; i < BINS; i += 256) hist[i] = 0;
    if (tid == 0) { cA = 0; cB = 0; }
    __syncthreads();
    for (int i = tid; i < NMEM; i += 256) atomicAdd(&hist[fkey(row[i]) >> 19], 1);
    __syncthreads();
    find_cross(hist, lsum, wsum, tid, CAND, &sB, &sNA);
    const int B = sB;
    for (int i = tid; i < NMEM; i += 256) {
      unsigned u = fkey(row[i]);
      int bin = (int)(u >> 19);
      if (bin < B)       { int k = atomicAdd(&cA, 1); au[k] = u; ai[k] = i; }
      else if (bin == B) { int k = atomicAdd(&cB, 1); if (k < 2048) { bu[k] = u; bi[k] = i; } }
    }
    __syncthreads();
    const int nAv = cA, m = (cB < 2048 ? cB : 2048), need = CAND - nAv;
    for (int t = tid; t < m; t += 256) {
      unsigned u = bu[t]; int id = bi[t];
      int r = 0;
      for (int k = 0; k < m; ++k) {
        unsigned uk = bu[k];
        r += (uk < u) || (uk == u && bi[k] < id);
      }
      if (r < need) { au[nAv + r] = u; ai[nAv + r] = id; }
    }
    __syncthreads();
  }

  // ---- exact fp32 recompute of the 48 candidate sims: -sum qs*(mk-qk)^2 * shr/8
  if (tid < CAND * 4) {
    int id = ai[tid >> 2];
    float s = 0.f;
    const int c0 = (tid & 3) * 16;
    #pragma unroll
    for (int j = 0; j < 16; ++j) {
      int c = c0 + j;
      float d = mem_key[(size_t)c * NMEM + id] - sqk[c];
      s = fmaf(sqs[c] * d, d, s);
    }
    s += __shfl_xor(s, 1);
    s += __shfl_xor(s, 2);
    if ((tid & 3) == 0) ev[tid >> 2] = -s * shr_s[id];
  }
  __syncthreads();

  // ---- exact top-30 by rank among the 48
  if (tid < CAND) {
    float v = ev[tid]; int id = ai[tid];
    int r = 0;
    for (int k = 0; k < CAND; ++k) {
      float vk = ev[k];
      r += (vk > v) || (vk == v && ai[k] < id);
    }
    if (r < TOPK) { fv[r] = v; fi[r] = id; }
  }
  __syncthreads();

  // ---- softmax (values <= 0; exp without max-sub, matching ref)
  if (tid < 32) {
    float e = (tid < TOPK) ? expf(fv[tid]) : 0.f;
    if (tid < TOPK) ew[tid] = e;
    float ssum = e;
    #pragma unroll
    for (int off = 16; off > 0; off >>= 1) ssum += __shfl_down(ssum, off);
    if (tid == 0) sSum = ssum;
  }
  __syncthreads();
  if (tid < TOPK) {
    wgt [(size_t)pix * 32 + tid] = ew[tid] / sSum;
    widx[(size_t)pix * 32 + tid] = fi[tid];
  }
}

// ---------------------------------------------------------------------------
// Kernel 3: transpose mem_value rows [chbase..chbase+ld) -> mvT[N][ld]
// ---------------------------------------------------------------------------
__global__ __launch_bounds__(256)
void k_transpose(const float* __restrict__ mv, float* __restrict__ mvT,
                 int chbase, int ld)
{
  __shared__ float t[64][65];
  const int n0 = blockIdx.x * 64, ch0 = blockIdx.y * 64;
  const int tid = threadIdx.x;
  for (int i = tid; i < 64 * 16; i += 256) {
    int r = i >> 4, c4 = (i & 15) << 2;
    float4 v = *reinterpret_cast<const float4*>(
        &mv[(size_t)(chbase + ch0 + r) * NMEM + n0 + c4]);
    t[r][c4] = v.x; t[r][c4 + 1] = v.y; t[r][c4 + 2] = v.z; t[r][c4 + 3] = v.w;
  }
  __syncthreads();
  for (int i = tid; i < 64 * 16; i += 256) {
    int r = i >> 4, c4 = (i & 15) << 2;
    float4 v = make_float4(t[c4][r], t[c4 + 1][r], t[c4 + 2][r], t[c4 + 3][r]);
    *reinterpret_cast<float4*>(&mvT[(size_t)(n0 + r) * ld + ch0 + c4]) = v;
  }
}

// ---------------------------------------------------------------------------
// Kernel 4: out[ch][p] = sum_k w[p][k] * mvT[idx[p][k]][ch]
// ---------------------------------------------------------------------------
__global__ __launch_bounds__(256)
void k_gather(const float* __restrict__ mvT, const float* __restrict__ wgt,
              const int* __restrict__ widx, float* __restrict__ out,
              int chbase, int ld)
{
  __shared__ float sw[16][TOPK];
  __shared__ int   si[16][TOPK];
  __shared__ float sbuf[256][17];
  const int p0 = blockIdx.x * 16, chg = blockIdx.y * 256;
  const int tid = threadIdx.x;

  for (int i = tid; i < 16 * TOPK; i += 256) {
    int q = i / TOPK, k = i - q * TOPK;
    sw[q][k] = wgt [(size_t)(p0 + q) * 32 + k];
    si[q][k] = widx[(size_t)(p0 + q) * 32 + k];
  }
  __syncthreads();

  const int ch = chg + tid;
  #pragma unroll 2
  for (int q = 0; q < 16; ++q) {
    float a = 0.f;
    #pragma unroll
    for (int k = 0; k < TOPK; ++k)
      a = fmaf(sw[q][k], mvT[(size_t)si[q][k] * ld + ch], a);
    sbuf[tid][q] = a;
  }
  __syncthreads();

  for (int i = tid; i < 256 * 16; i += 256) {
    int cl = i >> 4, q = i & 15;
    out[(size_t)(chbase + chg + cl) * HW + p0 + q] = sbuf[cl][q];
  }
}

// ---------------------------------------------------------------------------
extern "C" void kernel_launch(void* const* d_in, const int* in_sizes, int n_in,
                              void* d_out, int out_size, void* d_ws, size_t ws_size,
                              hipStream_t stream)
{
  (void)in_sizes; (void)n_in; (void)out_size;
  const float* q_key     = (const float*)d_in[0];
  const float* q_sel     = (const float*)d_in[1];
  const float* mem_key   = (const float*)d_in[2];
  const float* mem_shr   = (const float*)d_in[3];
  const float* mem_value = (const float*)d_in[4];
  float* out = (float*)d_out;

  char* ws = (char*)d_ws;
  size_t off = 0;
  auto alloc = [&](size_t b) { size_t c = off; off = (off + b + 255) & ~(size_t)255; return c; };
  size_t o_w   = alloc((size_t)HW * 32 * 4);
  size_t o_wi  = alloc((size_t)HW * 32 * 4);
  size_t o_bh  = alloc((size_t)NMEM * 128 * 2);   // 7.34 MB
  size_t o_bl  = alloc((size_t)NMEM * 128 * 2);   // 7.34 MB
  size_t o_uh  = alloc((size_t)HW * 128 * 2);     // 0.46 MB
  size_t o_ul  = alloc((size_t)HW * 128 * 2);     // 0.46 MB
  size_t o_bsq = alloc((size_t)HW * 4);
  size_t o_shr = alloc((size_t)NMEM * 4);
  size_t o_big = off;

  const size_t simfull = (size_t)HW * NMEM * 4;   // 205.5 MB
  const size_t mvTfull = (size_t)NMEM * 1024 * 4; // 117.4 MB
  size_t bigav = (ws_size > o_big) ? ws_size - o_big : 0;

  int nchunks, chld;
  if      (bigav >= simfull) { nchunks = 1; chld = 1024; }
  else if (bigav >= mvTfull) { nchunks = 2; chld = 1024; }
  else                       { nchunks = 4; chld = 256;  }

  float*          wg  = (float*)(ws + o_w);
  int*            wi  = (int*)  (ws + o_wi);
  unsigned short* Bh  = (unsigned short*)(ws + o_bh);
  unsigned short* Bl  = (unsigned short*)(ws + o_bl);
  unsigned short* Uh  = (unsigned short*)(ws + o_uh);
  unsigned short* Ul  = (unsigned short*)(ws + o_ul);
  float*          bsq = (float*)(ws + o_bsq);
  float*          shr = (float*)(ws + o_shr);
  float*          big = (float*)(ws + o_big);     // simT chunks, later mvT

  k_prep_b<<<NMEM / 256, 256, 0, stream>>>(mem_key, mem_shr, Bh, Bl, shr);
  k_prep_u<<<HW / 256, 256, 0, stream>>>(q_key, q_sel, Uh, Ul, bsq);

  const int PCH = HW / nchunks;
  for (int c = 0; c < nchunks; ++c) {
    int p0 = c * PCH;
    k_sim_mfma<<<dim3(PCH / 64, NMEM / 256), 256, 0, stream>>>(
        Uh, Ul, Bh, Bl, bsq, shr, big, p0);
    k_select<<<dim3(PCH), 256, 0, stream>>>(
        big, q_key, q_sel, mem_key, shr, wg, wi, p0);
  }
  for (int g = 0; g < 1024 / chld; ++g) {
    k_transpose<<<dim3(NMEM / 64, chld / 64), 256, 0, stream>>>(
        mem_value, big, g * chld, chld);
    k_gather<<<dim3(HW / 16, chld / 256), 256, 0, stream>>>(
        big, wg, wi, out, g * chld, chld);
  }
}

// Round 4
// 320.287 us; speedup vs baseline: 2.8167x; 1.2842x over previous
//
#include <hip/hip_runtime.h>
#include <math.h>

#define HW      1792
#define NMEM    28672
#define NCHUNK  3584          // NMEM/8 chunks of 8 (per-lane nt groups)
#define TOPK    30
#define CTARGET 48
#define BINS    4096
#define VCACHE  3072

typedef __attribute__((ext_vector_type(8))) short bf16x8;
typedef __attribute__((ext_vector_type(8))) unsigned short u16x8;
typedef __attribute__((ext_vector_type(4))) float f32x4;

static __device__ __forceinline__ unsigned short f2bf(float v) {
  unsigned b = __float_as_uint(v);
  return (unsigned short)((b + 0x7FFFu + ((b >> 16) & 1u)) >> 16);
}
static __device__ __forceinline__ float bf2f(unsigned short h) {
  return __uint_as_float(((unsigned)h) << 16);
}
// key: larger v <-> smaller key (v <= 0)
static __device__ __forceinline__ unsigned fkey(float v) {
  return __float_as_uint(-v) & 0x7FFFFFFFu;
}

// ---------------------------------------------------------------------------
// Prep B: Bh/Bl[n][cc] bf16 hi/lo (cc<64: mk, cc>=64: mk^2); mkT[n][64] fp32;
// shr_s = mem_shr / 8.
// ---------------------------------------------------------------------------
__global__ __launch_bounds__(256)
void k_prep_b(const float* __restrict__ mk, const float* __restrict__ shr_in,
              unsigned short* __restrict__ Bh, unsigned short* __restrict__ Bl,
              float* __restrict__ mkT, float* __restrict__ shr_s)
{
  const int n = blockIdx.x * 256 + threadIdx.x;
  shr_s[n] = shr_in[n] * 0.125f;
  for (int cb = 0; cb < 64; cb += 8) {
    u16x8 h1, l1, h2, l2;
    float vv[8];
    #pragma unroll
    for (int j = 0; j < 8; ++j) {
      float v = mk[(size_t)(cb + j) * NMEM + n];
      vv[j] = v;
      unsigned short h = f2bf(v);
      h1[j] = h; l1[j] = f2bf(v - bf2f(h));
      float v2 = v * v;
      unsigned short g = f2bf(v2);
      h2[j] = g; l2[j] = f2bf(v2 - bf2f(g));
    }
    *reinterpret_cast<u16x8*>(&Bh[(size_t)n * 128 + cb])      = h1;
    *reinterpret_cast<u16x8*>(&Bl[(size_t)n * 128 + cb])      = l1;
    *reinterpret_cast<u16x8*>(&Bh[(size_t)n * 128 + 64 + cb]) = h2;
    *reinterpret_cast<u16x8*>(&Bl[(size_t)n * 128 + 64 + cb]) = l2;
    *reinterpret_cast<float4*>(&mkT[(size_t)n * 64 + cb])     = make_float4(vv[0], vv[1], vv[2], vv[3]);
    *reinterpret_cast<float4*>(&mkT[(size_t)n * 64 + cb + 4]) = make_float4(vv[4], vv[5], vv[6], vv[7]);
  }
}

// ---------------------------------------------------------------------------
// Prep U: Uh/Ul[p][cc] bf16 hi/lo (cc<64: 2*qk*qs, cc>=64: -qs); bsq[p].
// ---------------------------------------------------------------------------
__global__ __launch_bounds__(256)
void k_prep_u(const float* __restrict__ q_key, const float* __restrict__ q_sel,
              unsigned short* __restrict__ Uh, unsigned short* __restrict__ Ul,
              float* __restrict__ bsq)
{
  const int p = blockIdx.x * 256 + threadIdx.x;
  float bs = 0.f;
  for (int cb = 0; cb < 64; cb += 8) {
    u16x8 h1, l1, h2, l2;
    #pragma unroll
    for (int j = 0; j < 8; ++j) {
      int c = cb + j;
      float k = q_key[(size_t)c * HW + p];
      float s = q_sel[(size_t)c * HW + p];
      float u = 2.f * k * s;
      float w = -s;
      bs = fmaf(s * k, k, bs);
      unsigned short h = f2bf(u); h1[j] = h; l1[j] = f2bf(u - bf2f(h));
      unsigned short g = f2bf(w); h2[j] = g; l2[j] = f2bf(w - bf2f(g));
    }
    *reinterpret_cast<u16x8*>(&Uh[(size_t)p * 128 + cb])      = h1;
    *reinterpret_cast<u16x8*>(&Ul[(size_t)p * 128 + cb])      = l1;
    *reinterpret_cast<u16x8*>(&Uh[(size_t)p * 128 + 64 + cb]) = h2;
    *reinterpret_cast<u16x8*>(&Ul[(size_t)p * 128 + 64 + cb]) = l2;
  }
  bsq[p] = bs;
}

// ---------------------------------------------------------------------------
// Kernel 1: MFMA sim GEMM -> per-(pixel, 8-n-chunk) maxima only (no simT).
// Block: 4 waves = 2x2 covering 64p x 256n. Wave: 32p x 128n = one n-window.
// Chunk c = w*16 + lr holds n = w*128 + lr + 16*t, t=0..7 (per-lane max, no shfl).
// ---------------------------------------------------------------------------
__global__ __launch_bounds__(256)
void k_sim_max(const unsigned short* __restrict__ Uh, const unsigned short* __restrict__ Ul,
               const unsigned short* __restrict__ Bh, const unsigned short* __restrict__ Bl,
               const float* __restrict__ bsq, const float* __restrict__ shr_s,
               float* __restrict__ pmax)
{
  const int tid = threadIdx.x;
  const int wid = tid >> 6, lane = tid & 63;
  const int lr = lane & 15, lg = lane >> 4;
  const int pw = blockIdx.x * 64 + (wid >> 1) * 32;   // wave pixel base
  const int w  = blockIdx.y * 2 + (wid & 1);          // 128-n window id
  const int nw = w * 128;

  f32x4 acc[2][8];
  #pragma unroll
  for (int a = 0; a < 2; ++a)
    #pragma unroll
    for (int b = 0; b < 8; ++b) acc[a][b] = (f32x4){0.f, 0.f, 0.f, 0.f};

  const size_t arow0 = (size_t)(pw + lr) * 128;
  const size_t arow1 = (size_t)(pw + 16 + lr) * 128;

  #pragma unroll
  for (int t = 0; t < 4; ++t) {
    const int ko = t * 32 + lg * 8;
    bf16x8 a0h = *reinterpret_cast<const bf16x8*>(&Uh[arow0 + ko]);
    bf16x8 a0l = *reinterpret_cast<const bf16x8*>(&Ul[arow0 + ko]);
    bf16x8 a1h = *reinterpret_cast<const bf16x8*>(&Uh[arow1 + ko]);
    bf16x8 a1l = *reinterpret_cast<const bf16x8*>(&Ul[arow1 + ko]);
    #pragma unroll
    for (int nt = 0; nt < 8; ++nt) {
      const size_t brow = (size_t)(nw + nt * 16 + lr) * 128 + ko;
      bf16x8 bh = *reinterpret_cast<const bf16x8*>(&Bh[brow]);
      bf16x8 bl = *reinterpret_cast<const bf16x8*>(&Bl[brow]);
      acc[0][nt] = __builtin_amdgcn_mfma_f32_16x16x32_bf16(a0h, bh, acc[0][nt], 0, 0, 0);
      acc[0][nt] = __builtin_amdgcn_mfma_f32_16x16x32_bf16(a0l, bh, acc[0][nt], 0, 0, 0);
      acc[0][nt] = __builtin_amdgcn_mfma_f32_16x16x32_bf16(a0h, bl, acc[0][nt], 0, 0, 0);
      acc[1][nt] = __builtin_amdgcn_mfma_f32_16x16x32_bf16(a1h, bh, acc[1][nt], 0, 0, 0);
      acc[1][nt] = __builtin_amdgcn_mfma_f32_16x16x32_bf16(a1l, bh, acc[1][nt], 0, 0, 0);
      acc[1][nt] = __builtin_amdgcn_mfma_f32_16x16x32_bf16(a1h, bl, acc[1][nt], 0, 0, 0);
    }
  }

  float shv[8];
  #pragma unroll
  for (int nt = 0; nt < 8; ++nt) shv[nt] = shr_s[nw + nt * 16 + lr];

  #pragma unroll
  for (int pt = 0; pt < 2; ++pt) {
    #pragma unroll
    for (int r = 0; r < 4; ++r) {
      const int p = pw + pt * 16 + 4 * lg + r;
      const float bq = bsq[p];
      float mx = -INFINITY;
      #pragma unroll
      for (int nt = 0; nt < 8; ++nt)
        mx = fmaxf(mx, (acc[pt][nt][r] - bq) * shv[nt]);
      pmax[(size_t)p * NCHUNK + w * 16 + lr] = mx;
    }
  }
}

// ---------------------------------------------------------------------------
// crossing finder: smallest bin B with prefix(<B) < target <= prefix(<=B)
// ---------------------------------------------------------------------------
__device__ __forceinline__ void find_cross(int* hist, int* lsum, int* wsum,
                                           int tid, int target, int* sB, int* sNA)
{
  const int base = tid * (BINS / 256);
  int ls = 0;
  #pragma unroll
  for (int k = 0; k < BINS / 256; ++k) ls += hist[base + k];
  lsum[tid] = ls;
  __syncthreads();
  int lane = tid & 63, wv = tid >> 6;
  int v = ls;
  #pragma unroll
  for (int off = 1; off < 64; off <<= 1) {
    int t = __shfl_up(v, off);
    if (lane >= off) v += t;
  }
  if (lane == 63) wsum[wv] = v;
  __syncthreads();
  int wo = 0;
  for (int k = 0; k < wv; ++k) wo += wsum[k];
  int run = wo + v - ls;
  #pragma unroll 1
  for (int k = 0; k < BINS / 256; ++k) {
    int h = hist[base + k];
    if (run < target && run + h >= target) { *sB = base + k; *sNA = run; }
    run += h;
  }
  __syncthreads();
}

// ---------------------------------------------------------------------------
// Kernel 2: per-pixel exact top-30 via chunk-max pruning + exact recompute.
// ---------------------------------------------------------------------------
__global__ __launch_bounds__(256)
void k_select(const float* __restrict__ pmax, const float* __restrict__ mkT,
              const float* __restrict__ q_key, const float* __restrict__ q_sel,
              const float* __restrict__ shr_s,
              float* __restrict__ wgt, int* __restrict__ widx)
{
  __shared__ int            hist[BINS];       // 16 KB
  __shared__ float          sqk[64], sqs[64];
  __shared__ unsigned short chl[NCHUNK];      // 7 KB survivor chunks
  __shared__ float          vcache[VCACHE];   // 12 KB
  __shared__ unsigned       au[64];
  __shared__ int            ai[64];
  __shared__ unsigned       bu[1024];         // 4 KB
  __shared__ int            bi[1024];         // 4 KB
  __shared__ float          fv[32];
  __shared__ int            fi[32];
  __shared__ float          ew[32];
  __shared__ int            lsum[256], wsum[4];
  __shared__ int            sB, sNA, cA, cB, sSC;
  __shared__ float          sSum;

  const int pix = blockIdx.x;
  const int tid = threadIdx.x;

  if (tid < 64) {
    sqk[tid] = q_key[(size_t)tid * HW + pix];
    sqs[tid] = q_sel[(size_t)tid * HW + pix];
  }
  for (int i = tid; i < BINS; i += 256) hist[i] = 0;
  if (tid == 0) { sSC = 0; cA = 0; cB = 0; }
  __syncthreads();

  // ---- stage 1: chunk maxima -> 48-crossing bin -> survivor chunks
  float m[NCHUNK / 256];
  const float* pm = pmax + (size_t)pix * NCHUNK;
  #pragma unroll
  for (int j = 0; j < NCHUNK / 256; ++j) m[j] = pm[tid + 256 * j];
  #pragma unroll
  for (int j = 0; j < NCHUNK / 256; ++j) atomicAdd(&hist[fkey(m[j]) >> 19], 1);
  __syncthreads();
  find_cross(hist, lsum, wsum, tid, CTARGET, &sB, &sNA);
  {
    const int B = sB;
    #pragma unroll
    for (int j = 0; j < NCHUNK / 256; ++j)
      if ((int)(fkey(m[j]) >> 19) <= B) {
        int k = atomicAdd(&sSC, 1);
        chl[k] = (unsigned short)(tid + 256 * j);
      }
  }
  __syncthreads();
  const int SC = sSC, NC = SC * 8;
  for (int i = tid; i < BINS; i += 256) hist[i] = 0;
  __syncthreads();

  const float4* sqk4 = reinterpret_cast<const float4*>(sqk);
  const float4* sqs4 = reinterpret_cast<const float4*>(sqs);

  // ---- stage 2 pass X: exact fp32 sims of candidates + histogram
  for (int c = tid; c < NC; c += 256) {
    const int cc = chl[c >> 3];
    const int n = ((cc >> 4) << 7) + (cc & 15) + ((c & 7) << 4);
    const float4* mr = reinterpret_cast<const float4*>(mkT + (size_t)n * 64);
    float s = 0.f;
    #pragma unroll
    for (int j = 0; j < 16; ++j) {
      float4 q = mr[j], k4 = sqk4[j], s4 = sqs4[j];
      float d0 = q.x - k4.x, d1 = q.y - k4.y, d2 = q.z - k4.z, d3 = q.w - k4.w;
      s = fmaf(s4.x * d0, d0, s); s = fmaf(s4.y * d1, d1, s);
      s = fmaf(s4.z * d2, d2, s); s = fmaf(s4.w * d3, d3, s);
    }
    float v = -s * shr_s[n];
    if (c < VCACHE) vcache[c] = v;
    atomicAdd(&hist[fkey(v) >> 19], 1);
  }
  __syncthreads();
  find_cross(hist, lsum, wsum, tid, TOPK, &sB, &sNA);

  // ---- stage 2 pass Y: collect top-30 (bins < B2) + boundary rank-cut
  {
    const int B2 = sB;
    for (int c = tid; c < NC; c += 256) {
      const int cc = chl[c >> 3];
      const int n = ((cc >> 4) << 7) + (cc & 15) + ((c & 7) << 4);
      float v;
      if (c < VCACHE) v = vcache[c];
      else {
        const float4* mr = reinterpret_cast<const float4*>(mkT + (size_t)n * 64);
        float s = 0.f;
        #pragma unroll
        for (int j = 0; j < 16; ++j) {
          float4 q = mr[j], k4 = sqk4[j], s4 = sqs4[j];
          float d0 = q.x - k4.x, d1 = q.y - k4.y, d2 = q.z - k4.z, d3 = q.w - k4.w;
          s = fmaf(s4.x * d0, d0, s); s = fmaf(s4.y * d1, d1, s);
          s = fmaf(s4.z * d2, d2, s); s = fmaf(s4.w * d3, d3, s);
        }
        v = -s * shr_s[n];
      }
      unsigned u = fkey(v);
      int bin = (int)(u >> 19);
      if (bin < sB)       { int k = atomicAdd(&cA, 1); au[k] = u; ai[k] = n; }
      else if (bin == B2) { int k = atomicAdd(&cB, 1); if (k < 1024) { bu[k] = u; bi[k] = n; } }
    }
  }
  __syncthreads();
  {
    const int nAv = cA, mm = (cB < 1024 ? cB : 1024), need = TOPK - nAv;
    for (int t = tid; t < mm; t += 256) {
      unsigned u = bu[t]; int id = bi[t];
      int r = 0;
      for (int k2 = 0; k2 < mm; ++k2) {
        unsigned uk = bu[k2];
        r += (uk < u) || (uk == u && bi[k2] < id);
      }
      if (r < need) { au[nAv + r] = u; ai[nAv + r] = id; }
    }
  }
  __syncthreads();

  // ---- deterministic ordering of the 30 + softmax
  if (tid < TOPK) {
    unsigned u = au[tid]; int id = ai[tid];
    int r = 0;
    for (int k2 = 0; k2 < TOPK; ++k2) {
      unsigned uk = au[k2];
      r += (uk < u) || (uk == u && ai[k2] < id);
    }
    fv[r] = -__uint_as_float(u); fi[r] = id;
  }
  __syncthreads();
  if (tid < 32) {
    float e = (tid < TOPK) ? expf(fv[tid]) : 0.f;
    if (tid < TOPK) ew[tid] = e;
    float ss = e;
    #pragma unroll
    for (int off = 16; off > 0; off >>= 1) ss += __shfl_down(ss, off);
    if (tid == 0) sSum = ss;
  }
  __syncthreads();
  if (tid < TOPK) {
    wgt [(size_t)pix * 32 + tid] = ew[tid] / sSum;
    widx[(size_t)pix * 32 + tid] = fi[tid];
  }
}

// ---------------------------------------------------------------------------
// Kernel 3: transpose mem_value rows [chbase..chbase+ld) -> mvT[N][ld]
// ---------------------------------------------------------------------------
__global__ __launch_bounds__(256)
void k_transpose(const float* __restrict__ mv, float* __restrict__ mvT,
                 int chbase, int ld)
{
  __shared__ float t[64][65];
  const int n0 = blockIdx.x * 64, ch0 = blockIdx.y * 64;
  const int tid = threadIdx.x;
  for (int i = tid; i < 64 * 16; i += 256) {
    int r = i >> 4, c4 = (i & 15) << 2;
    float4 v = *reinterpret_cast<const float4*>(
        &mv[(size_t)(chbase + ch0 + r) * NMEM + n0 + c4]);
    t[r][c4] = v.x; t[r][c4 + 1] = v.y; t[r][c4 + 2] = v.z; t[r][c4 + 3] = v.w;
  }
  __syncthreads();
  for (int i = tid; i < 64 * 16; i += 256) {
    int r = i >> 4, c4 = (i & 15) << 2;
    float4 v = make_float4(t[c4][r], t[c4 + 1][r], t[c4 + 2][r], t[c4 + 3][r]);
    *reinterpret_cast<float4*>(&mvT[(size_t)(n0 + r) * ld + ch0 + c4]) = v;
  }
}

// ---------------------------------------------------------------------------
// Kernel 4: out[out_chbase+ch][p] = sum_k w[p][k] * src[...]
// src addr = idx*n_stride + (src_chbase+ch)*ch_stride
// ---------------------------------------------------------------------------
__global__ __launch_bounds__(256)
void k_gather(const float* __restrict__ src, const float* __restrict__ wgt,
              const int* __restrict__ widx, float* __restrict__ out,
              int out_chbase, int src_chbase, long n_stride, long ch_stride)
{
  __shared__ float sw[16][TOPK];
  __shared__ int   si[16][TOPK];
  __shared__ float sbuf[256][17];
  const int p0 = blockIdx.x * 16, chg = blockIdx.y * 256;
  const int tid = threadIdx.x;

  for (int i = tid; i < 16 * TOPK; i += 256) {
    int q = i / TOPK, k = i - q * TOPK;
    sw[q][k] = wgt [(size_t)(p0 + q) * 32 + k];
    si[q][k] = widx[(size_t)(p0 + q) * 32 + k];
  }
  __syncthreads();

  const int ch = chg + tid;
  #pragma unroll 2
  for (int q = 0; q < 16; ++q) {
    float a = 0.f;
    #pragma unroll
    for (int k = 0; k < TOPK; ++k)
      a = fmaf(sw[q][k], src[(size_t)si[q][k] * n_stride +
                             (size_t)(src_chbase + ch) * ch_stride], a);
    sbuf[tid][q] = a;
  }
  __syncthreads();

  for (int i = tid; i < 256 * 16; i += 256) {
    int cl = i >> 4, q = i & 15;
    out[(size_t)(out_chbase + chg + cl) * HW + p0 + q] = sbuf[cl][q];
  }
}

// ---------------------------------------------------------------------------
extern "C" void kernel_launch(void* const* d_in, const int* in_sizes, int n_in,
                              void* d_out, int out_size, void* d_ws, size_t ws_size,
                              hipStream_t stream)
{
  (void)in_sizes; (void)n_in; (void)out_size;
  const float* q_key     = (const float*)d_in[0];
  const float* q_sel     = (const float*)d_in[1];
  const float* mem_key   = (const float*)d_in[2];
  const float* mem_shr   = (const float*)d_in[3];
  const float* mem_value = (const float*)d_in[4];
  float* out = (float*)d_out;

  char* ws = (char*)d_ws;
  size_t off = 0;
  auto alloc = [&](size_t b) { size_t c = off; off = (off + b + 255) & ~(size_t)255; return c; };
  size_t o_w   = alloc((size_t)HW * 32 * 4);
  size_t o_wi  = alloc((size_t)HW * 32 * 4);
  size_t o_pr  = off;                              // overlay point for mvT
  size_t o_bh  = alloc((size_t)NMEM * 128 * 2);    // 7.34 MB
  size_t o_bl  = alloc((size_t)NMEM * 128 * 2);    // 7.34 MB
  size_t o_uh  = alloc((size_t)HW * 128 * 2);
  size_t o_ul  = alloc((size_t)HW * 128 * 2);
  size_t o_bsq = alloc((size_t)HW * 4);
  size_t o_shr = alloc((size_t)NMEM * 4);
  size_t o_mkT = alloc((size_t)NMEM * 64 * 4);     // 7.34 MB
  size_t o_pm  = alloc((size_t)HW * NCHUNK * 4);   // 25.7 MB
  size_t o_end = off;

  float*          wg   = (float*)(ws + o_w);
  int*            wi   = (int*)  (ws + o_wi);
  unsigned short* Bh   = (unsigned short*)(ws + o_bh);
  unsigned short* Bl   = (unsigned short*)(ws + o_bl);
  unsigned short* Uh   = (unsigned short*)(ws + o_uh);
  unsigned short* Ul   = (unsigned short*)(ws + o_ul);
  float*          bsq  = (float*)(ws + o_bsq);
  float*          shr  = (float*)(ws + o_shr);
  float*          mkT  = (float*)(ws + o_mkT);
  float*          pmx  = (float*)(ws + o_pm);

  const size_t mvT_full = (size_t)NMEM * 1024 * 4;  // 117.4 MB
  const size_t mvT_q    = (size_t)NMEM * 256 * 4;   // 29.4 MB

  float* mvT = nullptr; int chld = 0; bool raw = false;
  if      (ws_size >= o_end + mvT_full) { mvT = (float*)(ws + o_end); chld = 1024; }
  else if (ws_size >= o_pr + mvT_full)  { mvT = (float*)(ws + o_pr);  chld = 1024; } // overlay (dead after k_select)
  else if (ws_size >= o_pr + mvT_q)     { mvT = (float*)(ws + o_pr);  chld = 256;  }
  else raw = true;

  k_prep_b<<<NMEM / 256, 256, 0, stream>>>(mem_key, mem_shr, Bh, Bl, mkT, shr);
  k_prep_u<<<HW / 256, 256, 0, stream>>>(q_key, q_sel, Uh, Ul, bsq);
  k_sim_max<<<dim3(HW / 64, NMEM / 256), 256, 0, stream>>>(Uh, Ul, Bh, Bl, bsq, shr, pmx);
  k_select<<<dim3(HW), 256, 0, stream>>>(pmx, mkT, q_key, q_sel, shr, wg, wi);

  if (!raw) {
    for (int g = 0; g < 1024 / chld; ++g) {
      k_transpose<<<dim3(NMEM / 64, chld / 64), 256, 0, stream>>>(
          mem_value, mvT, g * chld, chld);
      k_gather<<<dim3(HW / 16, chld / 256), 256, 0, stream>>>(
          mvT, wg, wi, out, g * chld, 0, chld, 1);
    }
  } else {
    k_gather<<<dim3(HW / 16, 4), 256, 0, stream>>>(
        mem_value, wg, wi, out, 0, 0, 1, NMEM);
  }
}

// Round 5
// 247.269 us; speedup vs baseline: 3.6484x; 1.2953x over previous
//
#include <hip/hip_runtime.h>
#include <math.h>

#define HW      1792
#define NMEM    28672
#define NCHUNK  3584          // NMEM/8 chunks of 8
#define TOPK    30
#define CTARGET 48
#define BINS    4096
#define VCACHE  3072
#define SIMB    (28 * 112)    // (HW/64) * (NMEM/256)
#define TRB     (448 * 16)    // (NMEM/64) * (1024/64)

typedef __attribute__((ext_vector_type(8))) short bf16x8;
typedef __attribute__((ext_vector_type(8))) unsigned short u16x8;
typedef __attribute__((ext_vector_type(4))) float f32x4;

static __device__ __forceinline__ unsigned short f2bf(float v) {
  unsigned b = __float_as_uint(v);
  return (unsigned short)((b + 0x7FFFu + ((b >> 16) & 1u)) >> 16);
}
static __device__ __forceinline__ float bf2f(unsigned short h) {
  return __uint_as_float(((unsigned)h) << 16);
}
static __device__ __forceinline__ unsigned fkey(float v) {
  return __float_as_uint(-v) & 0x7FFFFFFFu;
}
static __device__ __forceinline__ void gl_lds16(const void* g, void* l) {
  __builtin_amdgcn_global_load_lds(
      (const __attribute__((address_space(1))) unsigned*)g,
      (__attribute__((address_space(3))) unsigned*)l, 16, 0, 0);
}

// ---------------------------------------------------------------------------
// Prep B: K-slab layout Bh/Bl[t][n][32] bf16 hi/lo (t=0,1: mk cc=t*32..;
// t=2,3: mk^2). Also mkT[n][64] fp32 and shr_s = mem_shr/8.
// ---------------------------------------------------------------------------
__global__ __launch_bounds__(256)
void k_prep_b(const float* __restrict__ mk, const float* __restrict__ shr_in,
              unsigned short* __restrict__ Bh, unsigned short* __restrict__ Bl,
              float* __restrict__ mkT, float* __restrict__ shr_s)
{
  const int n = blockIdx.x * 256 + threadIdx.x;
  shr_s[n] = shr_in[n] * 0.125f;
  for (int cb = 0; cb < 64; cb += 8) {
    u16x8 h1, l1, h2, l2;
    float vv[8];
    #pragma unroll
    for (int j = 0; j < 8; ++j) {
      float v = mk[(size_t)(cb + j) * NMEM + n];
      vv[j] = v;
      unsigned short h = f2bf(v);
      h1[j] = h; l1[j] = f2bf(v - bf2f(h));
      float v2 = v * v;
      unsigned short g = f2bf(v2);
      h2[j] = g; l2[j] = f2bf(v2 - bf2f(g));
    }
    const int t1 = cb >> 5, k1 = cb & 31, t2 = 2 + t1;
    *reinterpret_cast<u16x8*>(&Bh[((size_t)t1 * NMEM + n) * 32 + k1]) = h1;
    *reinterpret_cast<u16x8*>(&Bl[((size_t)t1 * NMEM + n) * 32 + k1]) = l1;
    *reinterpret_cast<u16x8*>(&Bh[((size_t)t2 * NMEM + n) * 32 + k1]) = h2;
    *reinterpret_cast<u16x8*>(&Bl[((size_t)t2 * NMEM + n) * 32 + k1]) = l2;
    *reinterpret_cast<float4*>(&mkT[(size_t)n * 64 + cb])     = make_float4(vv[0], vv[1], vv[2], vv[3]);
    *reinterpret_cast<float4*>(&mkT[(size_t)n * 64 + cb + 4]) = make_float4(vv[4], vv[5], vv[6], vv[7]);
  }
}

// ---------------------------------------------------------------------------
// Prep U: K-slab layout Uh/Ul[t][p][32] (t=0,1: 2*qk*qs; t=2,3: -qs); bsq[p].
// ---------------------------------------------------------------------------
__global__ __launch_bounds__(256)
void k_prep_u(const float* __restrict__ q_key, const float* __restrict__ q_sel,
              unsigned short* __restrict__ Uh, unsigned short* __restrict__ Ul,
              float* __restrict__ bsq)
{
  const int p = blockIdx.x * 256 + threadIdx.x;
  float bs = 0.f;
  for (int cb = 0; cb < 64; cb += 8) {
    u16x8 h1, l1, h2, l2;
    #pragma unroll
    for (int j = 0; j < 8; ++j) {
      int c = cb + j;
      float k = q_key[(size_t)c * HW + p];
      float s = q_sel[(size_t)c * HW + p];
      float u = 2.f * k * s;
      float w = -s;
      bs = fmaf(s * k, k, bs);
      unsigned short h = f2bf(u); h1[j] = h; l1[j] = f2bf(u - bf2f(h));
      unsigned short g = f2bf(w); h2[j] = g; l2[j] = f2bf(w - bf2f(g));
    }
    const int t1 = cb >> 5, k1 = cb & 31, t2 = 2 + t1;
    *reinterpret_cast<u16x8*>(&Uh[((size_t)t1 * HW + p) * 32 + k1]) = h1;
    *reinterpret_cast<u16x8*>(&Ul[((size_t)t1 * HW + p) * 32 + k1]) = l1;
    *reinterpret_cast<u16x8*>(&Uh[((size_t)t2 * HW + p) * 32 + k1]) = h2;
    *reinterpret_cast<u16x8*>(&Ul[((size_t)t2 * HW + p) * 32 + k1]) = l2;
  }
  bsq[p] = bs;
}

// ---------------------------------------------------------------------------
// Fused phase A: sim blocks (LDS-staged MFMA GEMM -> chunk maxima) +
// transpose blocks (mem_value [1024][N] -> mvT[N][1024]), one launch.
// sim: block = 4 waves = 2p x 2n, tile 64p x 256n, K=128 in 4 steps of 32.
// B staged to LDS via global_load_lds (dbuf 2x32KB); A held in registers.
// ---------------------------------------------------------------------------
__global__ __launch_bounds__(256)
void k_phaseA(const unsigned short* __restrict__ Uh, const unsigned short* __restrict__ Ul,
              const unsigned short* __restrict__ Bh, const unsigned short* __restrict__ Bl,
              const float* __restrict__ bsq, const float* __restrict__ shr_s,
              float* __restrict__ pmax,
              const float* __restrict__ mv, float* __restrict__ mvT)
{
  __shared__ char smem[65536] __attribute__((aligned(16)));
  const int bx = blockIdx.x;
  const int tid = threadIdx.x;

  if (bx < SIMB) {
    const int wid = tid >> 6, lane = tid & 63;
    const int lr = lane & 15, lg = lane >> 4;
    const int pb = bx % 28, nb = bx / 28;
    const int pw = pb * 64 + (wid >> 1) * 32;
    const int nw0 = nb * 256;
    const int w = nb * 2 + (wid & 1);

    // A fragments for all K in registers (64 VGPR)
    bf16x8 a0h[4], a0l[4], a1h[4], a1l[4];
    #pragma unroll
    for (int t = 0; t < 4; ++t) {
      const size_t e0 = ((size_t)t * HW + pw + lr) * 32 + lg * 8;
      const size_t e1 = e0 + 16 * 32;
      a0h[t] = *reinterpret_cast<const bf16x8*>(&Uh[e0]);
      a0l[t] = *reinterpret_cast<const bf16x8*>(&Ul[e0]);
      a1h[t] = *reinterpret_cast<const bf16x8*>(&Uh[e1]);
      a1l[t] = *reinterpret_cast<const bf16x8*>(&Ul[e1]);
    }

    f32x4 acc[2][8];
    #pragma unroll
    for (int a = 0; a < 2; ++a)
      #pragma unroll
      for (int b = 0; b < 8; ++b) acc[a][b] = (f32x4){0.f, 0.f, 0.f, 0.f};

    // stage: Bh-slab-t rows [nw0, nw0+256) -> smem[buf][0], Bl -> smem[buf][1]
    auto stage = [&](int buf, int t) {
      const char* gh = (const char*)Bh + ((size_t)t * NMEM + nw0) * 64;
      const char* gl = (const char*)Bl + ((size_t)t * NMEM + nw0) * 64;
      char* dh = smem + buf * 32768;
      char* dl = dh + 16384;
      #pragma unroll
      for (int k = 0; k < 4; ++k) {
        const int o = (k * 256 + tid) * 16;
        gl_lds16(gh + o, dh + o);
        gl_lds16(gl + o, dl + o);
      }
    };

    stage(0, 0);
    __syncthreads();
    int buf = 0;
    #pragma unroll
    for (int t = 0; t < 4; ++t) {
      if (t < 3) stage(buf ^ 1, t + 1);
      const short* lbh = (const short*)(smem + buf * 32768);
      const short* lbl = (const short*)(smem + buf * 32768 + 16384);
      const int eb = ((wid & 1) * 128 + lr) * 32 + lg * 8;
      #pragma unroll
      for (int nt = 0; nt < 8; ++nt) {
        bf16x8 bh = *reinterpret_cast<const bf16x8*>(&lbh[eb + nt * 512]);
        bf16x8 bl = *reinterpret_cast<const bf16x8*>(&lbl[eb + nt * 512]);
        acc[0][nt] = __builtin_amdgcn_mfma_f32_16x16x32_bf16(a0h[t], bh, acc[0][nt], 0, 0, 0);
        acc[0][nt] = __builtin_amdgcn_mfma_f32_16x16x32_bf16(a0l[t], bh, acc[0][nt], 0, 0, 0);
        acc[0][nt] = __builtin_amdgcn_mfma_f32_16x16x32_bf16(a0h[t], bl, acc[0][nt], 0, 0, 0);
        acc[1][nt] = __builtin_amdgcn_mfma_f32_16x16x32_bf16(a1h[t], bh, acc[1][nt], 0, 0, 0);
        acc[1][nt] = __builtin_amdgcn_mfma_f32_16x16x32_bf16(a1l[t], bh, acc[1][nt], 0, 0, 0);
        acc[1][nt] = __builtin_amdgcn_mfma_f32_16x16x32_bf16(a1h[t], bl, acc[1][nt], 0, 0, 0);
      }
      __syncthreads();
      buf ^= 1;
    }

    float shv[8];
    #pragma unroll
    for (int nt = 0; nt < 8; ++nt) shv[nt] = shr_s[w * 128 + nt * 16 + lr];
    #pragma unroll
    for (int pt = 0; pt < 2; ++pt) {
      #pragma unroll
      for (int r = 0; r < 4; ++r) {
        const int p = pw + pt * 16 + 4 * lg + r;
        const float bq = bsq[p];
        float mx = -INFINITY;
        #pragma unroll
        for (int nt = 0; nt < 8; ++nt)
          mx = fmaxf(mx, (acc[pt][nt][r] - bq) * shv[nt]);
        pmax[(size_t)p * NCHUNK + w * 16 + lr] = mx;
      }
    }
  } else {
    // ---- transpose block
    float (*tt)[65] = (float(*)[65])smem;
    const int b2 = bx - SIMB;
    const int n0 = (b2 % 448) * 64, ch0 = (b2 / 448) * 64;
    for (int i = tid; i < 64 * 16; i += 256) {
      int r = i >> 4, c4 = (i & 15) << 2;
      float4 v = *reinterpret_cast<const float4*>(&mv[(size_t)(ch0 + r) * NMEM + n0 + c4]);
      tt[r][c4] = v.x; tt[r][c4 + 1] = v.y; tt[r][c4 + 2] = v.z; tt[r][c4 + 3] = v.w;
    }
    __syncthreads();
    for (int i = tid; i < 64 * 16; i += 256) {
      int r = i >> 4, c4 = (i & 15) << 2;
      float4 v = make_float4(tt[c4][r], tt[c4 + 1][r], tt[c4 + 2][r], tt[c4 + 3][r]);
      *reinterpret_cast<float4*>(&mvT[(size_t)(n0 + r) * 1024 + ch0 + c4]) = v;
    }
  }
}

// ---------------------------------------------------------------------------
// crossing finder: smallest bin B with prefix(<B) < target <= prefix(<=B)
// ---------------------------------------------------------------------------
__device__ __forceinline__ void find_cross(int* hist, int* lsum, int* wsum,
                                           int tid, int target, int* sB, int* sNA)
{
  const int base = tid * (BINS / 256);
  int ls = 0;
  #pragma unroll
  for (int k = 0; k < BINS / 256; ++k) ls += hist[base + k];
  lsum[tid] = ls;
  __syncthreads();
  int lane = tid & 63, wv = tid >> 6;
  int v = ls;
  #pragma unroll
  for (int off = 1; off < 64; off <<= 1) {
    int t = __shfl_up(v, off);
    if (lane >= off) v += t;
  }
  if (lane == 63) wsum[wv] = v;
  __syncthreads();
  int wo = 0;
  for (int k = 0; k < wv; ++k) wo += wsum[k];
  int run = wo + v - ls;
  #pragma unroll 1
  for (int k = 0; k < BINS / 256; ++k) {
    int h = hist[base + k];
    if (run < target && run + h >= target) { *sB = base + k; *sNA = run; }
    run += h;
  }
  __syncthreads();
}

// ---------------------------------------------------------------------------
// Kernel: per-pixel exact top-30 via chunk-max pruning + exact recompute.
// ---------------------------------------------------------------------------
__global__ __launch_bounds__(256)
void k_select(const float* __restrict__ pmax, const float* __restrict__ mkT,
              const float* __restrict__ q_key, const float* __restrict__ q_sel,
              const float* __restrict__ shr_s,
              float* __restrict__ wgt, int* __restrict__ widx)
{
  __shared__ int            hist[BINS];
  __shared__ float          sqk[64], sqs[64];
  __shared__ unsigned short chl[NCHUNK];
  __shared__ float          vcache[VCACHE];
  __shared__ unsigned       au[64];
  __shared__ int            ai[64];
  __shared__ unsigned       bu[1024];
  __shared__ int            bi[1024];
  __shared__ float          fv[32];
  __shared__ int            fi[32];
  __shared__ float          ew[32];
  __shared__ int            lsum[256], wsum[4];
  __shared__ int            sB, sNA, cA, cB, sSC;
  __shared__ float          sSum;

  const int pix = blockIdx.x;
  const int tid = threadIdx.x;

  if (tid < 64) {
    sqk[tid] = q_key[(size_t)tid * HW + pix];
    sqs[tid] = q_sel[(size_t)tid * HW + pix];
  }
  for (int i = tid; i < BINS; i += 256) hist[i] = 0;
  if (tid == 0) { sSC = 0; cA = 0; cB = 0; }
  __syncthreads();

  // ---- stage 1: chunk maxima -> 48-crossing bin -> survivor chunks
  float m[NCHUNK / 256];
  const float* pm = pmax + (size_t)pix * NCHUNK;
  #pragma unroll
  for (int j = 0; j < NCHUNK / 256; ++j) m[j] = pm[tid + 256 * j];
  #pragma unroll
  for (int j = 0; j < NCHUNK / 256; ++j) atomicAdd(&hist[fkey(m[j]) >> 19], 1);
  __syncthreads();
  find_cross(hist, lsum, wsum, tid, CTARGET, &sB, &sNA);
  {
    const int B = sB;
    #pragma unroll
    for (int j = 0; j < NCHUNK / 256; ++j)
      if ((int)(fkey(m[j]) >> 19) <= B) {
        int k = atomicAdd(&sSC, 1);
        chl[k] = (unsigned short)(tid + 256 * j);
      }
  }
  __syncthreads();
  const int SC = sSC, NC = SC * 8;
  for (int i = tid; i < BINS; i += 256) hist[i] = 0;
  __syncthreads();

  const float4* sqk4 = reinterpret_cast<const float4*>(sqk);
  const float4* sqs4 = reinterpret_cast<const float4*>(sqs);

  // ---- stage 2 pass X: exact fp32 sims of candidates + histogram
  for (int c = tid; c < NC; c += 256) {
    const int cc = chl[c >> 3];
    const int n = ((cc >> 4) << 7) + (cc & 15) + ((c & 7) << 4);
    const float4* mr = reinterpret_cast<const float4*>(mkT + (size_t)n * 64);
    float s = 0.f;
    #pragma unroll
    for (int j = 0; j < 16; ++j) {
      float4 q = mr[j], k4 = sqk4[j], s4 = sqs4[j];
      float d0 = q.x - k4.x, d1 = q.y - k4.y, d2 = q.z - k4.z, d3 = q.w - k4.w;
      s = fmaf(s4.x * d0, d0, s); s = fmaf(s4.y * d1, d1, s);
      s = fmaf(s4.z * d2, d2, s); s = fmaf(s4.w * d3, d3, s);
    }
    float v = -s * shr_s[n];
    if (c < VCACHE) vcache[c] = v;
    atomicAdd(&hist[fkey(v) >> 19], 1);
  }
  __syncthreads();
  find_cross(hist, lsum, wsum, tid, TOPK, &sB, &sNA);

  // ---- stage 2 pass Y: collect top-30 (bins < B2) + boundary rank-cut
  {
    const int B2 = sB;
    for (int c = tid; c < NC; c += 256) {
      const int cc = chl[c >> 3];
      const int n = ((cc >> 4) << 7) + (cc & 15) + ((c & 7) << 4);
      float v;
      if (c < VCACHE) v = vcache[c];
      else {
        const float4* mr = reinterpret_cast<const float4*>(mkT + (size_t)n * 64);
        float s = 0.f;
        #pragma unroll
        for (int j = 0; j < 16; ++j) {
          float4 q = mr[j], k4 = sqk4[j], s4 = sqs4[j];
          float d0 = q.x - k4.x, d1 = q.y - k4.y, d2 = q.z - k4.z, d3 = q.w - k4.w;
          s = fmaf(s4.x * d0, d0, s); s = fmaf(s4.y * d1, d1, s);
          s = fmaf(s4.z * d2, d2, s); s = fmaf(s4.w * d3, d3, s);
        }
        v = -s * shr_s[n];
      }
      unsigned u = fkey(v);
      int bin = (int)(u >> 19);
      if (bin < B2)       { int k = atomicAdd(&cA, 1); au[k] = u; ai[k] = n; }
      else if (bin == B2) { int k = atomicAdd(&cB, 1); if (k < 1024) { bu[k] = u; bi[k] = n; } }
    }
  }
  __syncthreads();
  {
    const int nAv = cA, mm = (cB < 1024 ? cB : 1024), need = TOPK - nAv;
    for (int t = tid; t < mm; t += 256) {
      unsigned u = bu[t]; int id = bi[t];
      int r = 0;
      for (int k2 = 0; k2 < mm; ++k2) {
        unsigned uk = bu[k2];
        r += (uk < u) || (uk == u && bi[k2] < id);
      }
      if (r < need) { au[nAv + r] = u; ai[nAv + r] = id; }
    }
  }
  __syncthreads();

  // ---- deterministic ordering of the 30 + softmax
  if (tid < TOPK) {
    unsigned u = au[tid]; int id = ai[tid];
    int r = 0;
    for (int k2 = 0; k2 < TOPK; ++k2) {
      unsigned uk = au[k2];
      r += (uk < u) || (uk == u && ai[k2] < id);
    }
    fv[r] = -__uint_as_float(u); fi[r] = id;
  }
  __syncthreads();
  if (tid < 32) {
    float e = (tid < TOPK) ? expf(fv[tid]) : 0.f;
    if (tid < TOPK) ew[tid] = e;
    float ss = e;
    #pragma unroll
    for (int off = 16; off > 0; off >>= 1) ss += __shfl_down(ss, off);
    if (tid == 0) sSum = ss;
  }
  __syncthreads();
  if (tid < TOPK) {
    wgt [(size_t)pix * 32 + tid] = ew[tid] / sSum;
    widx[(size_t)pix * 32 + tid] = fi[tid];
  }
}

// ---------------------------------------------------------------------------
// Standalone transpose (fallback, workspace-overlay mode)
// ---------------------------------------------------------------------------
__global__ __launch_bounds__(256)
void k_transpose(const float* __restrict__ mv, float* __restrict__ mvT,
                 int chbase, int ld)
{
  __shared__ float t[64][65];
  const int n0 = blockIdx.x * 64, ch0 = blockIdx.y * 64;
  const int tid = threadIdx.x;
  for (int i = tid; i < 64 * 16; i += 256) {
    int r = i >> 4, c4 = (i & 15) << 2;
    float4 v = *reinterpret_cast<const float4*>(
        &mv[(size_t)(chbase + ch0 + r) * NMEM + n0 + c4]);
    t[r][c4] = v.x; t[r][c4 + 1] = v.y; t[r][c4 + 2] = v.z; t[r][c4 + 3] = v.w;
  }
  __syncthreads();
  for (int i = tid; i < 64 * 16; i += 256) {
    int r = i >> 4, c4 = (i & 15) << 2;
    float4 v = make_float4(t[c4][r], t[c4 + 1][r], t[c4 + 2][r], t[c4 + 3][r]);
    *reinterpret_cast<float4*>(&mvT[(size_t)(n0 + r) * ld + ch0 + c4]) = v;
  }
}

// ---------------------------------------------------------------------------
// Gather: out[out_chbase+ch][p] = sum_k w[p][k] * src[idx*ns + (src_chbase+ch)*cs]
// ---------------------------------------------------------------------------
__global__ __launch_bounds__(256)
void k_gather(const float* __restrict__ src, const float* __restrict__ wgt,
              const int* __restrict__ widx, float* __restrict__ out,
              int out_chbase, int src_chbase, long n_stride, long ch_stride)
{
  __shared__ float sw[16][TOPK];
  __shared__ int   si[16][TOPK];
  __shared__ float sbuf[256][17];
  const int p0 = blockIdx.x * 16, chg = blockIdx.y * 256;
  const int tid = threadIdx.x;

  for (int i = tid; i < 16 * TOPK; i += 256) {
    int q = i / TOPK, k = i - q * TOPK;
    sw[q][k] = wgt [(size_t)(p0 + q) * 32 + k];
    si[q][k] = widx[(size_t)(p0 + q) * 32 + k];
  }
  __syncthreads();

  const int ch = chg + tid;
  #pragma unroll 2
  for (int q = 0; q < 16; ++q) {
    float a = 0.f;
    #pragma unroll
    for (int k = 0; k < TOPK; ++k)
      a = fmaf(sw[q][k], src[(size_t)si[q][k] * n_stride +
                             (size_t)(src_chbase + ch) * ch_stride], a);
    sbuf[tid][q] = a;
  }
  __syncthreads();

  for (int i = tid; i < 256 * 16; i += 256) {
    int cl = i >> 4, q = i & 15;
    out[(size_t)(out_chbase + chg + cl) * HW + p0 + q] = sbuf[cl][q];
  }
}

// ---------------------------------------------------------------------------
extern "C" void kernel_launch(void* const* d_in, const int* in_sizes, int n_in,
                              void* d_out, int out_size, void* d_ws, size_t ws_size,
                              hipStream_t stream)
{
  (void)in_sizes; (void)n_in; (void)out_size;
  const float* q_key     = (const float*)d_in[0];
  const float* q_sel     = (const float*)d_in[1];
  const float* mem_key   = (const float*)d_in[2];
  const float* mem_shr   = (const float*)d_in[3];
  const float* mem_value = (const float*)d_in[4];
  float* out = (float*)d_out;

  char* ws = (char*)d_ws;
  size_t off = 0;
  auto alloc = [&](size_t b) { size_t c = off; off = (off + b + 255) & ~(size_t)255; return c; };
  size_t o_w   = alloc((size_t)HW * 32 * 4);
  size_t o_wi  = alloc((size_t)HW * 32 * 4);
  size_t o_pr  = off;                              // overlay point (fallback)
  size_t o_bh  = alloc((size_t)NMEM * 128 * 2);
  size_t o_bl  = alloc((size_t)NMEM * 128 * 2);
  size_t o_uh  = alloc((size_t)HW * 128 * 2);
  size_t o_ul  = alloc((size_t)HW * 128 * 2);
  size_t o_bsq = alloc((size_t)HW * 4);
  size_t o_shr = alloc((size_t)NMEM * 4);
  size_t o_mkT = alloc((size_t)NMEM * 64 * 4);
  size_t o_pm  = alloc((size_t)HW * NCHUNK * 4);
  size_t o_end = off;

  float*          wg   = (float*)(ws + o_w);
  int*            wi   = (int*)  (ws + o_wi);
  unsigned short* Bh   = (unsigned short*)(ws + o_bh);
  unsigned short* Bl   = (unsigned short*)(ws + o_bl);
  unsigned short* Uh   = (unsigned short*)(ws + o_uh);
  unsigned short* Ul   = (unsigned short*)(ws + o_ul);
  float*          bsq  = (float*)(ws + o_bsq);
  float*          shr  = (float*)(ws + o_shr);
  float*          mkT  = (float*)(ws + o_mkT);
  float*          pmx  = (float*)(ws + o_pm);

  const size_t mvT_full = (size_t)NMEM * 1024 * 4;
  const size_t mvT_q    = (size_t)NMEM * 256 * 4;

  k_prep_b<<<NMEM / 256, 256, 0, stream>>>(mem_key, mem_shr, Bh, Bl, mkT, shr);
  k_prep_u<<<HW / 256, 256, 0, stream>>>(q_key, q_sel, Uh, Ul, bsq);

  if (ws_size >= o_end + mvT_full) {
    // fused: sim + transpose overlap in one launch (mvT doesn't alias anything)
    float* mvT = (float*)(ws + o_end);
    k_phaseA<<<SIMB + TRB, 256, 0, stream>>>(Uh, Ul, Bh, Bl, bsq, shr, pmx,
                                             mem_value, mvT);
    k_select<<<HW, 256, 0, stream>>>(pmx, mkT, q_key, q_sel, shr, wg, wi);
    k_gather<<<dim3(HW / 16, 4), 256, 0, stream>>>(mvT, wg, wi, out, 0, 0, 1024, 1);
  } else {
    // fallback: sequential, mvT overlays dead prep region after select
    k_phaseA<<<SIMB, 256, 0, stream>>>(Uh, Ul, Bh, Bl, bsq, shr, pmx,
                                       mem_value, nullptr);
    k_select<<<HW, 256, 0, stream>>>(pmx, mkT, q_key, q_sel, shr, wg, wi);
    float* mvT = (float*)(ws + o_pr); int chld; bool raw = false;
    if      (ws_size >= o_pr + mvT_full) chld = 1024;
    else if (ws_size >= o_pr + mvT_q)    chld = 256;
    else raw = true;
    if (!raw) {
      for (int g = 0; g < 1024 / chld; ++g) {
        k_transpose<<<dim3(NMEM / 64, chld / 64), 256, 0, stream>>>(
            mem_value, mvT, g * chld, chld);
        k_gather<<<dim3(HW / 16, chld / 256), 256, 0, stream>>>(
            mvT, wg, wi, out, g * chld, 0, chld, 1);
      }
    } else {
      k_gather<<<dim3(HW / 16, 4), 256, 0, stream>>>(
          mem_value, wg, wi, out, 0, 0, 1, NMEM);
    }
  }
}

// Round 6
// 227.122 us; speedup vs baseline: 3.9721x; 1.0887x over previous
//
#include <hip/hip_runtime.h>
#include <math.h>

#define HW      1792
#define NMEM    28672
#define NCHUNK  3584          // NMEM/8 chunks of 8
#define TOPK    30
#define CTARGET 64
#define BINS    4096
#define VCACHE  3072
#define SIMB    (28 * 112)    // (HW/64) * (NMEM/256) = 3136
#define TRB     (448 * 16)    // (NMEM/64) * (1024/64) = 7168

typedef __attribute__((ext_vector_type(8))) short bf16x8;
typedef __attribute__((ext_vector_type(8))) unsigned short u16x8;
typedef __attribute__((ext_vector_type(4))) float f32x4;

static __device__ __forceinline__ unsigned short f2bf(float v) {
  unsigned b = __float_as_uint(v);
  return (unsigned short)((b + 0x7FFFu + ((b >> 16) & 1u)) >> 16);
}
static __device__ __forceinline__ float bf2f(unsigned short h) {
  return __uint_as_float(((unsigned)h) << 16);
}
static __device__ __forceinline__ unsigned fkey(float v) {
  return __float_as_uint(-v) & 0x7FFFFFFFu;
}
static __device__ __forceinline__ void gl_lds16(const void* g, void* l) {
  __builtin_amdgcn_global_load_lds(
      (const __attribute__((address_space(1))) unsigned*)g,
      (__attribute__((address_space(3))) unsigned*)l, 16, 0, 0);
}

// ---------------------------------------------------------------------------
// Prep B: Bh[s][n][8] bf16-hi, slab s = 8-k group. s=0..7: mk (K 0..63),
// s=8..15: mk^2. Also mkT[n][64] fp32, shr_s = mem_shr/8. (No B-lo: the
// dropped a_hi*b_lo term costs ~2e-3 sim error; selection margin absorbs it
// and final sims are recomputed exactly.)
// ---------------------------------------------------------------------------
__global__ __launch_bounds__(256)
void k_prep_b(const float* __restrict__ mk, const float* __restrict__ shr_in,
              unsigned short* __restrict__ Bh,
              float* __restrict__ mkT, float* __restrict__ shr_s)
{
  const int n = blockIdx.x * 256 + threadIdx.x;
  shr_s[n] = shr_in[n] * 0.125f;
  for (int cb = 0; cb < 64; cb += 8) {
    u16x8 h1, h2;
    float vv[8];
    #pragma unroll
    for (int j = 0; j < 8; ++j) {
      float v = mk[(size_t)(cb + j) * NMEM + n];
      vv[j] = v;
      h1[j] = f2bf(v);
      h2[j] = f2bf(v * v);
    }
    const int s = cb >> 3;
    *reinterpret_cast<u16x8*>(&Bh[((size_t)s * NMEM + n) * 8])       = h1;
    *reinterpret_cast<u16x8*>(&Bh[((size_t)(s + 8) * NMEM + n) * 8]) = h2;
    *reinterpret_cast<float4*>(&mkT[(size_t)n * 64 + cb])     = make_float4(vv[0], vv[1], vv[2], vv[3]);
    *reinterpret_cast<float4*>(&mkT[(size_t)n * 64 + cb + 4]) = make_float4(vv[4], vv[5], vv[6], vv[7]);
  }
}

// ---------------------------------------------------------------------------
// Prep U: Uh/Ul[s][p][8] bf16 hi/lo. s=0..7: 2*qk*qs, s=8..15: -qs. bsq[p].
// ---------------------------------------------------------------------------
__global__ __launch_bounds__(256)
void k_prep_u(const float* __restrict__ q_key, const float* __restrict__ q_sel,
              unsigned short* __restrict__ Uh, unsigned short* __restrict__ Ul,
              float* __restrict__ bsq)
{
  const int p = blockIdx.x * 256 + threadIdx.x;
  float bs = 0.f;
  for (int cb = 0; cb < 64; cb += 8) {
    u16x8 h1, l1, h2, l2;
    #pragma unroll
    for (int j = 0; j < 8; ++j) {
      int c = cb + j;
      float k = q_key[(size_t)c * HW + p];
      float s = q_sel[(size_t)c * HW + p];
      float u = 2.f * k * s;
      float w = -s;
      bs = fmaf(s * k, k, bs);
      unsigned short h = f2bf(u); h1[j] = h; l1[j] = f2bf(u - bf2f(h));
      unsigned short g = f2bf(w); h2[j] = g; l2[j] = f2bf(w - bf2f(g));
    }
    const int s = cb >> 3;
    *reinterpret_cast<u16x8*>(&Uh[((size_t)s * HW + p) * 8])       = h1;
    *reinterpret_cast<u16x8*>(&Ul[((size_t)s * HW + p) * 8])       = l1;
    *reinterpret_cast<u16x8*>(&Uh[((size_t)(s + 8) * HW + p) * 8]) = h2;
    *reinterpret_cast<u16x8*>(&Ul[((size_t)(s + 8) * HW + p) * 8]) = l2;
  }
  bsq[p] = bs;
}

// ---------------------------------------------------------------------------
// Fused phase A: sim blocks (LDS-staged MFMA GEMM -> chunk maxima) +
// transpose blocks (mem_value -> mvT), interleaved 7 sim : 16 transpose.
// sim: 4 waves = 2p x 2n over 64p x 256n, K=128 in 4 steps of 32.
// LDS per K-step: [g(4)][row(256)][16B] = 16 KB, dbuf 32 KB -> 4 blocks/CU.
// Bank check: 16-lane phase reads addr = g*4096 + row*16, rows lr=0..15
// -> banks 4*(lr&7)+d = all 32 banks, 2 accesses each = conflict-free.
// ---------------------------------------------------------------------------
__global__ __launch_bounds__(256)
void k_phaseA(const unsigned short* __restrict__ Uh, const unsigned short* __restrict__ Ul,
              const unsigned short* __restrict__ Bh,
              const float* __restrict__ bsq, const float* __restrict__ shr_s,
              float* __restrict__ pmax,
              const float* __restrict__ mv, float* __restrict__ mvT)
{
  __shared__ char smem[32768] __attribute__((aligned(16)));
  const int tid = threadIdx.x;

  int sb = -1, tb = -1;
  if (gridDim.x > SIMB) {
    const int g = blockIdx.x / 23, r = blockIdx.x % 23;
    if (r < 7) sb = g * 7 + r; else tb = g * 16 + (r - 7);
  } else {
    sb = blockIdx.x;
  }

  if (sb >= 0) {
    const int wid = tid >> 6, lane = tid & 63;
    const int lr = lane & 15, lg = lane >> 4;
    const int pb = sb % 28, nb = sb / 28;
    const int pw = pb * 64 + (wid >> 1) * 32;
    const int nw0 = nb * 256;
    const int w = nb * 2 + (wid & 1);

    // A fragments (hi+lo) for all K in registers: slab s = t*4 + lg
    bf16x8 a0h[4], a0l[4], a1h[4], a1l[4];
    #pragma unroll
    for (int t = 0; t < 4; ++t) {
      const size_t e0 = ((size_t)(t * 4 + lg) * HW + pw + lr) * 8;
      const size_t e1 = e0 + 16 * 8;
      a0h[t] = *reinterpret_cast<const bf16x8*>(&Uh[e0]);
      a0l[t] = *reinterpret_cast<const bf16x8*>(&Ul[e0]);
      a1h[t] = *reinterpret_cast<const bf16x8*>(&Uh[e1]);
      a1l[t] = *reinterpret_cast<const bf16x8*>(&Ul[e1]);
    }

    f32x4 acc[2][8];
    #pragma unroll
    for (int a = 0; a < 2; ++a)
      #pragma unroll
      for (int b = 0; b < 8; ++b) acc[a][b] = (f32x4){0.f, 0.f, 0.f, 0.f};

    // stage slab-group t: 4 k-groups x 256 rows x 16B, linear dest
    auto stage = [&](int buf, int t) {
      #pragma unroll
      for (int g = 0; g < 4; ++g) {
        const char* src = (const char*)Bh + ((size_t)(t * 4 + g) * NMEM + nw0 + tid) * 16;
        gl_lds16(src, smem + buf * 16384 + (g * 256 + tid) * 16);
      }
    };

    stage(0, 0);
    __syncthreads();
    int buf = 0;
    #pragma unroll
    for (int t = 0; t < 4; ++t) {
      if (t < 3) stage(buf ^ 1, t + 1);
      const short* lb = (const short*)(smem + buf * 16384);
      const int rbase = (wid & 1) * 128;
      #pragma unroll
      for (int nt = 0; nt < 8; ++nt) {
        const int row = rbase + nt * 16 + lr;
        bf16x8 bh = *reinterpret_cast<const bf16x8*>(&lb[lg * 2048 + row * 8]);
        acc[0][nt] = __builtin_amdgcn_mfma_f32_16x16x32_bf16(a0h[t], bh, acc[0][nt], 0, 0, 0);
        acc[0][nt] = __builtin_amdgcn_mfma_f32_16x16x32_bf16(a0l[t], bh, acc[0][nt], 0, 0, 0);
        acc[1][nt] = __builtin_amdgcn_mfma_f32_16x16x32_bf16(a1h[t], bh, acc[1][nt], 0, 0, 0);
        acc[1][nt] = __builtin_amdgcn_mfma_f32_16x16x32_bf16(a1l[t], bh, acc[1][nt], 0, 0, 0);
      }
      __syncthreads();
      buf ^= 1;
    }

    float shv[8];
    #pragma unroll
    for (int nt = 0; nt < 8; ++nt) shv[nt] = shr_s[w * 128 + nt * 16 + lr];
    #pragma unroll
    for (int pt = 0; pt < 2; ++pt) {
      #pragma unroll
      for (int r = 0; r < 4; ++r) {
        const int p = pw + pt * 16 + 4 * lg + r;
        const float bq = bsq[p];
        float mx = -INFINITY;
        #pragma unroll
        for (int nt = 0; nt < 8; ++nt)
          mx = fmaxf(mx, (acc[pt][nt][r] - bq) * shv[nt]);
        pmax[(size_t)p * NCHUNK + w * 16 + lr] = mx;
      }
    }
  } else {
    // ---- transpose block
    float (*tt)[65] = (float(*)[65])smem;
    const int n0 = (tb % 448) * 64, ch0 = (tb / 448) * 64;
    for (int i = tid; i < 64 * 16; i += 256) {
      int r = i >> 4, c4 = (i & 15) << 2;
      float4 v = *reinterpret_cast<const float4*>(&mv[(size_t)(ch0 + r) * NMEM + n0 + c4]);
      tt[r][c4] = v.x; tt[r][c4 + 1] = v.y; tt[r][c4 + 2] = v.z; tt[r][c4 + 3] = v.w;
    }
    __syncthreads();
    for (int i = tid; i < 64 * 16; i += 256) {
      int r = i >> 4, c4 = (i & 15) << 2;
      float4 v = make_float4(tt[c4][r], tt[c4 + 1][r], tt[c4 + 2][r], tt[c4 + 3][r]);
      *reinterpret_cast<float4*>(&mvT[(size_t)(n0 + r) * 1024 + ch0 + c4]) = v;
    }
  }
}

// ---------------------------------------------------------------------------
// crossing finder: smallest bin B with prefix(<B) < target <= prefix(<=B)
// ---------------------------------------------------------------------------
__device__ __forceinline__ void find_cross(int* hist, int* lsum, int* wsum,
                                           int tid, int target, int* sB, int* sNA)
{
  const int base = tid * (BINS / 256);
  int ls = 0;
  #pragma unroll
  for (int k = 0; k < BINS / 256; ++k) ls += hist[base + k];
  lsum[tid] = ls;
  __syncthreads();
  int lane = tid & 63, wv = tid >> 6;
  int v = ls;
  #pragma unroll
  for (int off = 1; off < 64; off <<= 1) {
    int t = __shfl_up(v, off);
    if (lane >= off) v += t;
  }
  if (lane == 63) wsum[wv] = v;
  __syncthreads();
  int wo = 0;
  for (int k = 0; k < wv; ++k) wo += wsum[k];
  int run = wo + v - ls;
  #pragma unroll 1
  for (int k = 0; k < BINS / 256; ++k) {
    int h = hist[base + k];
    if (run < target && run + h >= target) { *sB = base + k; *sNA = run; }
    run += h;
  }
  __syncthreads();
}

// ---------------------------------------------------------------------------
// Kernel: per-pixel exact top-30 via chunk-max pruning + exact recompute.
// ---------------------------------------------------------------------------
__global__ __launch_bounds__(256)
void k_select(const float* __restrict__ pmax, const float* __restrict__ mkT,
              const float* __restrict__ q_key, const float* __restrict__ q_sel,
              const float* __restrict__ shr_s,
              float* __restrict__ wgt, int* __restrict__ widx)
{
  __shared__ int            hist[BINS];
  __shared__ float          sqk[64], sqs[64];
  __shared__ unsigned short chl[NCHUNK];
  __shared__ float          vcache[VCACHE];
  __shared__ unsigned       au[64];
  __shared__ int            ai[64];
  __shared__ unsigned       bu[1024];
  __shared__ int            bi[1024];
  __shared__ float          fv[32];
  __shared__ int            fi[32];
  __shared__ float          ew[32];
  __shared__ int            lsum[256], wsum[4];
  __shared__ int            sB, sNA, cA, cB, sSC;
  __shared__ float          sSum;

  const int pix = blockIdx.x;
  const int tid = threadIdx.x;

  if (tid < 64) {
    sqk[tid] = q_key[(size_t)tid * HW + pix];
    sqs[tid] = q_sel[(size_t)tid * HW + pix];
  }
  for (int i = tid; i < BINS; i += 256) hist[i] = 0;
  if (tid == 0) { sSC = 0; cA = 0; cB = 0; }
  __syncthreads();

  // ---- stage 1: chunk maxima -> CTARGET-crossing bin -> survivor chunks
  float m[NCHUNK / 256];
  const float* pm = pmax + (size_t)pix * NCHUNK;
  #pragma unroll
  for (int j = 0; j < NCHUNK / 256; ++j) m[j] = pm[tid + 256 * j];
  #pragma unroll
  for (int j = 0; j < NCHUNK / 256; ++j) atomicAdd(&hist[fkey(m[j]) >> 19], 1);
  __syncthreads();
  find_cross(hist, lsum, wsum, tid, CTARGET, &sB, &sNA);
  {
    const int B = sB;
    #pragma unroll
    for (int j = 0; j < NCHUNK / 256; ++j)
      if ((int)(fkey(m[j]) >> 19) <= B) {
        int k = atomicAdd(&sSC, 1);
        chl[k] = (unsigned short)(tid + 256 * j);
      }
  }
  __syncthreads();
  const int SC = sSC, NC = SC * 8;
  for (int i = tid; i < BINS; i += 256) hist[i] = 0;
  __syncthreads();

  const float4* sqk4 = reinterpret_cast<const float4*>(sqk);
  const float4* sqs4 = reinterpret_cast<const float4*>(sqs);

  // ---- stage 2 pass X: exact fp32 sims of candidates + histogram
  for (int c = tid; c < NC; c += 256) {
    const int cc = chl[c >> 3];
    const int n = ((cc >> 4) << 7) + (cc & 15) + ((c & 7) << 4);
    const float4* mr = reinterpret_cast<const float4*>(mkT + (size_t)n * 64);
    float s = 0.f;
    #pragma unroll
    for (int j = 0; j < 16; ++j) {
      float4 q = mr[j], k4 = sqk4[j], s4 = sqs4[j];
      float d0 = q.x - k4.x, d1 = q.y - k4.y, d2 = q.z - k4.z, d3 = q.w - k4.w;
      s = fmaf(s4.x * d0, d0, s); s = fmaf(s4.y * d1, d1, s);
      s = fmaf(s4.z * d2, d2, s); s = fmaf(s4.w * d3, d3, s);
    }
    float v = -s * shr_s[n];
    if (c < VCACHE) vcache[c] = v;
    atomicAdd(&hist[fkey(v) >> 19], 1);
  }
  __syncthreads();
  find_cross(hist, lsum, wsum, tid, TOPK, &sB, &sNA);

  // ---- stage 2 pass Y: collect top-30 (bins < B2) + boundary rank-cut
  {
    const int B2 = sB;
    for (int c = tid; c < NC; c += 256) {
      const int cc = chl[c >> 3];
      const int n = ((cc >> 4) << 7) + (cc & 15) + ((c & 7) << 4);
      float v;
      if (c < VCACHE) v = vcache[c];
      else {
        const float4* mr = reinterpret_cast<const float4*>(mkT + (size_t)n * 64);
        float s = 0.f;
        #pragma unroll
        for (int j = 0; j < 16; ++j) {
          float4 q = mr[j], k4 = sqk4[j], s4 = sqs4[j];
          float d0 = q.x - k4.x, d1 = q.y - k4.y, d2 = q.z - k4.z, d3 = q.w - k4.w;
          s = fmaf(s4.x * d0, d0, s); s = fmaf(s4.y * d1, d1, s);
          s = fmaf(s4.z * d2, d2, s); s = fmaf(s4.w * d3, d3, s);
        }
        v = -s * shr_s[n];
      }
      unsigned u = fkey(v);
      int bin = (int)(u >> 19);
      if (bin < B2)       { int k = atomicAdd(&cA, 1); au[k] = u; ai[k] = n; }
      else if (bin == B2) { int k = atomicAdd(&cB, 1); if (k < 1024) { bu[k] = u; bi[k] = n; } }
    }
  }
  __syncthreads();
  {
    const int nAv = cA, mm = (cB < 1024 ? cB : 1024), need = TOPK - nAv;
    for (int t = tid; t < mm; t += 256) {
      unsigned u = bu[t]; int id = bi[t];
      int r = 0;
      for (int k2 = 0; k2 < mm; ++k2) {
        unsigned uk = bu[k2];
        r += (uk < u) || (uk == u && bi[k2] < id);
      }
      if (r < need) { au[nAv + r] = u; ai[nAv + r] = id; }
    }
  }
  __syncthreads();

  // ---- deterministic ordering of the 30 + softmax
  if (tid < TOPK) {
    unsigned u = au[tid]; int id = ai[tid];
    int r = 0;
    for (int k2 = 0; k2 < TOPK; ++k2) {
      unsigned uk = au[k2];
      r += (uk < u) || (uk == u && ai[k2] < id);
    }
    fv[r] = -__uint_as_float(u); fi[r] = id;
  }
  __syncthreads();
  if (tid < 32) {
    float e = (tid < TOPK) ? expf(fv[tid]) : 0.f;
    if (tid < TOPK) ew[tid] = e;
    float ss = e;
    #pragma unroll
    for (int off = 16; off > 0; off >>= 1) ss += __shfl_down(ss, off);
    if (tid == 0) sSum = ss;
  }
  __syncthreads();
  if (tid < TOPK) {
    wgt [(size_t)pix * 32 + tid] = ew[tid] / sSum;
    widx[(size_t)pix * 32 + tid] = fi[tid];
  }
}

// ---------------------------------------------------------------------------
// Standalone transpose (fallback, workspace-overlay mode)
// ---------------------------------------------------------------------------
__global__ __launch_bounds__(256)
void k_transpose(const float* __restrict__ mv, float* __restrict__ mvT,
                 int chbase, int ld)
{
  __shared__ float t[64][65];
  const int n0 = blockIdx.x * 64, ch0 = blockIdx.y * 64;
  const int tid = threadIdx.x;
  for (int i = tid; i < 64 * 16; i += 256) {
    int r = i >> 4, c4 = (i & 15) << 2;
    float4 v = *reinterpret_cast<const float4*>(
        &mv[(size_t)(chbase + ch0 + r) * NMEM + n0 + c4]);
    t[r][c4] = v.x; t[r][c4 + 1] = v.y; t[r][c4 + 2] = v.z; t[r][c4 + 3] = v.w;
  }
  __syncthreads();
  for (int i = tid; i < 64 * 16; i += 256) {
    int r = i >> 4, c4 = (i & 15) << 2;
    float4 v = make_float4(t[c4][r], t[c4 + 1][r], t[c4 + 2][r], t[c4 + 3][r]);
    *reinterpret_cast<float4*>(&mvT[(size_t)(n0 + r) * ld + ch0 + c4]) = v;
  }
}

// ---------------------------------------------------------------------------
// Gather: 8-pixel tiles, out[out_chbase+ch][p] = sum_k w[p][k]*src[...]
// ---------------------------------------------------------------------------
__global__ __launch_bounds__(256)
void k_gather(const float* __restrict__ src, const float* __restrict__ wgt,
              const int* __restrict__ widx, float* __restrict__ out,
              int out_chbase, int src_chbase, long n_stride, long ch_stride)
{
  __shared__ float sw[8][TOPK];
  __shared__ int   si[8][TOPK];
  __shared__ float sbuf[256][9];
  const int p0 = blockIdx.x * 8, chg = blockIdx.y * 256;
  const int tid = threadIdx.x;

  for (int i = tid; i < 8 * TOPK; i += 256) {
    int q = i / TOPK, k = i - q * TOPK;
    sw[q][k] = wgt [(size_t)(p0 + q) * 32 + k];
    si[q][k] = widx[(size_t)(p0 + q) * 32 + k];
  }
  __syncthreads();

  const int ch = chg + tid;
  #pragma unroll 2
  for (int q = 0; q < 8; ++q) {
    float a = 0.f;
    #pragma unroll
    for (int k = 0; k < TOPK; ++k)
      a = fmaf(sw[q][k], src[(size_t)si[q][k] * n_stride +
                             (size_t)(src_chbase + ch) * ch_stride], a);
    sbuf[tid][q] = a;
  }
  __syncthreads();

  for (int i = tid; i < 256 * 8; i += 256) {
    int cl = i >> 3, q = i & 7;
    out[(size_t)(out_chbase + chg + cl) * HW + p0 + q] = sbuf[cl][q];
  }
}

// ---------------------------------------------------------------------------
extern "C" void kernel_launch(void* const* d_in, const int* in_sizes, int n_in,
                              void* d_out, int out_size, void* d_ws, size_t ws_size,
                              hipStream_t stream)
{
  (void)in_sizes; (void)n_in; (void)out_size;
  const float* q_key     = (const float*)d_in[0];
  const float* q_sel     = (const float*)d_in[1];
  const float* mem_key   = (const float*)d_in[2];
  const float* mem_shr   = (const float*)d_in[3];
  const float* mem_value = (const float*)d_in[4];
  float* out = (float*)d_out;

  char* ws = (char*)d_ws;
  size_t off = 0;
  auto alloc = [&](size_t b) { size_t c = off; off = (off + b + 255) & ~(size_t)255; return c; };
  size_t o_w   = alloc((size_t)HW * 32 * 4);
  size_t o_wi  = alloc((size_t)HW * 32 * 4);
  size_t o_pr  = off;                              // overlay point (fallback)
  size_t o_bh  = alloc((size_t)NMEM * 128 * 2);    // 7.34 MB (hi only)
  size_t o_uh  = alloc((size_t)HW * 128 * 2);
  size_t o_ul  = alloc((size_t)HW * 128 * 2);
  size_t o_bsq = alloc((size_t)HW * 4);
  size_t o_shr = alloc((size_t)NMEM * 4);
  size_t o_mkT = alloc((size_t)NMEM * 64 * 4);     // 7.34 MB
  size_t o_pm  = alloc((size_t)HW * NCHUNK * 4);   // 25.7 MB
  size_t o_end = off;

  float*          wg   = (float*)(ws + o_w);
  int*            wi   = (int*)  (ws + o_wi);
  unsigned short* Bh   = (unsigned short*)(ws + o_bh);
  unsigned short* Uh   = (unsigned short*)(ws + o_uh);
  unsigned short* Ul   = (unsigned short*)(ws + o_ul);
  float*          bsq  = (float*)(ws + o_bsq);
  float*          shr  = (float*)(ws + o_shr);
  float*          mkT  = (float*)(ws + o_mkT);
  float*          pmx  = (float*)(ws + o_pm);

  const size_t mvT_full = (size_t)NMEM * 1024 * 4;
  const size_t mvT_q    = (size_t)NMEM * 256 * 4;

  k_prep_b<<<NMEM / 256, 256, 0, stream>>>(mem_key, mem_shr, Bh, mkT, shr);
  k_prep_u<<<HW / 256, 256, 0, stream>>>(q_key, q_sel, Uh, Ul, bsq);

  if (ws_size >= o_end + mvT_full) {
    // fused: sim + transpose interleaved 7:16 in one launch
    float* mvT = (float*)(ws + o_end);
    k_phaseA<<<SIMB + TRB, 256, 0, stream>>>(Uh, Ul, Bh, bsq, shr, pmx,
                                             mem_value, mvT);
    k_select<<<HW, 256, 0, stream>>>(pmx, mkT, q_key, q_sel, shr, wg, wi);
    k_gather<<<dim3(HW / 8, 4), 256, 0, stream>>>(mvT, wg, wi, out, 0, 0, 1024, 1);
  } else {
    // fallback: sequential, mvT overlays dead prep region after select
    k_phaseA<<<SIMB, 256, 0, stream>>>(Uh, Ul, Bh, bsq, shr, pmx,
                                       mem_value, nullptr);
    k_select<<<HW, 256, 0, stream>>>(pmx, mkT, q_key, q_sel, shr, wg, wi);
    float* mvT = (float*)(ws + o_pr); int chld; bool raw = false;
    if      (ws_size >= o_pr + mvT_full) chld = 1024;
    else if (ws_size >= o_pr + mvT_q)    chld = 256;
    else raw = true;
    if (!raw) {
      for (int g = 0; g < 1024 / chld; ++g) {
        k_transpose<<<dim3(NMEM / 64, chld / 64), 256, 0, stream>>>(
            mem_value, mvT, g * chld, chld);
        k_gather<<<dim3(HW / 8, chld / 256), 256, 0, stream>>>(
            mvT, wg, wi, out, g * chld, 0, chld, 1);
      }
    } else {
      k_gather<<<dim3(HW / 8, 4), 256, 0, stream>>>(
          mem_value, wg, wi, out, 0, 0, 1, NMEM);
    }
  }
}

// Round 7
// 195.580 us; speedup vs baseline: 4.6127x; 1.1613x over previous
//
#include <hip/hip_runtime.h>
#include <math.h>

#define HW      1792
#define NMEM    28672
#define NCHUNK  3584          // NMEM/8 chunks of 8
#define TOPK    30
#define CTARGET 64
#define BINS    4096
#define VCACHE  3072
#define SIMB    224           // 14 p-blocks(128px) x 16 strips
#define TRB     7168          // (NMEM/64) * (1024/64)
#define WPS     14            // 128-n windows per strip

typedef __attribute__((ext_vector_type(8))) short bf16x8;
typedef __attribute__((ext_vector_type(8))) unsigned short u16x8;
typedef __attribute__((ext_vector_type(4))) float f32x4;
typedef __attribute__((ext_vector_type(4))) _Float16 h4;

static __device__ __forceinline__ unsigned short f2bf(float v) {
  unsigned b = __float_as_uint(v);
  return (unsigned short)((b + 0x7FFFu + ((b >> 16) & 1u)) >> 16);
}
static __device__ __forceinline__ float bf2f(unsigned short h) {
  return __uint_as_float(((unsigned)h) << 16);
}
static __device__ __forceinline__ unsigned fkey(float v) {
  return __float_as_uint(-v) & 0x7FFFFFFFu;
}
static __device__ __forceinline__ void gl_lds16(const void* g, void* l) {
  __builtin_amdgcn_global_load_lds(
      (const __attribute__((address_space(1))) unsigned*)g,
      (__attribute__((address_space(3))) unsigned*)l, 16, 0, 0);
}

// ---------------------------------------------------------------------------
// Prep B: Bh[s][n][8] bf16-hi (s=0..7: mk, s=8..15: mk^2); mkT[n][64] fp32;
// shr_s = mem_shr/8. (B-lo dropped: ~2e-3 sim error absorbed by CTARGET=64
// margin; final sims recomputed exactly in fp32.)
// ---------------------------------------------------------------------------
__global__ __launch_bounds__(256)
void k_prep_b(const float* __restrict__ mk, const float* __restrict__ shr_in,
              unsigned short* __restrict__ Bh,
              float* __restrict__ mkT, float* __restrict__ shr_s)
{
  const int n = blockIdx.x * 256 + threadIdx.x;
  shr_s[n] = shr_in[n] * 0.125f;
  for (int cb = 0; cb < 64; cb += 8) {
    u16x8 h1, h2;
    float vv[8];
    #pragma unroll
    for (int j = 0; j < 8; ++j) {
      float v = mk[(size_t)(cb + j) * NMEM + n];
      vv[j] = v;
      h1[j] = f2bf(v);
      h2[j] = f2bf(v * v);
    }
    const int s = cb >> 3;
    *reinterpret_cast<u16x8*>(&Bh[((size_t)s * NMEM + n) * 8])       = h1;
    *reinterpret_cast<u16x8*>(&Bh[((size_t)(s + 8) * NMEM + n) * 8]) = h2;
    *reinterpret_cast<float4*>(&mkT[(size_t)n * 64 + cb])     = make_float4(vv[0], vv[1], vv[2], vv[3]);
    *reinterpret_cast<float4*>(&mkT[(size_t)n * 64 + cb + 4]) = make_float4(vv[4], vv[5], vv[6], vv[7]);
  }
}

// ---------------------------------------------------------------------------
// Prep U: Uh/Ul[s][p][8] bf16 hi/lo. s=0..7: 2*qk*qs, s=8..15: -qs. bsq[p].
// ---------------------------------------------------------------------------
__global__ __launch_bounds__(256)
void k_prep_u(const float* __restrict__ q_key, const float* __restrict__ q_sel,
              unsigned short* __restrict__ Uh, unsigned short* __restrict__ Ul,
              float* __restrict__ bsq)
{
  const int p = blockIdx.x * 256 + threadIdx.x;
  float bs = 0.f;
  for (int cb = 0; cb < 64; cb += 8) {
    u16x8 h1, l1, h2, l2;
    #pragma unroll
    for (int j = 0; j < 8; ++j) {
      int c = cb + j;
      float k = q_key[(size_t)c * HW + p];
      float s = q_sel[(size_t)c * HW + p];
      float u = 2.f * k * s;
      float w = -s;
      bs = fmaf(s * k, k, bs);
      unsigned short h = f2bf(u); h1[j] = h; l1[j] = f2bf(u - bf2f(h));
      unsigned short g = f2bf(w); h2[j] = g; l2[j] = f2bf(w - bf2f(g));
    }
    const int s = cb >> 3;
    *reinterpret_cast<u16x8*>(&Uh[((size_t)s * HW + p) * 8])       = h1;
    *reinterpret_cast<u16x8*>(&Ul[((size_t)s * HW + p) * 8])       = l1;
    *reinterpret_cast<u16x8*>(&Uh[((size_t)(s + 8) * HW + p) * 8]) = h2;
    *reinterpret_cast<u16x8*>(&Ul[((size_t)(s + 8) * HW + p) * 8]) = l2;
  }
  bsq[p] = bs;
}

// ---------------------------------------------------------------------------
// Fused phase A.
// sim blocks: 128 pixels x 14-window strip. Full K=128 in LDS per window
// ([16 slabs][128 rows][16B] = 32 KB, dbuf 64 KB). One barrier per window;
// next-window global_load_lds issued right after the barrier so staging
// latency hides under ~128 MFMA/wave of compute. acc reset per window,
// chunk-max epilogue identical encoding to before (chunk = w*16+lr).
// transpose blocks: mem_value fp32 -> mvT fp16 [n][1024].
// ---------------------------------------------------------------------------
__global__ __launch_bounds__(256, 2)
void k_phaseA(const unsigned short* __restrict__ Uh, const unsigned short* __restrict__ Ul,
              const unsigned short* __restrict__ Bh,
              const float* __restrict__ bsq, const float* __restrict__ shr_s,
              float* __restrict__ pmax,
              const float* __restrict__ mv, _Float16* __restrict__ mvT)
{
  __shared__ char smem[65536] __attribute__((aligned(16)));
  const int tid = threadIdx.x;

  int sb = -1, tb = -1;
  if (gridDim.x > SIMB) {
    const int g = blockIdx.x / 33, r = blockIdx.x % 33;
    if (r == 0) sb = g; else tb = g * 32 + (r - 1);
  } else {
    sb = blockIdx.x;
  }

  if (sb >= 0) {
    const int wid = tid >> 6, lane = tid & 63;
    const int lr = lane & 15, lg = lane >> 4;
    const int pb = sb % 14, st = sb / 14;
    const int pw = pb * 128 + wid * 32;
    const int w0 = st * WPS;            // first global window of strip

    // A fragments (hi+lo) for all K, and bsq, in registers
    bf16x8 a0h[4], a0l[4], a1h[4], a1l[4];
    #pragma unroll
    for (int t = 0; t < 4; ++t) {
      const size_t e0 = ((size_t)(t * 4 + lg) * HW + pw + lr) * 8;
      const size_t e1 = e0 + 16 * 8;
      a0h[t] = *reinterpret_cast<const bf16x8*>(&Uh[e0]);
      a0l[t] = *reinterpret_cast<const bf16x8*>(&Ul[e0]);
      a1h[t] = *reinterpret_cast<const bf16x8*>(&Uh[e1]);
      a1l[t] = *reinterpret_cast<const bf16x8*>(&Ul[e1]);
    }
    float bq[2][4];
    #pragma unroll
    for (int pt = 0; pt < 2; ++pt)
      #pragma unroll
      for (int r = 0; r < 4; ++r) bq[pt][r] = bsq[pw + pt * 16 + 4 * lg + r];

    // stage window i of this strip into buf (2048 x 16B, linear lane order)
    auto stage = [&](int buf, int i) {
      const int n0 = (w0 + i) * 128;
      #pragma unroll
      for (int j = 0; j < 8; ++j) {
        const int idx = j * 256 + tid;
        const int s = idx >> 7, rr = idx & 127;
        gl_lds16((const char*)Bh + ((size_t)s * NMEM + n0 + rr) * 16,
                 smem + buf * 32768 + idx * 16);
      }
    };

    stage(0, 0);
    int buf = 0;
    for (int i = 0; i < WPS; ++i) {
      __syncthreads();                    // buf ready; buf^1 free
      if (i + 1 < WPS) stage(buf ^ 1, i + 1);

      f32x4 acc[2][8];
      #pragma unroll
      for (int a = 0; a < 2; ++a)
        #pragma unroll
        for (int b = 0; b < 8; ++b) acc[a][b] = (f32x4){0.f, 0.f, 0.f, 0.f};

      const short* lb = (const short*)(smem + buf * 32768);
      #pragma unroll
      for (int t = 0; t < 4; ++t) {
        #pragma unroll
        for (int nt = 0; nt < 8; ++nt) {
          bf16x8 bh = *reinterpret_cast<const bf16x8*>(
              &lb[((t * 4 + lg) * 128 + nt * 16 + lr) * 8]);
          acc[0][nt] = __builtin_amdgcn_mfma_f32_16x16x32_bf16(a0h[t], bh, acc[0][nt], 0, 0, 0);
          acc[0][nt] = __builtin_amdgcn_mfma_f32_16x16x32_bf16(a0l[t], bh, acc[0][nt], 0, 0, 0);
          acc[1][nt] = __builtin_amdgcn_mfma_f32_16x16x32_bf16(a1h[t], bh, acc[1][nt], 0, 0, 0);
          acc[1][nt] = __builtin_amdgcn_mfma_f32_16x16x32_bf16(a1l[t], bh, acc[1][nt], 0, 0, 0);
        }
      }

      const int wgl = w0 + i;
      const int n0 = wgl * 128;
      float shv[8];
      #pragma unroll
      for (int nt = 0; nt < 8; ++nt) shv[nt] = shr_s[n0 + nt * 16 + lr];
      #pragma unroll
      for (int pt = 0; pt < 2; ++pt) {
        #pragma unroll
        for (int r = 0; r < 4; ++r) {
          float mx = -INFINITY;
          #pragma unroll
          for (int nt = 0; nt < 8; ++nt)
            mx = fmaxf(mx, (acc[pt][nt][r] - bq[pt][r]) * shv[nt]);
          pmax[(size_t)(pw + pt * 16 + 4 * lg + r) * NCHUNK + wgl * 16 + lr] = mx;
        }
      }
      buf ^= 1;
    }
  } else {
    // ---- transpose block: 64n x 64ch fp32 -> fp16
    float (*tt)[65] = (float(*)[65])smem;
    const int n0 = (tb % 448) * 64, ch0 = (tb / 448) * 64;
    for (int i = tid; i < 64 * 16; i += 256) {
      int r = i >> 4, c4 = (i & 15) << 2;
      float4 v = *reinterpret_cast<const float4*>(&mv[(size_t)(ch0 + r) * NMEM + n0 + c4]);
      tt[r][c4] = v.x; tt[r][c4 + 1] = v.y; tt[r][c4 + 2] = v.z; tt[r][c4 + 3] = v.w;
    }
    __syncthreads();
    for (int i = tid; i < 64 * 16; i += 256) {
      int r = i >> 4, c4 = (i & 15) << 2;
      h4 hv = {(_Float16)tt[c4][r], (_Float16)tt[c4 + 1][r],
               (_Float16)tt[c4 + 2][r], (_Float16)tt[c4 + 3][r]};
      *reinterpret_cast<h4*>(&mvT[(size_t)(n0 + r) * 1024 + ch0 + c4]) = hv;
    }
  }
}

// ---------------------------------------------------------------------------
// crossing finder: smallest bin B with prefix(<B) < target <= prefix(<=B)
// ---------------------------------------------------------------------------
__device__ __forceinline__ void find_cross(int* hist, int* lsum, int* wsum,
                                           int tid, int target, int* sB, int* sNA)
{
  const int base = tid * (BINS / 256);
  int ls = 0;
  #pragma unroll
  for (int k = 0; k < BINS / 256; ++k) ls += hist[base + k];
  lsum[tid] = ls;
  __syncthreads();
  int lane = tid & 63, wv = tid >> 6;
  int v = ls;
  #pragma unroll
  for (int off = 1; off < 64; off <<= 1) {
    int t = __shfl_up(v, off);
    if (lane >= off) v += t;
  }
  if (lane == 63) wsum[wv] = v;
  __syncthreads();
  int wo = 0;
  for (int k = 0; k < wv; ++k) wo += wsum[k];
  int run = wo + v - ls;
  #pragma unroll 1
  for (int k = 0; k < BINS / 256; ++k) {
    int h = hist[base + k];
    if (run < target && run + h >= target) { *sB = base + k; *sNA = run; }
    run += h;
  }
  __syncthreads();
}

// ---------------------------------------------------------------------------
// Kernel: per-pixel exact top-30 via chunk-max pruning + exact recompute.
// ---------------------------------------------------------------------------
__global__ __launch_bounds__(256)
void k_select(const float* __restrict__ pmax, const float* __restrict__ mkT,
              const float* __restrict__ q_key, const float* __restrict__ q_sel,
              const float* __restrict__ shr_s,
              float* __restrict__ wgt, int* __restrict__ widx)
{
  __shared__ int            hist[BINS];
  __shared__ float          sqk[64], sqs[64];
  __shared__ unsigned short chl[NCHUNK];
  __shared__ float          vcache[VCACHE];
  __shared__ unsigned       au[96];
  __shared__ int            ai[96];
  __shared__ unsigned       bu[1024];
  __shared__ int            bi[1024];
  __shared__ float          fv[32];
  __shared__ int            fi[32];
  __shared__ float          ew[32];
  __shared__ int            lsum[256], wsum[4];
  __shared__ int            sB, sNA, cA, cB, sSC;
  __shared__ float          sSum;

  const int pix = blockIdx.x;
  const int tid = threadIdx.x;

  if (tid < 64) {
    sqk[tid] = q_key[(size_t)tid * HW + pix];
    sqs[tid] = q_sel[(size_t)tid * HW + pix];
  }
  for (int i = tid; i < BINS; i += 256) hist[i] = 0;
  if (tid == 0) { sSC = 0; cA = 0; cB = 0; }
  __syncthreads();

  // ---- stage 1: chunk maxima -> CTARGET-crossing bin -> survivor chunks
  float m[NCHUNK / 256];
  const float* pm = pmax + (size_t)pix * NCHUNK;
  #pragma unroll
  for (int j = 0; j < NCHUNK / 256; ++j) m[j] = pm[tid + 256 * j];
  #pragma unroll
  for (int j = 0; j < NCHUNK / 256; ++j) atomicAdd(&hist[fkey(m[j]) >> 19], 1);
  __syncthreads();
  find_cross(hist, lsum, wsum, tid, CTARGET, &sB, &sNA);
  {
    const int B = sB;
    #pragma unroll
    for (int j = 0; j < NCHUNK / 256; ++j)
      if ((int)(fkey(m[j]) >> 19) <= B) {
        int k = atomicAdd(&sSC, 1);
        chl[k] = (unsigned short)(tid + 256 * j);
      }
  }
  __syncthreads();
  const int SC = sSC, NC = SC * 8;
  for (int i = tid; i < BINS; i += 256) hist[i] = 0;
  __syncthreads();

  const float4* sqk4 = reinterpret_cast<const float4*>(sqk);
  const float4* sqs4 = reinterpret_cast<const float4*>(sqs);

  // ---- stage 2 pass X: exact fp32 sims of candidates + histogram
  for (int c = tid; c < NC; c += 256) {
    const int cc = chl[c >> 3];
    const int n = ((cc >> 4) << 7) + (cc & 15) + ((c & 7) << 4);
    const float4* mr = reinterpret_cast<const float4*>(mkT + (size_t)n * 64);
    float s = 0.f;
    #pragma unroll
    for (int j = 0; j < 16; ++j) {
      float4 q = mr[j], k4 = sqk4[j], s4 = sqs4[j];
      float d0 = q.x - k4.x, d1 = q.y - k4.y, d2 = q.z - k4.z, d3 = q.w - k4.w;
      s = fmaf(s4.x * d0, d0, s); s = fmaf(s4.y * d1, d1, s);
      s = fmaf(s4.z * d2, d2, s); s = fmaf(s4.w * d3, d3, s);
    }
    float v = -s * shr_s[n];
    if (c < VCACHE) vcache[c] = v;
    atomicAdd(&hist[fkey(v) >> 19], 1);
  }
  __syncthreads();
  find_cross(hist, lsum, wsum, tid, TOPK, &sB, &sNA);

  // ---- stage 2 pass Y: collect top-30 (bins < B2) + boundary rank-cut
  {
    const int B2 = sB;
    for (int c = tid; c < NC; c += 256) {
      const int cc = chl[c >> 3];
      const int n = ((cc >> 4) << 7) + (cc & 15) + ((c & 7) << 4);
      float v;
      if (c < VCACHE) v = vcache[c];
      else {
        const float4* mr = reinterpret_cast<const float4*>(mkT + (size_t)n * 64);
        float s = 0.f;
        #pragma unroll
        for (int j = 0; j < 16; ++j) {
          float4 q = mr[j], k4 = sqk4[j], s4 = sqs4[j];
          float d0 = q.x - k4.x, d1 = q.y - k4.y, d2 = q.z - k4.z, d3 = q.w - k4.w;
          s = fmaf(s4.x * d0, d0, s); s = fmaf(s4.y * d1, d1, s);
          s = fmaf(s4.z * d2, d2, s); s = fmaf(s4.w * d3, d3, s);
        }
        v = -s * shr_s[n];
      }
      unsigned u = fkey(v);
      int bin = (int)(u >> 19);
      if (bin < B2)       { int k = atomicAdd(&cA, 1); au[k] = u; ai[k] = n; }
      else if (bin == B2) { int k = atomicAdd(&cB, 1); if (k < 1024) { bu[k] = u; bi[k] = n; } }
    }
  }
  __syncthreads();
  {
    const int nAv = cA, mm = (cB < 1024 ? cB : 1024), need = TOPK - nAv;
    for (int t = tid; t < mm; t += 256) {
      unsigned u = bu[t]; int id = bi[t];
      int r = 0;
      for (int k2 = 0; k2 < mm; ++k2) {
        unsigned uk = bu[k2];
        r += (uk < u) || (uk == u && bi[k2] < id);
      }
      if (r < need) { au[nAv + r] = u; ai[nAv + r] = id; }
    }
  }
  __syncthreads();

  // ---- deterministic ordering of the 30 + softmax
  if (tid < TOPK) {
    unsigned u = au[tid]; int id = ai[tid];
    int r = 0;
    for (int k2 = 0; k2 < TOPK; ++k2) {
      unsigned uk = au[k2];
      r += (uk < u) || (uk == u && ai[k2] < id);
    }
    fv[r] = -__uint_as_float(u); fi[r] = id;
  }
  __syncthreads();
  if (tid < 32) {
    float e = (tid < TOPK) ? expf(fv[tid]) : 0.f;
    if (tid < TOPK) ew[tid] = e;
    float ss = e;
    #pragma unroll
    for (int off = 16; off > 0; off >>= 1) ss += __shfl_down(ss, off);
    if (tid == 0) sSum = ss;
  }
  __syncthreads();
  if (tid < TOPK) {
    wgt [(size_t)pix * 32 + tid] = ew[tid] / sSum;
    widx[(size_t)pix * 32 + tid] = fi[tid];
  }
}

// ---------------------------------------------------------------------------
// Standalone fp16 transpose (fallback, overlay mode)
// ---------------------------------------------------------------------------
__global__ __launch_bounds__(256)
void k_transpose_h(const float* __restrict__ mv, _Float16* __restrict__ mvT)
{
  __shared__ float t[64][65];
  const int n0 = blockIdx.x * 64, ch0 = blockIdx.y * 64;
  const int tid = threadIdx.x;
  for (int i = tid; i < 64 * 16; i += 256) {
    int r = i >> 4, c4 = (i & 15) << 2;
    float4 v = *reinterpret_cast<const float4*>(&mv[(size_t)(ch0 + r) * NMEM + n0 + c4]);
    t[r][c4] = v.x; t[r][c4 + 1] = v.y; t[r][c4 + 2] = v.z; t[r][c4 + 3] = v.w;
  }
  __syncthreads();
  for (int i = tid; i < 64 * 16; i += 256) {
    int r = i >> 4, c4 = (i & 15) << 2;
    h4 hv = {(_Float16)t[c4][r], (_Float16)t[c4 + 1][r],
             (_Float16)t[c4 + 2][r], (_Float16)t[c4 + 3][r]};
    *reinterpret_cast<h4*>(&mvT[(size_t)(n0 + r) * 1024 + ch0 + c4]) = hv;
  }
}

// ---------------------------------------------------------------------------
// Gather (fp16 source): out[ch][p] = sum_k w[p][k] * mvT[idx[p][k]][ch]
// ---------------------------------------------------------------------------
__global__ __launch_bounds__(256)
void k_gather_h(const _Float16* __restrict__ mvT, const float* __restrict__ wgt,
                const int* __restrict__ widx, float* __restrict__ out)
{
  __shared__ float sw[8][TOPK];
  __shared__ int   si[8][TOPK];
  __shared__ float sbuf[256][9];
  const int p0 = blockIdx.x * 8, chg = blockIdx.y * 256;
  const int tid = threadIdx.x;

  for (int i = tid; i < 8 * TOPK; i += 256) {
    int q = i / TOPK, k = i - q * TOPK;
    sw[q][k] = wgt [(size_t)(p0 + q) * 32 + k];
    si[q][k] = widx[(size_t)(p0 + q) * 32 + k];
  }
  __syncthreads();

  const int ch = chg + tid;
  #pragma unroll 2
  for (int q = 0; q < 8; ++q) {
    float a = 0.f;
    #pragma unroll
    for (int k = 0; k < TOPK; ++k)
      a = fmaf(sw[q][k], (float)mvT[(size_t)si[q][k] * 1024 + ch], a);
    sbuf[tid][q] = a;
  }
  __syncthreads();

  for (int i = tid; i < 256 * 8; i += 256) {
    int cl = i >> 3, q = i & 7;
    out[(size_t)(chg + cl) * HW + p0 + q] = sbuf[cl][q];
  }
}

// ---------------------------------------------------------------------------
// Gather (fp32 strided source, raw fallback)
// ---------------------------------------------------------------------------
__global__ __launch_bounds__(256)
void k_gather_f(const float* __restrict__ src, const float* __restrict__ wgt,
                const int* __restrict__ widx, float* __restrict__ out,
                long n_stride, long ch_stride)
{
  __shared__ float sw[8][TOPK];
  __shared__ int   si[8][TOPK];
  __shared__ float sbuf[256][9];
  const int p0 = blockIdx.x * 8, chg = blockIdx.y * 256;
  const int tid = threadIdx.x;

  for (int i = tid; i < 8 * TOPK; i += 256) {
    int q = i / TOPK, k = i - q * TOPK;
    sw[q][k] = wgt [(size_t)(p0 + q) * 32 + k];
    si[q][k] = widx[(size_t)(p0 + q) * 32 + k];
  }
  __syncthreads();

  const int ch = chg + tid;
  #pragma unroll 2
  for (int q = 0; q < 8; ++q) {
    float a = 0.f;
    #pragma unroll
    for (int k = 0; k < TOPK; ++k)
      a = fmaf(sw[q][k], src[(size_t)si[q][k] * n_stride + (size_t)ch * ch_stride], a);
    sbuf[tid][q] = a;
  }
  __syncthreads();

  for (int i = tid; i < 256 * 8; i += 256) {
    int cl = i >> 3, q = i & 7;
    out[(size_t)(chg + cl) * HW + p0 + q] = sbuf[cl][q];
  }
}

// ---------------------------------------------------------------------------
extern "C" void kernel_launch(void* const* d_in, const int* in_sizes, int n_in,
                              void* d_out, int out_size, void* d_ws, size_t ws_size,
                              hipStream_t stream)
{
  (void)in_sizes; (void)n_in; (void)out_size;
  const float* q_key     = (const float*)d_in[0];
  const float* q_sel     = (const float*)d_in[1];
  const float* mem_key   = (const float*)d_in[2];
  const float* mem_shr   = (const float*)d_in[3];
  const float* mem_value = (const float*)d_in[4];
  float* out = (float*)d_out;

  char* ws = (char*)d_ws;
  size_t off = 0;
  auto alloc = [&](size_t b) { size_t c = off; off = (off + b + 255) & ~(size_t)255; return c; };
  size_t o_w   = alloc((size_t)HW * 32 * 4);
  size_t o_wi  = alloc((size_t)HW * 32 * 4);
  size_t o_pr  = off;                              // overlay point (fallback)
  size_t o_bh  = alloc((size_t)NMEM * 128 * 2);    // 7.34 MB
  size_t o_uh  = alloc((size_t)HW * 128 * 2);
  size_t o_ul  = alloc((size_t)HW * 128 * 2);
  size_t o_bsq = alloc((size_t)HW * 4);
  size_t o_shr = alloc((size_t)NMEM * 4);
  size_t o_mkT = alloc((size_t)NMEM * 64 * 4);     // 7.34 MB
  size_t o_pm  = alloc((size_t)HW * NCHUNK * 4);   // 25.7 MB
  size_t o_end = off;

  float*          wg   = (float*)(ws + o_w);
  int*            wi   = (int*)  (ws + o_wi);
  unsigned short* Bh   = (unsigned short*)(ws + o_bh);
  unsigned short* Uh   = (unsigned short*)(ws + o_uh);
  unsigned short* Ul   = (unsigned short*)(ws + o_ul);
  float*          bsq  = (float*)(ws + o_bsq);
  float*          shr  = (float*)(ws + o_shr);
  float*          mkT  = (float*)(ws + o_mkT);
  float*          pmx  = (float*)(ws + o_pm);

  const size_t mvh_sz = (size_t)NMEM * 1024 * 2;   // 58.7 MB fp16

  k_prep_b<<<NMEM / 256, 256, 0, stream>>>(mem_key, mem_shr, Bh, mkT, shr);
  k_prep_u<<<HW / 256, 256, 0, stream>>>(q_key, q_sel, Uh, Ul, bsq);

  if (ws_size >= o_end + mvh_sz) {
    // fused: sim (224 long blocks) + transpose (7168), interleaved 1:32
    _Float16* mvT = (_Float16*)(ws + o_end);
    k_phaseA<<<SIMB * 33, 256, 0, stream>>>(Uh, Ul, Bh, bsq, shr, pmx,
                                            mem_value, mvT);
    k_select<<<HW, 256, 0, stream>>>(pmx, mkT, q_key, q_sel, shr, wg, wi);
    k_gather_h<<<dim3(HW / 8, 4), 256, 0, stream>>>(mvT, wg, wi, out);
  } else {
    // fallback: sim only, then select, then transpose into overlay region
    k_phaseA<<<SIMB, 256, 0, stream>>>(Uh, Ul, Bh, bsq, shr, pmx,
                                       mem_value, nullptr);
    k_select<<<HW, 256, 0, stream>>>(pmx, mkT, q_key, q_sel, shr, wg, wi);
    if (ws_size >= o_pr + mvh_sz) {
      _Float16* mvT = (_Float16*)(ws + o_pr);      // Bh..pmx dead after select
      k_transpose_h<<<dim3(NMEM / 64, 16), 256, 0, stream>>>(mem_value, mvT);
      k_gather_h<<<dim3(HW / 8, 4), 256, 0, stream>>>(mvT, wg, wi, out);
    } else {
      k_gather_f<<<dim3(HW / 8, 4), 256, 0, stream>>>(
          mem_value, wg, wi, out, 1, NMEM);
    }
  }
}

// Round 8
// 172.062 us; speedup vs baseline: 5.2432x; 1.1367x over previous
//
#include <hip/hip_runtime.h>
#include <math.h>

#define HW      1792
#define NMEM    28672
#define NCHUNK  3584          // NMEM/8 chunks of 8
#define TOPK    30
#define CTARGET 64
#define BINS    4096
#define VCACHE  3072
#define SIMB    448           // 14 p-blocks(128px) x 32 strips
#define WPS     7             // 128-n windows per strip

typedef __attribute__((ext_vector_type(8))) short bf16x8;
typedef __attribute__((ext_vector_type(8))) unsigned short u16x8;
typedef __attribute__((ext_vector_type(4))) float f32x4;
typedef __attribute__((ext_vector_type(4))) _Float16 h4;

static __device__ __forceinline__ unsigned short f2bf(float v) {
  unsigned b = __float_as_uint(v);
  return (unsigned short)((b + 0x7FFFu + ((b >> 16) & 1u)) >> 16);
}
static __device__ __forceinline__ float bf2f(unsigned short h) {
  return __uint_as_float(((unsigned)h) << 16);
}
static __device__ __forceinline__ unsigned fkey(float v) {
  return __float_as_uint(-v) & 0x7FFFFFFFu;
}
static __device__ __forceinline__ void gl_lds16(const void* g, void* l) {
  __builtin_amdgcn_global_load_lds(
      (const __attribute__((address_space(1))) unsigned*)g,
      (__attribute__((address_space(3))) unsigned*)l, 16, 0, 0);
}

// ---------------------------------------------------------------------------
// Prep B: Bh[s][n][8] bf16-hi (s=0..7: mk, s=8..15: mk^2); mkT[n][64] fp32;
// shr_s = mem_shr/8. (B-lo dropped: ~2e-3 sim error absorbed by CTARGET=64
// margin; final sims recomputed exactly in fp32.)
// ---------------------------------------------------------------------------
__global__ __launch_bounds__(256)
void k_prep_b(const float* __restrict__ mk, const float* __restrict__ shr_in,
              unsigned short* __restrict__ Bh,
              float* __restrict__ mkT, float* __restrict__ shr_s)
{
  const int n = blockIdx.x * 256 + threadIdx.x;
  shr_s[n] = shr_in[n] * 0.125f;
  for (int cb = 0; cb < 64; cb += 8) {
    u16x8 h1, h2;
    float vv[8];
    #pragma unroll
    for (int j = 0; j < 8; ++j) {
      float v = mk[(size_t)(cb + j) * NMEM + n];
      vv[j] = v;
      h1[j] = f2bf(v);
      h2[j] = f2bf(v * v);
    }
    const int s = cb >> 3;
    *reinterpret_cast<u16x8*>(&Bh[((size_t)s * NMEM + n) * 8])       = h1;
    *reinterpret_cast<u16x8*>(&Bh[((size_t)(s + 8) * NMEM + n) * 8]) = h2;
    *reinterpret_cast<float4*>(&mkT[(size_t)n * 64 + cb])     = make_float4(vv[0], vv[1], vv[2], vv[3]);
    *reinterpret_cast<float4*>(&mkT[(size_t)n * 64 + cb + 4]) = make_float4(vv[4], vv[5], vv[6], vv[7]);
  }
}

// ---------------------------------------------------------------------------
// Prep U: Uh/Ul[s][p][8] bf16 hi/lo. s=0..7: 2*qk*qs, s=8..15: -qs. bsq[p].
// ---------------------------------------------------------------------------
__global__ __launch_bounds__(256)
void k_prep_u(const float* __restrict__ q_key, const float* __restrict__ q_sel,
              unsigned short* __restrict__ Uh, unsigned short* __restrict__ Ul,
              float* __restrict__ bsq)
{
  const int p = blockIdx.x * 256 + threadIdx.x;
  float bs = 0.f;
  for (int cb = 0; cb < 64; cb += 8) {
    u16x8 h1, l1, h2, l2;
    #pragma unroll
    for (int j = 0; j < 8; ++j) {
      int c = cb + j;
      float k = q_key[(size_t)c * HW + p];
      float s = q_sel[(size_t)c * HW + p];
      float u = 2.f * k * s;
      float w = -s;
      bs = fmaf(s * k, k, bs);
      unsigned short h = f2bf(u); h1[j] = h; l1[j] = f2bf(u - bf2f(h));
      unsigned short g = f2bf(w); h2[j] = g; l2[j] = f2bf(w - bf2f(g));
    }
    const int s = cb >> 3;
    *reinterpret_cast<u16x8*>(&Uh[((size_t)s * HW + p) * 8])       = h1;
    *reinterpret_cast<u16x8*>(&Ul[((size_t)s * HW + p) * 8])       = l1;
    *reinterpret_cast<u16x8*>(&Uh[((size_t)(s + 8) * HW + p) * 8]) = h2;
    *reinterpret_cast<u16x8*>(&Ul[((size_t)(s + 8) * HW + p) * 8]) = l2;
  }
  bsq[p] = bs;
}

// ---------------------------------------------------------------------------
// Sim kernel: 128 pixels x 7-window strip per block (448 blocks).
// Full K=128 in LDS per 128-n window ([16 slabs][128 rows][16B] = 32 KB,
// dbuf 64 KB). One barrier per window; next-window global_load_lds issued
// right after. Chunk-max epilogue (chunk = wgl*16+lr, 8 elems n+16t).
// ---------------------------------------------------------------------------
__global__ __launch_bounds__(256, 2)
void k_sim(const unsigned short* __restrict__ Uh, const unsigned short* __restrict__ Ul,
           const unsigned short* __restrict__ Bh,
           const float* __restrict__ bsq, const float* __restrict__ shr_s,
           float* __restrict__ pmax)
{
  __shared__ char smem[65536] __attribute__((aligned(16)));
  const int tid = threadIdx.x;
  const int wid = tid >> 6, lane = tid & 63;
  const int lr = lane & 15, lg = lane >> 4;
  const int pb = blockIdx.x % 14, st = blockIdx.x / 14;
  const int pw = pb * 128 + wid * 32;
  const int w0 = st * WPS;

  // A fragments (hi+lo) for all K, and bsq, in registers
  bf16x8 a0h[4], a0l[4], a1h[4], a1l[4];
  #pragma unroll
  for (int t = 0; t < 4; ++t) {
    const size_t e0 = ((size_t)(t * 4 + lg) * HW + pw + lr) * 8;
    const size_t e1 = e0 + 16 * 8;
    a0h[t] = *reinterpret_cast<const bf16x8*>(&Uh[e0]);
    a0l[t] = *reinterpret_cast<const bf16x8*>(&Ul[e0]);
    a1h[t] = *reinterpret_cast<const bf16x8*>(&Uh[e1]);
    a1l[t] = *reinterpret_cast<const bf16x8*>(&Ul[e1]);
  }
  float bq[2][4];
  #pragma unroll
  for (int pt = 0; pt < 2; ++pt)
    #pragma unroll
    for (int r = 0; r < 4; ++r) bq[pt][r] = bsq[pw + pt * 16 + 4 * lg + r];

  auto stage = [&](int buf, int i) {
    const int n0 = (w0 + i) * 128;
    #pragma unroll
    for (int j = 0; j < 8; ++j) {
      const int idx = j * 256 + tid;
      const int s = idx >> 7, rr = idx & 127;
      gl_lds16((const char*)Bh + ((size_t)s * NMEM + n0 + rr) * 16,
               smem + buf * 32768 + idx * 16);
    }
  };

  stage(0, 0);
  int buf = 0;
  for (int i = 0; i < WPS; ++i) {
    __syncthreads();                    // buf ready; buf^1 free
    if (i + 1 < WPS) stage(buf ^ 1, i + 1);

    f32x4 acc[2][8];
    #pragma unroll
    for (int a = 0; a < 2; ++a)
      #pragma unroll
      for (int b = 0; b < 8; ++b) acc[a][b] = (f32x4){0.f, 0.f, 0.f, 0.f};

    const short* lb = (const short*)(smem + buf * 32768);
    #pragma unroll
    for (int t = 0; t < 4; ++t) {
      #pragma unroll
      for (int nt = 0; nt < 8; ++nt) {
        bf16x8 bh = *reinterpret_cast<const bf16x8*>(
            &lb[((t * 4 + lg) * 128 + nt * 16 + lr) * 8]);
        acc[0][nt] = __builtin_amdgcn_mfma_f32_16x16x32_bf16(a0h[t], bh, acc[0][nt], 0, 0, 0);
        acc[0][nt] = __builtin_amdgcn_mfma_f32_16x16x32_bf16(a0l[t], bh, acc[0][nt], 0, 0, 0);
        acc[1][nt] = __builtin_amdgcn_mfma_f32_16x16x32_bf16(a1h[t], bh, acc[1][nt], 0, 0, 0);
        acc[1][nt] = __builtin_amdgcn_mfma_f32_16x16x32_bf16(a1l[t], bh, acc[1][nt], 0, 0, 0);
      }
    }

    const int wgl = w0 + i;
    const int n0 = wgl * 128;
    float shv[8];
    #pragma unroll
    for (int nt = 0; nt < 8; ++nt) shv[nt] = shr_s[n0 + nt * 16 + lr];
    #pragma unroll
    for (int pt = 0; pt < 2; ++pt) {
      #pragma unroll
      for (int r = 0; r < 4; ++r) {
        float mx = -INFINITY;
        #pragma unroll
        for (int nt = 0; nt < 8; ++nt)
          mx = fmaxf(mx, (acc[pt][nt][r] - bq[pt][r]) * shv[nt]);
        pmax[(size_t)(pw + pt * 16 + 4 * lg + r) * NCHUNK + wgl * 16 + lr] = mx;
      }
    }
    buf ^= 1;
  }
}

// ---------------------------------------------------------------------------
// Transpose: mem_value fp32 [1024][N] -> mvT fp16 [N][1024].
// 16.6 KB LDS -> ~8 blocks/CU -> HBM-saturating.
// ---------------------------------------------------------------------------
__global__ __launch_bounds__(256)
void k_transpose_h(const float* __restrict__ mv, _Float16* __restrict__ mvT)
{
  __shared__ float t[64][65];
  const int n0 = blockIdx.x * 64, ch0 = blockIdx.y * 64;
  const int tid = threadIdx.x;
  for (int i = tid; i < 64 * 16; i += 256) {
    int r = i >> 4, c4 = (i & 15) << 2;
    float4 v = *reinterpret_cast<const float4*>(&mv[(size_t)(ch0 + r) * NMEM + n0 + c4]);
    t[r][c4] = v.x; t[r][c4 + 1] = v.y; t[r][c4 + 2] = v.z; t[r][c4 + 3] = v.w;
  }
  __syncthreads();
  for (int i = tid; i < 64 * 16; i += 256) {
    int r = i >> 4, c4 = (i & 15) << 2;
    h4 hv = {(_Float16)t[c4][r], (_Float16)t[c4 + 1][r],
             (_Float16)t[c4 + 2][r], (_Float16)t[c4 + 3][r]};
    *reinterpret_cast<h4*>(&mvT[(size_t)(n0 + r) * 1024 + ch0 + c4]) = hv;
  }
}

// ---------------------------------------------------------------------------
// crossing finder: smallest bin B with prefix(<B) < target <= prefix(<=B)
// ---------------------------------------------------------------------------
__device__ __forceinline__ void find_cross(int* hist, int* lsum, int* wsum,
                                           int tid, int target, int* sB, int* sNA)
{
  const int base = tid * (BINS / 256);
  int ls = 0;
  #pragma unroll
  for (int k = 0; k < BINS / 256; ++k) ls += hist[base + k];
  lsum[tid] = ls;
  __syncthreads();
  int lane = tid & 63, wv = tid >> 6;
  int v = ls;
  #pragma unroll
  for (int off = 1; off < 64; off <<= 1) {
    int t = __shfl_up(v, off);
    if (lane >= off) v += t;
  }
  if (lane == 63) wsum[wv] = v;
  __syncthreads();
  int wo = 0;
  for (int k = 0; k < wv; ++k) wo += wsum[k];
  int run = wo + v - ls;
  #pragma unroll 1
  for (int k = 0; k < BINS / 256; ++k) {
    int h = hist[base + k];
    if (run < target && run + h >= target) { *sB = base + k; *sNA = run; }
    run += h;
  }
  __syncthreads();
}

// ---------------------------------------------------------------------------
// Kernel: per-pixel exact top-30 via chunk-max pruning + exact recompute.
// ---------------------------------------------------------------------------
__global__ __launch_bounds__(256)
void k_select(const float* __restrict__ pmax, const float* __restrict__ mkT,
              const float* __restrict__ q_key, const float* __restrict__ q_sel,
              const float* __restrict__ shr_s,
              float* __restrict__ wgt, int* __restrict__ widx)
{
  __shared__ int            hist[BINS];
  __shared__ float          sqk[64], sqs[64];
  __shared__ unsigned short chl[NCHUNK];
  __shared__ float          vcache[VCACHE];
  __shared__ unsigned       au[96];
  __shared__ int            ai[96];
  __shared__ unsigned       bu[1024];
  __shared__ int            bi[1024];
  __shared__ float          fv[32];
  __shared__ int            fi[32];
  __shared__ float          ew[32];
  __shared__ int            lsum[256], wsum[4];
  __shared__ int            sB, sNA, cA, cB, sSC;
  __shared__ float          sSum;

  const int pix = blockIdx.x;
  const int tid = threadIdx.x;

  if (tid < 64) {
    sqk[tid] = q_key[(size_t)tid * HW + pix];
    sqs[tid] = q_sel[(size_t)tid * HW + pix];
  }
  for (int i = tid; i < BINS; i += 256) hist[i] = 0;
  if (tid == 0) { sSC = 0; cA = 0; cB = 0; }
  __syncthreads();

  // ---- stage 1: chunk maxima -> CTARGET-crossing bin -> survivor chunks
  float m[NCHUNK / 256];
  const float* pm = pmax + (size_t)pix * NCHUNK;
  #pragma unroll
  for (int j = 0; j < NCHUNK / 256; ++j) m[j] = pm[tid + 256 * j];
  #pragma unroll
  for (int j = 0; j < NCHUNK / 256; ++j) atomicAdd(&hist[fkey(m[j]) >> 19], 1);
  __syncthreads();
  find_cross(hist, lsum, wsum, tid, CTARGET, &sB, &sNA);
  {
    const int B = sB;
    #pragma unroll
    for (int j = 0; j < NCHUNK / 256; ++j)
      if ((int)(fkey(m[j]) >> 19) <= B) {
        int k = atomicAdd(&sSC, 1);
        chl[k] = (unsigned short)(tid + 256 * j);
      }
  }
  __syncthreads();
  const int SC = sSC, NC = SC * 8;
  for (int i = tid; i < BINS; i += 256) hist[i] = 0;
  __syncthreads();

  const float4* sqk4 = reinterpret_cast<const float4*>(sqk);
  const float4* sqs4 = reinterpret_cast<const float4*>(sqs);

  // ---- stage 2 pass X: exact fp32 sims of candidates + histogram
  for (int c = tid; c < NC; c += 256) {
    const int cc = chl[c >> 3];
    const int n = ((cc >> 4) << 7) + (cc & 15) + ((c & 7) << 4);
    const float4* mr = reinterpret_cast<const float4*>(mkT + (size_t)n * 64);
    float s = 0.f;
    #pragma unroll
    for (int j = 0; j < 16; ++j) {
      float4 q = mr[j], k4 = sqk4[j], s4 = sqs4[j];
      float d0 = q.x - k4.x, d1 = q.y - k4.y, d2 = q.z - k4.z, d3 = q.w - k4.w;
      s = fmaf(s4.x * d0, d0, s); s = fmaf(s4.y * d1, d1, s);
      s = fmaf(s4.z * d2, d2, s); s = fmaf(s4.w * d3, d3, s);
    }
    float v = -s * shr_s[n];
    if (c < VCACHE) vcache[c] = v;
    atomicAdd(&hist[fkey(v) >> 19], 1);
  }
  __syncthreads();
  find_cross(hist, lsum, wsum, tid, TOPK, &sB, &sNA);

  // ---- stage 2 pass Y: collect top-30 (bins < B2) + boundary rank-cut
  {
    const int B2 = sB;
    for (int c = tid; c < NC; c += 256) {
      const int cc = chl[c >> 3];
      const int n = ((cc >> 4) << 7) + (cc & 15) + ((c & 7) << 4);
      float v;
      if (c < VCACHE) v = vcache[c];
      else {
        const float4* mr = reinterpret_cast<const float4*>(mkT + (size_t)n * 64);
        float s = 0.f;
        #pragma unroll
        for (int j = 0; j < 16; ++j) {
          float4 q = mr[j], k4 = sqk4[j], s4 = sqs4[j];
          float d0 = q.x - k4.x, d1 = q.y - k4.y, d2 = q.z - k4.z, d3 = q.w - k4.w;
          s = fmaf(s4.x * d0, d0, s); s = fmaf(s4.y * d1, d1, s);
          s = fmaf(s4.z * d2, d2, s); s = fmaf(s4.w * d3, d3, s);
        }
        v = -s * shr_s[n];
      }
      unsigned u = fkey(v);
      int bin = (int)(u >> 19);
      if (bin < B2)       { int k = atomicAdd(&cA, 1); au[k] = u; ai[k] = n; }
      else if (bin == B2) { int k = atomicAdd(&cB, 1); if (k < 1024) { bu[k] = u; bi[k] = n; } }
    }
  }
  __syncthreads();
  {
    const int nAv = cA, mm = (cB < 1024 ? cB : 1024), need = TOPK - nAv;
    for (int t = tid; t < mm; t += 256) {
      unsigned u = bu[t]; int id = bi[t];
      int r = 0;
      for (int k2 = 0; k2 < mm; ++k2) {
        unsigned uk = bu[k2];
        r += (uk < u) || (uk == u && bi[k2] < id);
      }
      if (r < need) { au[nAv + r] = u; ai[nAv + r] = id; }
    }
  }
  __syncthreads();

  // ---- deterministic ordering of the 30 + softmax
  if (tid < TOPK) {
    unsigned u = au[tid]; int id = ai[tid];
    int r = 0;
    for (int k2 = 0; k2 < TOPK; ++k2) {
      unsigned uk = au[k2];
      r += (uk < u) || (uk == u && ai[k2] < id);
    }
    fv[r] = -__uint_as_float(u); fi[r] = id;
  }
  __syncthreads();
  if (tid < 32) {
    float e = (tid < TOPK) ? expf(fv[tid]) : 0.f;
    if (tid < TOPK) ew[tid] = e;
    float ss = e;
    #pragma unroll
    for (int off = 16; off > 0; off >>= 1) ss += __shfl_down(ss, off);
    if (tid == 0) sSum = ss;
  }
  __syncthreads();
  if (tid < TOPK) {
    wgt [(size_t)pix * 32 + tid] = ew[tid] / sSum;
    widx[(size_t)pix * 32 + tid] = fi[tid];
  }
}

// ---------------------------------------------------------------------------
// Gather (fp16 source): out[ch][p] = sum_k w[p][k] * mvT[idx[p][k]][ch]
// ---------------------------------------------------------------------------
__global__ __launch_bounds__(256)
void k_gather_h(const _Float16* __restrict__ mvT, const float* __restrict__ wgt,
                const int* __restrict__ widx, float* __restrict__ out)
{
  __shared__ float sw[8][TOPK];
  __shared__ int   si[8][TOPK];
  __shared__ float sbuf[256][9];
  const int p0 = blockIdx.x * 8, chg = blockIdx.y * 256;
  const int tid = threadIdx.x;

  for (int i = tid; i < 8 * TOPK; i += 256) {
    int q = i / TOPK, k = i - q * TOPK;
    sw[q][k] = wgt [(size_t)(p0 + q) * 32 + k];
    si[q][k] = widx[(size_t)(p0 + q) * 32 + k];
  }
  __syncthreads();

  const int ch = chg + tid;
  #pragma unroll 2
  for (int q = 0; q < 8; ++q) {
    float a = 0.f;
    #pragma unroll
    for (int k = 0; k < TOPK; ++k)
      a = fmaf(sw[q][k], (float)mvT[(size_t)si[q][k] * 1024 + ch], a);
    sbuf[tid][q] = a;
  }
  __syncthreads();

  for (int i = tid; i < 256 * 8; i += 256) {
    int cl = i >> 3, q = i & 7;
    out[(size_t)(chg + cl) * HW + p0 + q] = sbuf[cl][q];
  }
}

// ---------------------------------------------------------------------------
// Gather (fp32 strided source, raw fallback)
// ---------------------------------------------------------------------------
__global__ __launch_bounds__(256)
void k_gather_f(const float* __restrict__ src, const float* __restrict__ wgt,
                const int* __restrict__ widx, float* __restrict__ out,
                long n_stride, long ch_stride)
{
  __shared__ float sw[8][TOPK];
  __shared__ int   si[8][TOPK];
  __shared__ float sbuf[256][9];
  const int p0 = blockIdx.x * 8, chg = blockIdx.y * 256;
  const int tid = threadIdx.x;

  for (int i = tid; i < 8 * TOPK; i += 256) {
    int q = i / TOPK, k = i - q * TOPK;
    sw[q][k] = wgt [(size_t)(p0 + q) * 32 + k];
    si[q][k] = widx[(size_t)(p0 + q) * 32 + k];
  }
  __syncthreads();

  const int ch = chg + tid;
  #pragma unroll 2
  for (int q = 0; q < 8; ++q) {
    float a = 0.f;
    #pragma unroll
    for (int k = 0; k < TOPK; ++k)
      a = fmaf(sw[q][k], src[(size_t)si[q][k] * n_stride + (size_t)ch * ch_stride], a);
    sbuf[tid][q] = a;
  }
  __syncthreads();

  for (int i = tid; i < 256 * 8; i += 256) {
    int cl = i >> 3, q = i & 7;
    out[(size_t)(chg + cl) * HW + p0 + q] = sbuf[cl][q];
  }
}

// ---------------------------------------------------------------------------
extern "C" void kernel_launch(void* const* d_in, const int* in_sizes, int n_in,
                              void* d_out, int out_size, void* d_ws, size_t ws_size,
                              hipStream_t stream)
{
  (void)in_sizes; (void)n_in; (void)out_size;
  const float* q_key     = (const float*)d_in[0];
  const float* q_sel     = (const float*)d_in[1];
  const float* mem_key   = (const float*)d_in[2];
  const float* mem_shr   = (const float*)d_in[3];
  const float* mem_value = (const float*)d_in[4];
  float* out = (float*)d_out;

  char* ws = (char*)d_ws;
  size_t off = 0;
  auto alloc = [&](size_t b) { size_t c = off; off = (off + b + 255) & ~(size_t)255; return c; };
  size_t o_w   = alloc((size_t)HW * 32 * 4);
  size_t o_wi  = alloc((size_t)HW * 32 * 4);
  size_t o_pr  = off;                              // overlay point (fallback)
  size_t o_bh  = alloc((size_t)NMEM * 128 * 2);    // 7.34 MB
  size_t o_uh  = alloc((size_t)HW * 128 * 2);
  size_t o_ul  = alloc((size_t)HW * 128 * 2);
  size_t o_bsq = alloc((size_t)HW * 4);
  size_t o_shr = alloc((size_t)NMEM * 4);
  size_t o_mkT = alloc((size_t)NMEM * 64 * 4);     // 7.34 MB
  size_t o_pm  = alloc((size_t)HW * NCHUNK * 4);   // 25.7 MB
  size_t o_end = off;

  float*          wg   = (float*)(ws + o_w);
  int*            wi   = (int*)  (ws + o_wi);
  unsigned short* Bh   = (unsigned short*)(ws + o_bh);
  unsigned short* Uh   = (unsigned short*)(ws + o_uh);
  unsigned short* Ul   = (unsigned short*)(ws + o_ul);
  float*          bsq  = (float*)(ws + o_bsq);
  float*          shr  = (float*)(ws + o_shr);
  float*          mkT  = (float*)(ws + o_mkT);
  float*          pmx  = (float*)(ws + o_pm);

  const size_t mvh_sz = (size_t)NMEM * 1024 * 2;   // 58.7 MB fp16

  k_prep_b<<<NMEM / 256, 256, 0, stream>>>(mem_key, mem_shr, Bh, mkT, shr);
  k_prep_u<<<HW / 256, 256, 0, stream>>>(q_key, q_sel, Uh, Ul, bsq);
  k_sim<<<SIMB, 256, 0, stream>>>(Uh, Ul, Bh, bsq, shr, pmx);

  if (ws_size >= o_end + mvh_sz) {
    _Float16* mvT = (_Float16*)(ws + o_end);
    k_transpose_h<<<dim3(NMEM / 64, 16), 256, 0, stream>>>(mem_value, mvT);
    k_select<<<HW, 256, 0, stream>>>(pmx, mkT, q_key, q_sel, shr, wg, wi);
    k_gather_h<<<dim3(HW / 8, 4), 256, 0, stream>>>(mvT, wg, wi, out);
  } else {
    k_select<<<HW, 256, 0, stream>>>(pmx, mkT, q_key, q_sel, shr, wg, wi);
    if (ws_size >= o_pr + mvh_sz) {
      _Float16* mvT = (_Float16*)(ws + o_pr);      // Bh..pmx dead after select
      k_transpose_h<<<dim3(NMEM / 64, 16), 256, 0, stream>>>(mem_value, mvT);
      k_gather_h<<<dim3(HW / 8, 4), 256, 0, stream>>>(mvT, wg, wi, out);
    } else {
      k_gather_f<<<dim3(HW / 8, 4), 256, 0, stream>>>(
          mem_value, wg, wi, out, 1, NMEM);
    }
  }
}

// Round 9
// 143.543 us; speedup vs baseline: 6.2849x; 1.1987x over previous
//
#include <hip/hip_runtime.h>
#include <math.h>

#define HW      1792
#define NMEM    28672
#define NCHUNK  3584          // NMEM/8 chunks of 8
#define TOPK    30
#define CTARGET 64
#define BINS    2048
#define BSHIFT  20
#define VCACHE  2048
#define BCAP    768
#define SIMB    448           // 14 p-blocks(128px) x 32 strips
#define WPS     7             // 128-n windows per strip

typedef __attribute__((ext_vector_type(8))) short bf16x8;
typedef __attribute__((ext_vector_type(8))) unsigned short u16x8;
typedef __attribute__((ext_vector_type(4))) float f32x4;
typedef __attribute__((ext_vector_type(4))) _Float16 h4;

static __device__ __forceinline__ unsigned short f2bf(float v) {
  unsigned b = __float_as_uint(v);
  return (unsigned short)((b + 0x7FFFu + ((b >> 16) & 1u)) >> 16);
}
static __device__ __forceinline__ float bf2f(unsigned short h) {
  return __uint_as_float(((unsigned)h) << 16);
}
static __device__ __forceinline__ unsigned fkey(float v) {
  return __float_as_uint(-v) & 0x7FFFFFFFu;
}
static __device__ __forceinline__ void gl_lds16(const void* g, void* l) {
  __builtin_amdgcn_global_load_lds(
      (const __attribute__((address_space(1))) unsigned*)g,
      (__attribute__((address_space(3))) unsigned*)l, 16, 0, 0);
}

// ---------------------------------------------------------------------------
// Prep B: Bh[s][n][8] bf16-hi (s=0..7: mk, s=8..15: mk^2); mkT[n][64] fp32;
// shr_s = mem_shr/8.
// ---------------------------------------------------------------------------
__global__ __launch_bounds__(256)
void k_prep_b(const float* __restrict__ mk, const float* __restrict__ shr_in,
              unsigned short* __restrict__ Bh,
              float* __restrict__ mkT, float* __restrict__ shr_s)
{
  const int n = blockIdx.x * 256 + threadIdx.x;
  shr_s[n] = shr_in[n] * 0.125f;
  for (int cb = 0; cb < 64; cb += 8) {
    u16x8 h1, h2;
    float vv[8];
    #pragma unroll
    for (int j = 0; j < 8; ++j) {
      float v = mk[(size_t)(cb + j) * NMEM + n];
      vv[j] = v;
      h1[j] = f2bf(v);
      h2[j] = f2bf(v * v);
    }
    const int s = cb >> 3;
    *reinterpret_cast<u16x8*>(&Bh[((size_t)s * NMEM + n) * 8])       = h1;
    *reinterpret_cast<u16x8*>(&Bh[((size_t)(s + 8) * NMEM + n) * 8]) = h2;
    *reinterpret_cast<float4*>(&mkT[(size_t)n * 64 + cb])     = make_float4(vv[0], vv[1], vv[2], vv[3]);
    *reinterpret_cast<float4*>(&mkT[(size_t)n * 64 + cb + 4]) = make_float4(vv[4], vv[5], vv[6], vv[7]);
  }
}

// ---------------------------------------------------------------------------
// Prep U: Uh/Ul[s][p][8] bf16 hi/lo. s=0..7: 2*qk*qs, s=8..15: -qs. bsq[p].
// ---------------------------------------------------------------------------
__global__ __launch_bounds__(256)
void k_prep_u(const float* __restrict__ q_key, const float* __restrict__ q_sel,
              unsigned short* __restrict__ Uh, unsigned short* __restrict__ Ul,
              float* __restrict__ bsq)
{
  const int p = blockIdx.x * 256 + threadIdx.x;
  float bs = 0.f;
  for (int cb = 0; cb < 64; cb += 8) {
    u16x8 h1, l1, h2, l2;
    #pragma unroll
    for (int j = 0; j < 8; ++j) {
      int c = cb + j;
      float k = q_key[(size_t)c * HW + p];
      float s = q_sel[(size_t)c * HW + p];
      float u = 2.f * k * s;
      float w = -s;
      bs = fmaf(s * k, k, bs);
      unsigned short h = f2bf(u); h1[j] = h; l1[j] = f2bf(u - bf2f(h));
      unsigned short g = f2bf(w); h2[j] = g; l2[j] = f2bf(w - bf2f(g));
    }
    const int s = cb >> 3;
    *reinterpret_cast<u16x8*>(&Uh[((size_t)s * HW + p) * 8])       = h1;
    *reinterpret_cast<u16x8*>(&Ul[((size_t)s * HW + p) * 8])       = l1;
    *reinterpret_cast<u16x8*>(&Uh[((size_t)(s + 8) * HW + p) * 8]) = h2;
    *reinterpret_cast<u16x8*>(&Ul[((size_t)(s + 8) * HW + p) * 8]) = l2;
  }
  bsq[p] = bs;
}

// ---------------------------------------------------------------------------
// Sim kernel: 128 pixels x 7-window strip per block (448 blocks).
// ---------------------------------------------------------------------------
__global__ __launch_bounds__(256, 2)
void k_sim(const unsigned short* __restrict__ Uh, const unsigned short* __restrict__ Ul,
           const unsigned short* __restrict__ Bh,
           const float* __restrict__ bsq, const float* __restrict__ shr_s,
           float* __restrict__ pmax)
{
  __shared__ char smem[65536] __attribute__((aligned(16)));
  const int tid = threadIdx.x;
  const int wid = tid >> 6, lane = tid & 63;
  const int lr = lane & 15, lg = lane >> 4;
  const int pb = blockIdx.x % 14, st = blockIdx.x / 14;
  const int pw = pb * 128 + wid * 32;
  const int w0 = st * WPS;

  bf16x8 a0h[4], a0l[4], a1h[4], a1l[4];
  #pragma unroll
  for (int t = 0; t < 4; ++t) {
    const size_t e0 = ((size_t)(t * 4 + lg) * HW + pw + lr) * 8;
    const size_t e1 = e0 + 16 * 8;
    a0h[t] = *reinterpret_cast<const bf16x8*>(&Uh[e0]);
    a0l[t] = *reinterpret_cast<const bf16x8*>(&Ul[e0]);
    a1h[t] = *reinterpret_cast<const bf16x8*>(&Uh[e1]);
    a1l[t] = *reinterpret_cast<const bf16x8*>(&Ul[e1]);
  }
  float bq[2][4];
  #pragma unroll
  for (int pt = 0; pt < 2; ++pt)
    #pragma unroll
    for (int r = 0; r < 4; ++r) bq[pt][r] = bsq[pw + pt * 16 + 4 * lg + r];

  auto stage = [&](int buf, int i) {
    const int n0 = (w0 + i) * 128;
    #pragma unroll
    for (int j = 0; j < 8; ++j) {
      const int idx = j * 256 + tid;
      const int s = idx >> 7, rr = idx & 127;
      gl_lds16((const char*)Bh + ((size_t)s * NMEM + n0 + rr) * 16,
               smem + buf * 32768 + idx * 16);
    }
  };

  stage(0, 0);
  int buf = 0;
  for (int i = 0; i < WPS; ++i) {
    __syncthreads();
    if (i + 1 < WPS) stage(buf ^ 1, i + 1);

    f32x4 acc[2][8];
    #pragma unroll
    for (int a = 0; a < 2; ++a)
      #pragma unroll
      for (int b = 0; b < 8; ++b) acc[a][b] = (f32x4){0.f, 0.f, 0.f, 0.f};

    const short* lb = (const short*)(smem + buf * 32768);
    #pragma unroll
    for (int t = 0; t < 4; ++t) {
      #pragma unroll
      for (int nt = 0; nt < 8; ++nt) {
        bf16x8 bh = *reinterpret_cast<const bf16x8*>(
            &lb[((t * 4 + lg) * 128 + nt * 16 + lr) * 8]);
        acc[0][nt] = __builtin_amdgcn_mfma_f32_16x16x32_bf16(a0h[t], bh, acc[0][nt], 0, 0, 0);
        acc[0][nt] = __builtin_amdgcn_mfma_f32_16x16x32_bf16(a0l[t], bh, acc[0][nt], 0, 0, 0);
        acc[1][nt] = __builtin_amdgcn_mfma_f32_16x16x32_bf16(a1h[t], bh, acc[1][nt], 0, 0, 0);
        acc[1][nt] = __builtin_amdgcn_mfma_f32_16x16x32_bf16(a1l[t], bh, acc[1][nt], 0, 0, 0);
      }
    }

    const int wgl = w0 + i;
    const int n0 = wgl * 128;
    float shv[8];
    #pragma unroll
    for (int nt = 0; nt < 8; ++nt) shv[nt] = shr_s[n0 + nt * 16 + lr];
    #pragma unroll
    for (int pt = 0; pt < 2; ++pt) {
      #pragma unroll
      for (int r = 0; r < 4; ++r) {
        float mx = -INFINITY;
        #pragma unroll
        for (int nt = 0; nt < 8; ++nt)
          mx = fmaxf(mx, (acc[pt][nt][r] - bq[pt][r]) * shv[nt]);
        pmax[(size_t)(pw + pt * 16 + 4 * lg + r) * NCHUNK + wgl * 16 + lr] = mx;
      }
    }
    buf ^= 1;
  }
}

// ---------------------------------------------------------------------------
// Shared-memory union for the fused select/transpose kernel (~32.3 KB)
// ---------------------------------------------------------------------------
struct SelS {
  int            hist[BINS];     // 8 KB
  unsigned short chl[NCHUNK];    // 7 KB
  float          vcache[VCACHE]; // 8 KB
  float          sqk[64], sqs[64];
  unsigned       au[64];
  int            ai[64];
  unsigned       bu[BCAP];       // 3 KB
  int            bi[BCAP];       // 3 KB
  float          fv[32];
  int            fi[32];
  float          ew[32];
  int            lsum[256];
  int            wsum[4];
  int            sB, sNA, cA, cB, sSC;
  float          sSum;
};
union SMemU {
  SelS  sel;
  float tt[64][65];              // 16.6 KB transpose tile
};

// ---------------------------------------------------------------------------
// crossing finder (operates on sm.sel): smallest bin B with
// prefix(<B) < target <= prefix(<=B)
// ---------------------------------------------------------------------------
__device__ __forceinline__ void find_cross(SelS& s, int tid, int target)
{
  const int base = tid * (BINS / 256);
  int ls = 0;
  #pragma unroll
  for (int k = 0; k < BINS / 256; ++k) ls += s.hist[base + k];
  s.lsum[tid] = ls;
  __syncthreads();
  int lane = tid & 63, wv = tid >> 6;
  int v = ls;
  #pragma unroll
  for (int off = 1; off < 64; off <<= 1) {
    int t = __shfl_up(v, off);
    if (lane >= off) v += t;
  }
  if (lane == 63) s.wsum[wv] = v;
  __syncthreads();
  int wo = 0;
  for (int k = 0; k < wv; ++k) wo += s.wsum[k];
  int run = wo + v - ls;
  #pragma unroll 1
  for (int k = 0; k < BINS / 256; ++k) {
    int h = s.hist[base + k];
    if (run < target && run + h >= target) { s.sB = base + k; s.sNA = run; }
    run += h;
  }
  __syncthreads();
}

// ---------------------------------------------------------------------------
// Fused kernel: select blocks (per-pixel exact top-30 via chunk-max pruning
// + exact fp32 recompute) interleaved 1:4 with transpose blocks
// (mem_value fp32 [1024][N] -> mvT fp16 [N][1024]).
// ---------------------------------------------------------------------------
__global__ __launch_bounds__(256, 4)
void k_selT(const float* __restrict__ pmax, const float* __restrict__ mkT,
            const float* __restrict__ q_key, const float* __restrict__ q_sel,
            const float* __restrict__ shr_s,
            float* __restrict__ wgt, int* __restrict__ widx,
            const float* __restrict__ mv, _Float16* __restrict__ mvT)
{
  __shared__ SMemU sm;
  const int tid = threadIdx.x;

  int pix = -1, tb = -1;
  if (gridDim.x > HW) {
    const int g = blockIdx.x / 5, r = blockIdx.x % 5;
    if (r == 0) pix = g; else tb = g * 4 + (r - 1);
  } else {
    pix = blockIdx.x;
  }

  if (tb >= 0) {
    // ---- transpose block: 64n x 64ch fp32 -> fp16
    const int n0 = (tb % 448) * 64, ch0 = (tb / 448) * 64;
    for (int i = tid; i < 64 * 16; i += 256) {
      int r = i >> 4, c4 = (i & 15) << 2;
      float4 v = *reinterpret_cast<const float4*>(&mv[(size_t)(ch0 + r) * NMEM + n0 + c4]);
      sm.tt[r][c4] = v.x; sm.tt[r][c4 + 1] = v.y;
      sm.tt[r][c4 + 2] = v.z; sm.tt[r][c4 + 3] = v.w;
    }
    __syncthreads();
    for (int i = tid; i < 64 * 16; i += 256) {
      int r = i >> 4, c4 = (i & 15) << 2;
      h4 hv = {(_Float16)sm.tt[c4][r], (_Float16)sm.tt[c4 + 1][r],
               (_Float16)sm.tt[c4 + 2][r], (_Float16)sm.tt[c4 + 3][r]};
      *reinterpret_cast<h4*>(&mvT[(size_t)(n0 + r) * 1024 + ch0 + c4]) = hv;
    }
    return;
  }

  SelS& s = sm.sel;
  if (tid < 64) {
    s.sqk[tid] = q_key[(size_t)tid * HW + pix];
    s.sqs[tid] = q_sel[(size_t)tid * HW + pix];
  }
  for (int i = tid; i < BINS; i += 256) s.hist[i] = 0;
  if (tid == 0) { s.sSC = 0; s.cA = 0; s.cB = 0; }
  __syncthreads();

  // ---- stage 1: chunk maxima -> CTARGET-crossing bin -> survivor chunks
  float m[NCHUNK / 256];
  const float* pm = pmax + (size_t)pix * NCHUNK;
  #pragma unroll
  for (int j = 0; j < NCHUNK / 256; ++j) m[j] = pm[tid + 256 * j];
  #pragma unroll
  for (int j = 0; j < NCHUNK / 256; ++j) atomicAdd(&s.hist[fkey(m[j]) >> BSHIFT], 1);
  __syncthreads();
  find_cross(s, tid, CTARGET);
  {
    const int B = s.sB;
    #pragma unroll
    for (int j = 0; j < NCHUNK / 256; ++j)
      if ((int)(fkey(m[j]) >> BSHIFT) <= B) {
        int k = atomicAdd(&s.sSC, 1);
        s.chl[k] = (unsigned short)(tid + 256 * j);
      }
  }
  __syncthreads();
  const int NC = s.sSC * 8;
  for (int i = tid; i < BINS; i += 256) s.hist[i] = 0;
  __syncthreads();

  const float4* sqk4 = reinterpret_cast<const float4*>(s.sqk);
  const float4* sqs4 = reinterpret_cast<const float4*>(s.sqs);

  // ---- stage 2 pass X: exact fp32 sims of candidates + histogram
  for (int c = tid; c < NC; c += 256) {
    const int cc = s.chl[c >> 3];
    const int n = ((cc >> 4) << 7) + (cc & 15) + ((c & 7) << 4);
    const float4* mr = reinterpret_cast<const float4*>(mkT + (size_t)n * 64);
    float sv = 0.f;
    #pragma unroll
    for (int j = 0; j < 16; ++j) {
      float4 q = mr[j], k4 = sqk4[j], s4 = sqs4[j];
      float d0 = q.x - k4.x, d1 = q.y - k4.y, d2 = q.z - k4.z, d3 = q.w - k4.w;
      sv = fmaf(s4.x * d0, d0, sv); sv = fmaf(s4.y * d1, d1, sv);
      sv = fmaf(s4.z * d2, d2, sv); sv = fmaf(s4.w * d3, d3, sv);
    }
    float v = -sv * shr_s[n];
    if (c < VCACHE) s.vcache[c] = v;
    atomicAdd(&s.hist[fkey(v) >> BSHIFT], 1);
  }
  __syncthreads();
  find_cross(s, tid, TOPK);

  // ---- stage 2 pass Y: collect top-30 (bins < B2) + boundary rank-cut
  {
    const int B2 = s.sB;
    for (int c = tid; c < NC; c += 256) {
      const int cc = s.chl[c >> 3];
      const int n = ((cc >> 4) << 7) + (cc & 15) + ((c & 7) << 4);
      float v;
      if (c < VCACHE) v = s.vcache[c];
      else {
        const float4* mr = reinterpret_cast<const float4*>(mkT + (size_t)n * 64);
        float sv = 0.f;
        #pragma unroll
        for (int j = 0; j < 16; ++j) {
          float4 q = mr[j], k4 = sqk4[j], s4 = sqs4[j];
          float d0 = q.x - k4.x, d1 = q.y - k4.y, d2 = q.z - k4.z, d3 = q.w - k4.w;
          sv = fmaf(s4.x * d0, d0, sv); sv = fmaf(s4.y * d1, d1, sv);
          sv = fmaf(s4.z * d2, d2, sv); sv = fmaf(s4.w * d3, d3, sv);
        }
        v = -sv * shr_s[n];
      }
      unsigned u = fkey(v);
      int bin = (int)(u >> BSHIFT);
      if (bin < B2)       { int k = atomicAdd(&s.cA, 1); s.au[k] = u; s.ai[k] = n; }
      else if (bin == B2) { int k = atomicAdd(&s.cB, 1); if (k < BCAP) { s.bu[k] = u; s.bi[k] = n; } }
    }
  }
  __syncthreads();
  {
    const int nAv = s.cA, mm = (s.cB < BCAP ? s.cB : BCAP), need = TOPK - nAv;
    for (int t = tid; t < mm; t += 256) {
      unsigned u = s.bu[t]; int id = s.bi[t];
      int r = 0;
      for (int k2 = 0; k2 < mm; ++k2) {
        unsigned uk = s.bu[k2];
        r += (uk < u) || (uk == u && s.bi[k2] < id);
      }
      if (r < need) { s.au[nAv + r] = u; s.ai[nAv + r] = id; }
    }
  }
  __syncthreads();

  // ---- deterministic ordering of the 30 + softmax
  if (tid < TOPK) {
    unsigned u = s.au[tid]; int id = s.ai[tid];
    int r = 0;
    for (int k2 = 0; k2 < TOPK; ++k2) {
      unsigned uk = s.au[k2];
      r += (uk < u) || (uk == u && s.ai[k2] < id);
    }
    s.fv[r] = -__uint_as_float(u); s.fi[r] = id;
  }
  __syncthreads();
  if (tid < 32) {
    float e = (tid < TOPK) ? expf(s.fv[tid]) : 0.f;
    if (tid < TOPK) s.ew[tid] = e;
    float ss = e;
    #pragma unroll
    for (int off = 16; off > 0; off >>= 1) ss += __shfl_down(ss, off);
    if (tid == 0) s.sSum = ss;
  }
  __syncthreads();
  if (tid < TOPK) {
    wgt [(size_t)pix * 32 + tid] = s.ew[tid] / s.sSum;
    widx[(size_t)pix * 32 + tid] = s.fi[tid];
  }
}

// ---------------------------------------------------------------------------
// Standalone fp16 transpose (fallback, overlay mode)
// ---------------------------------------------------------------------------
__global__ __launch_bounds__(256)
void k_transpose_h(const float* __restrict__ mv, _Float16* __restrict__ mvT)
{
  __shared__ float t[64][65];
  const int n0 = blockIdx.x * 64, ch0 = blockIdx.y * 64;
  const int tid = threadIdx.x;
  for (int i = tid; i < 64 * 16; i += 256) {
    int r = i >> 4, c4 = (i & 15) << 2;
    float4 v = *reinterpret_cast<const float4*>(&mv[(size_t)(ch0 + r) * NMEM + n0 + c4]);
    t[r][c4] = v.x; t[r][c4 + 1] = v.y; t[r][c4 + 2] = v.z; t[r][c4 + 3] = v.w;
  }
  __syncthreads();
  for (int i = tid; i < 64 * 16; i += 256) {
    int r = i >> 4, c4 = (i & 15) << 2;
    h4 hv = {(_Float16)t[c4][r], (_Float16)t[c4 + 1][r],
             (_Float16)t[c4 + 2][r], (_Float16)t[c4 + 3][r]};
    *reinterpret_cast<h4*>(&mvT[(size_t)(n0 + r) * 1024 + ch0 + c4]) = hv;
  }
}

// ---------------------------------------------------------------------------
// Gather (fp16 source): out[ch][p] = sum_k w[p][k] * mvT[idx[p][k]][ch]
// ---------------------------------------------------------------------------
__global__ __launch_bounds__(256)
void k_gather_h(const _Float16* __restrict__ mvT, const float* __restrict__ wgt,
                const int* __restrict__ widx, float* __restrict__ out)
{
  __shared__ float sw[8][TOPK];
  __shared__ int   si[8][TOPK];
  __shared__ float sbuf[256][9];
  const int p0 = blockIdx.x * 8, chg = blockIdx.y * 256;
  const int tid = threadIdx.x;

  for (int i = tid; i < 8 * TOPK; i += 256) {
    int q = i / TOPK, k = i - q * TOPK;
    sw[q][k] = wgt [(size_t)(p0 + q) * 32 + k];
    si[q][k] = widx[(size_t)(p0 + q) * 32 + k];
  }
  __syncthreads();

  const int ch = chg + tid;
  #pragma unroll 2
  for (int q = 0; q < 8; ++q) {
    float a = 0.f;
    #pragma unroll
    for (int k = 0; k < TOPK; ++k)
      a = fmaf(sw[q][k], (float)mvT[(size_t)si[q][k] * 1024 + ch], a);
    sbuf[tid][q] = a;
  }
  __syncthreads();

  for (int i = tid; i < 256 * 8; i += 256) {
    int cl = i >> 3, q = i & 7;
    out[(size_t)(chg + cl) * HW + p0 + q] = sbuf[cl][q];
  }
}

// ---------------------------------------------------------------------------
// Gather (fp32 strided source, raw fallback)
// ---------------------------------------------------------------------------
__global__ __launch_bounds__(256)
void k_gather_f(const float* __restrict__ src, const float* __restrict__ wgt,
                const int* __restrict__ widx, float* __restrict__ out,
                long n_stride, long ch_stride)
{
  __shared__ float sw[8][TOPK];
  __shared__ int   si[8][TOPK];
  __shared__ float sbuf[256][9];
  const int p0 = blockIdx.x * 8, chg = blockIdx.y * 256;
  const int tid = threadIdx.x;

  for (int i = tid; i < 8 * TOPK; i += 256) {
    int q = i / TOPK, k = i - q * TOPK;
    sw[q][k] = wgt [(size_t)(p0 + q) * 32 + k];
    si[q][k] = widx[(size_t)(p0 + q) * 32 + k];
  }
  __syncthreads();

  const int ch = chg + tid;
  #pragma unroll 2
  for (int q = 0; q < 8; ++q) {
    float a = 0.f;
    #pragma unroll
    for (int k = 0; k < TOPK; ++k)
      a = fmaf(sw[q][k], src[(size_t)si[q][k] * n_stride + (size_t)ch * ch_stride], a);
    sbuf[tid][q] = a;
  }
  __syncthreads();

  for (int i = tid; i < 256 * 8; i += 256) {
    int cl = i >> 3, q = i & 7;
    out[(size_t)(chg + cl) * HW + p0 + q] = sbuf[cl][q];
  }
}

// ---------------------------------------------------------------------------
extern "C" void kernel_launch(void* const* d_in, const int* in_sizes, int n_in,
                              void* d_out, int out_size, void* d_ws, size_t ws_size,
                              hipStream_t stream)
{
  (void)in_sizes; (void)n_in; (void)out_size;
  const float* q_key     = (const float*)d_in[0];
  const float* q_sel     = (const float*)d_in[1];
  const float* mem_key   = (const float*)d_in[2];
  const float* mem_shr   = (const float*)d_in[3];
  const float* mem_value = (const float*)d_in[4];
  float* out = (float*)d_out;

  char* ws = (char*)d_ws;
  size_t off = 0;
  auto alloc = [&](size_t b) { size_t c = off; off = (off + b + 255) & ~(size_t)255; return c; };
  size_t o_w   = alloc((size_t)HW * 32 * 4);
  size_t o_wi  = alloc((size_t)HW * 32 * 4);
  size_t o_pr  = off;                              // overlay point (fallback)
  size_t o_bh  = alloc((size_t)NMEM * 128 * 2);    // 7.34 MB
  size_t o_uh  = alloc((size_t)HW * 128 * 2);
  size_t o_ul  = alloc((size_t)HW * 128 * 2);
  size_t o_bsq = alloc((size_t)HW * 4);
  size_t o_shr = alloc((size_t)NMEM * 4);
  size_t o_mkT = alloc((size_t)NMEM * 64 * 4);     // 7.34 MB
  size_t o_pm  = alloc((size_t)HW * NCHUNK * 4);   // 25.7 MB
  size_t o_end = off;

  float*          wg   = (float*)(ws + o_w);
  int*            wi   = (int*)  (ws + o_wi);
  unsigned short* Bh   = (unsigned short*)(ws + o_bh);
  unsigned short* Uh   = (unsigned short*)(ws + o_uh);
  unsigned short* Ul   = (unsigned short*)(ws + o_ul);
  float*          bsq  = (float*)(ws + o_bsq);
  float*          shr  = (float*)(ws + o_shr);
  float*          mkT  = (float*)(ws + o_mkT);
  float*          pmx  = (float*)(ws + o_pm);

  const size_t mvh_sz = (size_t)NMEM * 1024 * 2;   // 58.7 MB fp16

  k_prep_b<<<NMEM / 256, 256, 0, stream>>>(mem_key, mem_shr, Bh, mkT, shr);
  k_prep_u<<<HW / 256, 256, 0, stream>>>(q_key, q_sel, Uh, Ul, bsq);
  k_sim<<<SIMB, 256, 0, stream>>>(Uh, Ul, Bh, bsq, shr, pmx);

  if (ws_size >= o_end + mvh_sz) {
    // fused: select (1792) + transpose (7168) interleaved 1:4
    _Float16* mvT = (_Float16*)(ws + o_end);
    k_selT<<<HW * 5, 256, 0, stream>>>(pmx, mkT, q_key, q_sel, shr,
                                       wg, wi, mem_value, mvT);
    k_gather_h<<<dim3(HW / 8, 4), 256, 0, stream>>>(mvT, wg, wi, out);
  } else {
    // fallback: select only, then transpose into overlay region (or raw)
    k_selT<<<HW, 256, 0, stream>>>(pmx, mkT, q_key, q_sel, shr,
                                   wg, wi, mem_value, nullptr);
    if (ws_size >= o_pr + mvh_sz) {
      _Float16* mvT = (_Float16*)(ws + o_pr);      // Bh..pmx dead after select
      k_transpose_h<<<dim3(NMEM / 64, 16), 256, 0, stream>>>(mem_value, mvT);
      k_gather_h<<<dim3(HW / 8, 4), 256, 0, stream>>>(mvT, wg, wi, out);
    } else {
      k_gather_f<<<dim3(HW / 8, 4), 256, 0, stream>>>(
          mem_value, wg, wi, out, 1, NMEM);
    }
  }
}